// Round 1
// baseline (2535.306 us; speedup 1.0000x reference)
//
#include <hip/hip_runtime.h>

#define B_ 32
#define L_ 256
#define D_ 768
#define H_ 12
#define DK_ 64
#define MEM_ 384

// ---------------- block reduce helpers (256 threads = 4 waves) ----------------
__device__ inline float waveRedSum(float v) {
#pragma unroll
  for (int o = 32; o; o >>= 1) v += __shfl_xor(v, o, 64);
  return v;
}
__device__ inline float waveRedMax(float v) {
#pragma unroll
  for (int o = 32; o; o >>= 1) v = fmaxf(v, __shfl_xor(v, o, 64));
  return v;
}
__device__ inline float blkRedSum(float v, float* red) {
  v = waveRedSum(v);
  int w = threadIdx.x >> 6;
  __syncthreads();
  if ((threadIdx.x & 63) == 0) red[w] = v;
  __syncthreads();
  return red[0] + red[1] + red[2] + red[3];
}
__device__ inline float blkRedMax(float v, float* red) {
  v = waveRedMax(v);
  int w = threadIdx.x >> 6;
  __syncthreads();
  if ((threadIdx.x & 63) == 0) red[w] = v;
  __syncthreads();
  return fmaxf(fmaxf(red[0], red[1]), fmaxf(red[2], red[3]));
}

// ---------------- LayerNorm (ddof=1 std, (sd+1e-6) denominator) ----------------
__global__ __launch_bounds__(256) void ln_kernel(const float* __restrict__ in,
                                                 const float* __restrict__ g,
                                                 const float* __restrict__ bt,
                                                 float* __restrict__ out) {
  long row = blockIdx.x;
  const float* p = in + row * D_;
  float v[3];
#pragma unroll
  for (int i = 0; i < 3; ++i) v[i] = p[threadIdx.x + i * 256];
  __shared__ float red[4];
  float s = v[0] + v[1] + v[2];
  s = blkRedSum(s, red);
  float mu = s * (1.f / D_);
  float ss = 0.f;
#pragma unroll
  for (int i = 0; i < 3; ++i) { float d = v[i] - mu; ss += d * d; }
  ss = blkRedSum(ss, red);
  float sd = sqrtf(ss * (1.f / (D_ - 1)));
  float inv = 1.f / (sd + 1e-6f);
#pragma unroll
  for (int i = 0; i < 3; ++i) {
    int c = threadIdx.x + i * 256;
    out[row * D_ + c] = g[c] * (v[i] - mu) * inv + bt[c];
  }
}

// ---------------- generic tiled SGEMM, 64x64 tile, 4x4 microtile ----------------
// C[z,m,n] = epi( sum_k A[z,m,k] * B[z, k or n, n or k] )
// epi: v = acc*rowScale[z*M+m]; v += bias[n]; v /= rowDiv[z*M+m]; relu
__global__ __launch_bounds__(256) void gemm64(
    const float* __restrict__ A, const float* __restrict__ B, float* __restrict__ C,
    int M, int N, int K, long sA, long sB, long sC,
    const float* __restrict__ rowScale, const float* __restrict__ bias,
    const float* __restrict__ rowDiv, int relu, int transB) {
  const int tid = threadIdx.x;
  const int bn = blockIdx.x, bm = blockIdx.y, bz = blockIdx.z;
  A += (long)bz * sA; B += (long)bz * sB; C += (long)bz * sC;
  __shared__ float As[16][65];
  __shared__ float Bs[16][65];
  float acc[4][4] = {};
  const int tm = tid & 15, tn = tid >> 4;
  for (int k0 = 0; k0 < K; k0 += 16) {
#pragma unroll
    for (int i = 0; i < 4; ++i) {
      int idx = tid + i * 256;
      int r = idx >> 4, c = idx & 15;
      As[c][r] = A[(long)(bm * 64 + r) * K + k0 + c];
    }
    if (!transB) {
#pragma unroll
      for (int i = 0; i < 4; ++i) {
        int idx = tid + i * 256;
        int r = idx >> 6, c = idx & 63;
        Bs[r][c] = B[(long)(k0 + r) * N + bn * 64 + c];
      }
    } else {
#pragma unroll
      for (int i = 0; i < 4; ++i) {
        int idx = tid + i * 256;
        int r = idx >> 4, c = idx & 15;
        Bs[c][r] = B[(long)(bn * 64 + r) * K + k0 + c];
      }
    }
    __syncthreads();
#pragma unroll
    for (int kk = 0; kk < 16; ++kk) {
      float a[4], bb[4];
#pragma unroll
      for (int i = 0; i < 4; ++i) a[i] = As[kk][tm * 4 + i];
#pragma unroll
      for (int j = 0; j < 4; ++j) bb[j] = Bs[kk][tn * 4 + j];
#pragma unroll
      for (int i = 0; i < 4; ++i)
#pragma unroll
        for (int j = 0; j < 4; ++j) acc[i][j] += a[i] * bb[j];
    }
    __syncthreads();
  }
#pragma unroll
  for (int i = 0; i < 4; ++i) {
    int r = bm * 64 + tm * 4 + i;
    long grow = (long)bz * M + r;
    float rs = rowScale ? rowScale[grow] : 1.f;
    float rd = rowDiv ? 1.f / rowDiv[grow] : 1.f;
#pragma unroll
    for (int j = 0; j < 4; ++j) {
      int cn = bn * 64 + tn * 4 + j;
      float v = acc[i][j] * rs;
      if (bias) v += bias[cn];
      v *= rd;
      if (relu) v = fmaxf(v, 0.f);
      C[(long)r * N + cn] = v;
    }
  }
}

// ---------------- fused attention: adj_s = rowmask * fixdiag(mean_h softmax(qk^T/8, colmask)) ----
__global__ __launch_bounds__(256) void attn_adjs(const float* __restrict__ q,
                                                 const float* __restrict__ k,
                                                 const float* __restrict__ srcm,
                                                 float* __restrict__ adj_s) {
  int bl = blockIdx.x;  // b*L + l
  int b = bl >> 8, l = bl & 255;
  int m = threadIdx.x;
  __shared__ float qs[D_];
  __shared__ float red[4];
#pragma unroll
  for (int i = 0; i < 3; ++i) qs[m + i * 256] = q[(long)bl * D_ + m + i * 256];
  __syncthreads();
  float cm = srcm[b * L_ + m];
  const float* kp = k + ((long)b * L_ + m) * D_;
  float acc = 0.f;
  for (int h = 0; h < H_; ++h) {
    const float4* k4 = (const float4*)(kp + h * DK_);
    float s = 0.f;
#pragma unroll
    for (int j = 0; j < 16; ++j) {
      float4 kv = k4[j];
      s += qs[h * 64 + 4 * j + 0] * kv.x + qs[h * 64 + 4 * j + 1] * kv.y +
           qs[h * 64 + 4 * j + 2] * kv.z + qs[h * 64 + 4 * j + 3] * kv.w;
    }
    s *= 0.125f;  // 1/sqrt(64)
    if (cm == 0.f) s = -1e9f;
    float mx = blkRedMax(s, red);
    float e = expf(s - mx);
    float ssum = blkRedSum(e, red);
    acc += e / ssum;
  }
  float v = acc * (1.f / H_);
  if (m == l) v = 1.f;
  v *= srcm[b * L_ + l];
  adj_s[(long)bl * L_ + m] = v;
}

// ---------------- tmpA[b,h] = asp[b] (L x 64) @ Wm[h] (64 x 64) ----------------
__global__ __launch_bounds__(256) void asp_wm(const float* __restrict__ asp,
                                              const float* __restrict__ wm,
                                              float* __restrict__ tmpA) {
  int bh = blockIdx.x;
  int b = bh / H_, h = bh % H_;
  int t = threadIdx.x;
  __shared__ float WmS[64][64];
  __shared__ float aspS[64][64];
#pragma unroll
  for (int i = 0; i < 16; ++i) {
    int idx = t + i * 256;
    WmS[idx >> 6][idx & 63] = wm[h * 4096 + idx];
  }
  int e = t & 63, lr = t >> 6;
  for (int c = 0; c < 4; ++c) {
    __syncthreads();
#pragma unroll
    for (int i = 0; i < 16; ++i) {
      int idx = t + i * 256;
      aspS[idx >> 6][idx & 63] = asp[((long)b * L_ + c * 64 + (idx >> 6)) * 64 + (idx & 63)];
    }
    __syncthreads();
    for (int s = 0; s < 16; ++s) {
      int ll = s * 4 + lr;
      float accv = 0.f;
#pragma unroll
      for (int d = 0; d < 64; ++d) accv += aspS[ll][d] * WmS[d][e];
      tmpA[(((long)b * H_ + h) * L_ + c * 64 + ll) * 64 + e] = accv;
    }
  }
}

// ---------------- asps_mean[b,l,m] = mean_h tanh(tmpA[b,h,l,:] . k_h[b,m,:] + bias) ----------------
__global__ __launch_bounds__(256) void asps_mean_kernel(const float* __restrict__ tmpA,
                                                        const float* __restrict__ k,
                                                        const float* __restrict__ bias_m,
                                                        float* __restrict__ asps_mean) {
  int blk = blockIdx.x;  // b*16 + chunk
  int b = blk >> 4, l0 = (blk & 15) << 4;
  int m = threadIdx.x;
  float bm = bias_m[0];
  __shared__ float tAs[16][64];
  float acc[16];
#pragma unroll
  for (int i = 0; i < 16; ++i) acc[i] = 0.f;
  for (int h = 0; h < H_; ++h) {
    __syncthreads();
#pragma unroll
    for (int i = 0; i < 4; ++i) {
      int idx = m + i * 256;
      tAs[idx >> 6][idx & 63] =
          tmpA[(((long)b * H_ + h) * L_ + l0 + (idx >> 6)) * 64 + (idx & 63)];
    }
    __syncthreads();
    const float4* k4 = (const float4*)(k + ((long)b * L_ + m) * D_ + h * DK_);
    float4 kr[16];
#pragma unroll
    for (int j = 0; j < 16; ++j) kr[j] = k4[j];
#pragma unroll
    for (int l = 0; l < 16; ++l) {
      float s = 0.f;
#pragma unroll
      for (int j = 0; j < 16; ++j) {
        s += tAs[l][4 * j + 0] * kr[j].x + tAs[l][4 * j + 1] * kr[j].y +
             tAs[l][4 * j + 2] * kr[j].z + tAs[l][4 * j + 3] * kr[j].w;
      }
      acc[l] += tanhf(s + bm);
    }
  }
#pragma unroll
  for (int l = 0; l < 16; ++l)
    asps_mean[((long)b * L_ + l0 + l) * L_ + m] = acc[l] * (1.f / H_);
}

// ---------------- avgH[b,m] = mean_l asps_mean[b,l,m] ----------------
__global__ __launch_bounds__(256) void avgh_kernel(const float* __restrict__ asps_mean,
                                                   float* __restrict__ avgH) {
  int b = blockIdx.x, m = threadIdx.x;
  float s = 0.f;
  for (int l = 0; l < L_; ++l) s += asps_mean[((long)b * L_ + l) * L_ + m];
  avgH[b * L_ + m] = s * (1.f / L_);
}

// ---------------- adj_ag = where(asa>BETA,1,exp(adj_r)) * asa, with mask-case asa ----------------
__global__ __launch_bounds__(256) void adjag_kernel(const float* __restrict__ asps_mean,
                                                    const float* __restrict__ avgH,
                                                    const float* __restrict__ amask,
                                                    const float* __restrict__ adjr,
                                                    float* __restrict__ adj_ag) {
  long idx = (long)blockIdx.x * 256 + threadIdx.x;
  int m = idx & 255;
  long bl = idx >> 8;
  int l = (int)(bl & 255);
  int b = (int)(bl >> 8);
  bool rowa = amask[b * L_ + l] > 0.f;
  bool cola = amask[b * L_ + m] > 0.f;
  float asa;
  if (rowa && cola) asa = (l >= m) ? avgH[b * L_ + m] : avgH[b * L_ + l];
  else if (rowa)    asa = avgH[b * L_ + m];
  else if (cola)    asa = avgH[b * L_ + l];
  else              asa = asps_mean[idx];
  float r = (asa > 0.25f) ? 1.f : expf(adjr[idx]);  // ALPHA = 1.0
  adj_ag[idx] = r * asa;
}

// ---------------- KL partials + row denominators ----------------
__global__ __launch_bounds__(256) void kl_denom(const float* __restrict__ adj_s,
                                                const float* __restrict__ adj_ag,
                                                float* __restrict__ klpart,
                                                float* __restrict__ den_s,
                                                float* __restrict__ den_ag) {
  long row = blockIdx.x;
  int m = threadIdx.x;
  __shared__ float red[4];
  float s = adj_s[row * L_ + m];
  float a = adj_ag[row * L_ + m];
  float sum_s = blkRedSum(s, red);
  float sum_a = blkRedSum(a, red);
  float mx_s = blkRedMax(s, red);
  float mx_a = blkRedMax(a, red);
  float es = expf(s - mx_s), ea = expf(a - mx_a);
  float ses = blkRedSum(es, red);
  float sea = blkRedSum(ea, red);
  float logq = (s - mx_s) - logf(ses);
  float logp = (a - mx_a) - logf(sea);
  float term = (es / ses) * (logq - logp);
  float kp = blkRedSum(term, red);
  if (m == 0) {
    klpart[row] = kp;
    den_s[row] = sum_s + 1.f;
    den_ag[row] = sum_a + 1.f;
  }
}

__global__ __launch_bounds__(256) void kl_final(const float* __restrict__ klpart,
                                                float* __restrict__ dout) {
  __shared__ float red[4];
  float s = 0.f;
  for (int i = threadIdx.x; i < B_ * L_; i += 256) s += klpart[i];
  s = blkRedSum(s, red);
  if (threadIdx.x == 0) dout[96] = expf(-s * 0.1f);  // GAMA = 0.1
}

// ---------------- in-place row softmax over last dim (256) ----------------
__global__ __launch_bounds__(256) void softmax_rows(float* __restrict__ S) {
  long row = blockIdx.x;
  int m = threadIdx.x;
  __shared__ float red[4];
  float v = S[row * L_ + m];
  float mx = blkRedMax(v, red);
  float e = expf(v - mx);
  float s = blkRedSum(e, red);
  S[row * L_ + m] = e / s;
}

// ---------------- classifier head ----------------
__global__ __launch_bounds__(256) void final_kernel(const float* __restrict__ o_ag,
                                                    const float* __restrict__ o_s,
                                                    const float* __restrict__ pooled,
                                                    const float* __restrict__ amask,
                                                    const float* __restrict__ wc,
                                                    const float* __restrict__ bc,
                                                    float* __restrict__ dout) {
  int b = blockIdx.x, t = threadIdx.x;
  __shared__ float cS[1536];
  __shared__ float maskS[256];
  __shared__ float red[4];
  maskS[t] = amask[b * L_ + t];
  float wn = blkRedSum(maskS[t], red);  // includes the syncs protecting maskS
  for (int e = t; e < MEM_; e += 256) {
    float s1 = 0.f, s2 = 0.f;
    for (int l = 0; l < L_; ++l) {
      float mk = maskS[l];
      if (mk != 0.f) {
        s1 += mk * o_ag[((long)b * L_ + l) * MEM_ + e];
        s2 += mk * o_s[((long)b * L_ + l) * MEM_ + e];
      }
    }
    cS[e] = s1 / wn;
    cS[MEM_ + e] = s2 / wn;
  }
  for (int j = t; j < D_; j += 256) cS[2 * MEM_ + j] = pooled[b * D_ + j];
  __syncthreads();
  float p0 = 0.f, p1 = 0.f, p2 = 0.f;
  for (int j = t; j < 1536; j += 256) {
    float v = cS[j];
    p0 += v * wc[j * 3 + 0];
    p1 += v * wc[j * 3 + 1];
    p2 += v * wc[j * 3 + 2];
  }
  p0 = blkRedSum(p0, red);
  p1 = blkRedSum(p1, red);
  p2 = blkRedSum(p2, red);
  if (t == 0) {
    dout[b * 3 + 0] = p0 + bc[0];
    dout[b * 3 + 1] = p1 + bc[1];
    dout[b * 3 + 2] = p2 + bc[2];
  }
}

extern "C" void kernel_launch(void* const* d_in, const int* in_sizes, int n_in,
                              void* d_out, int out_size, void* d_ws, size_t ws_size,
                              hipStream_t stream) {
  const float* seq    = (const float*)d_in[0];
  const float* pooled = (const float*)d_in[1];
  const float* adjr   = (const float*)d_in[2];
  const float* srcm   = (const float*)d_in[3];
  const float* amask  = (const float*)d_in[4];
  const float* ln_g   = (const float*)d_in[5];
  const float* ln_b   = (const float*)d_in[6];
  const float* wq     = (const float*)d_in[7];
  const float* bq     = (const float*)d_in[8];
  const float* wk     = (const float*)d_in[9];
  const float* bk     = (const float*)d_in[10];
  const float* wd     = (const float*)d_in[11];
  const float* bd     = (const float*)d_in[12];
  const float* wm     = (const float*)d_in[13];
  const float* bm     = (const float*)d_in[14];
  const float* wa0    = (const float*)d_in[15];
  const float* ba0    = (const float*)d_in[16];
  const float* wa1    = (const float*)d_in[17];
  const float* ba1    = (const float*)d_in[18];
  const float* ws0    = (const float*)d_in[19];
  const float* bs0    = (const float*)d_in[20];
  const float* ws1    = (const float*)d_in[21];
  const float* bs1    = (const float*)d_in[22];
  const float* aff1   = (const float*)d_in[23];
  const float* aff2   = (const float*)d_in[24];
  const float* wc     = (const float*)d_in[25];
  const float* bc     = (const float*)d_in[26];

  float* ws = (float*)d_ws;
  // region sizes (floats)
  const long SZ_BLD = (long)B_ * L_ * D_;       // 6291456
  const long SZ_BLM = (long)B_ * L_ * MEM_;     // 3145728
  const long SZ_BLL = (long)B_ * L_ * L_;       // 2097152
  float* x      = ws;                 // B,L,D ; later [o_ag | o_s]
  float* qbuf   = ws + SZ_BLD;        // q ; later tmpA ; later [g_s | u]
  float* kbuf   = ws + 2 * SZ_BLD;    // k ; later [t | g_ag]
  float* asp    = ws + 3 * SZ_BLD;                       // B,L,64
  float* asps   = ws + 3 * SZ_BLD + (long)B_ * L_ * DK_; // B,L,L ; later S
  float* adj_s  = asps + SZ_BLL;
  float* adj_ag = adj_s + SZ_BLL;
  float* avgH   = adj_ag + SZ_BLL;              // B*L
  float* den_s  = avgH + B_ * L_;
  float* den_ag = den_s + B_ * L_;
  float* klp    = den_ag + B_ * L_;             // B*L
  float* tmpA = qbuf;
  float* g_s  = qbuf;            float* u    = qbuf + SZ_BLM;
  float* t    = kbuf;            float* g_ag = kbuf + SZ_BLM;
  float* S    = asps;
  float* o_ag = x;               float* o_s  = x + SZ_BLM;
  float* dout = (float*)d_out;

  const long sAdj = (long)L_ * L_;   // 65536
  const long sMem = (long)L_ * MEM_; // 98304

  // 1. LayerNorm
  ln_kernel<<<B_ * L_, 256, 0, stream>>>(seq, ln_g, ln_b, x);
  // 2-3. q, k projections
  gemm64<<<dim3(12, 128, 1), 256, 0, stream>>>(x, wq, qbuf, 8192, 768, 768, 0, 0, 0,
                                               nullptr, bq, nullptr, 0, 0);
  gemm64<<<dim3(12, 128, 1), 256, 0, stream>>>(x, wk, kbuf, 8192, 768, 768, 0, 0, 0,
                                               nullptr, bk, nullptr, 0, 0);
  // 4. adj_s (frees qbuf)
  attn_adjs<<<B_ * L_, 256, 0, stream>>>(qbuf, kbuf, srcm, adj_s);
  // 5. asp = mask*(x@wd) + bd
  gemm64<<<dim3(1, 128, 1), 256, 0, stream>>>(x, wd, asp, 8192, 64, 768, 0, 0, 0,
                                              amask, bd, nullptr, 0, 0);
  // 6. tmpA = asp @ Wm[h]  (into qbuf region)
  asp_wm<<<B_ * H_, 256, 0, stream>>>(asp, wm, tmpA);
  // 7. asps_mean (frees kbuf afterwards)
  asps_mean_kernel<<<B_ * 16, 256, 0, stream>>>(tmpA, kbuf, bm, asps);
  // 8. avgH
  avgh_kernel<<<B_, 256, 0, stream>>>(asps, avgH);
  // 9. adj_ag
  adjag_kernel<<<B_ * L_ * L_ / 256, 256, 0, stream>>>(asps, avgH, amask, adjr, adj_ag);
  // 10-11. KL + denoms
  kl_denom<<<B_ * L_, 256, 0, stream>>>(adj_s, adj_ag, klp, den_s, den_ag);
  kl_final<<<1, 256, 0, stream>>>(klp, dout);

  // 12. GCN layers
  for (int li = 0; li < 2; ++li) {
    int Kd = li ? MEM_ : D_;
    const float* inag = li ? o_ag : x;
    const float* ins  = li ? o_s : x;
    const float* wA = li ? wa1 : wa0;
    const float* bA = li ? ba1 : ba0;
    const float* wS = li ? ws1 : ws0;
    const float* bS = li ? bs1 : bs0;
    // t = in_ag @ wA ; g_ag = relu((adj_ag@t + bA)/den_ag)
    gemm64<<<dim3(6, 128, 1), 256, 0, stream>>>(inag, wA, t, 8192, MEM_, Kd, 0, 0, 0,
                                                nullptr, nullptr, nullptr, 0, 0);
    gemm64<<<dim3(6, 4, 32), 256, 0, stream>>>(adj_ag, t, g_ag, L_, MEM_, L_, sAdj, sMem,
                                               sMem, nullptr, bA, den_ag, 1, 0);
    // t = in_s @ wS ; g_s = relu((adj_s@t + bS)/den_s)
    gemm64<<<dim3(6, 128, 1), 256, 0, stream>>>(ins, wS, t, 8192, MEM_, Kd, 0, 0, 0,
                                                nullptr, nullptr, nullptr, 0, 0);
    gemm64<<<dim3(6, 4, 32), 256, 0, stream>>>(adj_s, t, g_s, L_, MEM_, L_, sAdj, sMem,
                                               sMem, nullptr, bS, den_s, 1, 0);
    // A1 = softmax((g_ag@aff1) @ g_s^T) ; o_ag = A1 @ g_s
    gemm64<<<dim3(6, 128, 1), 256, 0, stream>>>(g_ag, aff1, u, 8192, MEM_, MEM_, 0, 0, 0,
                                                nullptr, nullptr, nullptr, 0, 0);
    gemm64<<<dim3(4, 4, 32), 256, 0, stream>>>(u, g_s, S, L_, L_, MEM_, sMem, sMem, sAdj,
                                               nullptr, nullptr, nullptr, 0, 1);
    softmax_rows<<<B_ * L_, 256, 0, stream>>>(S);
    gemm64<<<dim3(6, 4, 32), 256, 0, stream>>>(S, g_s, o_ag, L_, MEM_, L_, sAdj, sMem,
                                               sMem, nullptr, nullptr, nullptr, 0, 0);
    // A2 = softmax((g_s@aff2) @ g_ag^T) ; o_s = A2 @ g_ag
    gemm64<<<dim3(6, 128, 1), 256, 0, stream>>>(g_s, aff2, u, 8192, MEM_, MEM_, 0, 0, 0,
                                                nullptr, nullptr, nullptr, 0, 0);
    gemm64<<<dim3(4, 4, 32), 256, 0, stream>>>(u, g_ag, S, L_, L_, MEM_, sMem, sMem, sAdj,
                                               nullptr, nullptr, nullptr, 0, 1);
    softmax_rows<<<B_ * L_, 256, 0, stream>>>(S);
    gemm64<<<dim3(6, 4, 32), 256, 0, stream>>>(S, g_ag, o_s, L_, MEM_, L_, sAdj, sMem,
                                               sMem, nullptr, nullptr, nullptr, 0, 0);
  }

  // 13. classifier head
  final_kernel<<<B_, 256, 0, stream>>>(o_ag, o_s, pooled, amask, wc, bc, dout);
}

// Round 2
// 1932.237 us; speedup vs baseline: 1.3121x; 1.3121x over previous
//
#include <hip/hip_runtime.h>

#define B_ 32
#define L_ 256
#define D_ 768
#define H_ 12
#define DK_ 64
#define MEM_ 384

// ---------------- block reduce helpers (256 threads = 4 waves) ----------------
__device__ inline float waveRedSum(float v) {
#pragma unroll
  for (int o = 32; o; o >>= 1) v += __shfl_xor(v, o, 64);
  return v;
}
__device__ inline float waveRedMax(float v) {
#pragma unroll
  for (int o = 32; o; o >>= 1) v = fmaxf(v, __shfl_xor(v, o, 64));
  return v;
}
__device__ inline float blkRedSum(float v, float* red) {
  v = waveRedSum(v);
  int w = threadIdx.x >> 6;
  __syncthreads();
  if ((threadIdx.x & 63) == 0) red[w] = v;
  __syncthreads();
  return red[0] + red[1] + red[2] + red[3];
}
__device__ inline float blkRedMax(float v, float* red) {
  v = waveRedMax(v);
  int w = threadIdx.x >> 6;
  __syncthreads();
  if ((threadIdx.x & 63) == 0) red[w] = v;
  __syncthreads();
  return fmaxf(fmaxf(red[0], red[1]), fmaxf(red[2], red[3]));
}

// component select, folds at compile time under full unroll
__device__ inline float comp4(const float4& v, int i) {
  return i == 0 ? v.x : i == 1 ? v.y : i == 2 ? v.z : v.w;
}

// ---------------- LayerNorm (ddof=1 std, (sd+1e-6) denominator) ----------------
__global__ __launch_bounds__(256) void ln_kernel(const float* __restrict__ in,
                                                 const float* __restrict__ g,
                                                 const float* __restrict__ bt,
                                                 float* __restrict__ out) {
  long row = blockIdx.x;
  const float* p = in + row * D_;
  float v[3];
#pragma unroll
  for (int i = 0; i < 3; ++i) v[i] = p[threadIdx.x + i * 256];
  __shared__ float red[4];
  float s = v[0] + v[1] + v[2];
  s = blkRedSum(s, red);
  float mu = s * (1.f / D_);
  float ss = 0.f;
#pragma unroll
  for (int i = 0; i < 3; ++i) { float d = v[i] - mu; ss += d * d; }
  ss = blkRedSum(ss, red);
  float sd = sqrtf(ss * (1.f / (D_ - 1)));
  float inv = 1.f / (sd + 1e-6f);
#pragma unroll
  for (int i = 0; i < 3; ++i) {
    int c = threadIdx.x + i * 256;
    out[row * D_ + c] = g[c] * (v[i] - mu) * inv + bt[c];
  }
}

// ---------------- generic tiled SGEMM, 64x64 tile, 4x4 microtile ----------------
__global__ __launch_bounds__(256) void gemm64(
    const float* __restrict__ A, const float* __restrict__ B, float* __restrict__ C,
    int M, int N, int K, long sA, long sB, long sC,
    const float* __restrict__ rowScale, const float* __restrict__ bias,
    const float* __restrict__ rowDiv, int relu, int transB) {
  const int tid = threadIdx.x;
  const int bn = blockIdx.x, bm = blockIdx.y, bz = blockIdx.z;
  A += (long)bz * sA; B += (long)bz * sB; C += (long)bz * sC;
  __shared__ float As[16][65];
  __shared__ float Bs[16][65];
  float acc[4][4] = {};
  const int tm = tid & 15, tn = tid >> 4;
  for (int k0 = 0; k0 < K; k0 += 16) {
#pragma unroll
    for (int i = 0; i < 4; ++i) {
      int idx = tid + i * 256;
      int r = idx >> 4, c = idx & 15;
      As[c][r] = A[(long)(bm * 64 + r) * K + k0 + c];
    }
    if (!transB) {
#pragma unroll
      for (int i = 0; i < 4; ++i) {
        int idx = tid + i * 256;
        int r = idx >> 6, c = idx & 63;
        Bs[r][c] = B[(long)(k0 + r) * N + bn * 64 + c];
      }
    } else {
#pragma unroll
      for (int i = 0; i < 4; ++i) {
        int idx = tid + i * 256;
        int r = idx >> 4, c = idx & 15;
        Bs[c][r] = B[(long)(bn * 64 + r) * K + k0 + c];
      }
    }
    __syncthreads();
#pragma unroll
    for (int kk = 0; kk < 16; ++kk) {
      float a[4], bb[4];
#pragma unroll
      for (int i = 0; i < 4; ++i) a[i] = As[kk][tm * 4 + i];
#pragma unroll
      for (int j = 0; j < 4; ++j) bb[j] = Bs[kk][tn * 4 + j];
#pragma unroll
      for (int i = 0; i < 4; ++i)
#pragma unroll
        for (int j = 0; j < 4; ++j) acc[i][j] += a[i] * bb[j];
    }
    __syncthreads();
  }
#pragma unroll
  for (int i = 0; i < 4; ++i) {
    int r = bm * 64 + tm * 4 + i;
    long grow = (long)bz * M + r;
    float rs = rowScale ? rowScale[grow] : 1.f;
    float rd = rowDiv ? 1.f / rowDiv[grow] : 1.f;
#pragma unroll
    for (int j = 0; j < 4; ++j) {
      int cn = bn * 64 + tn * 4 + j;
      float v = acc[i][j] * rs;
      if (bias) v += bias[cn];
      v *= rd;
      if (relu) v = fmaxf(v, 0.f);
      C[(long)r * N + cn] = v;
    }
  }
}

// ---------------- fused attention v2: tiled scores + in-wave softmax ----------------
// grid: B*8 blocks; block = (b, rows l0..l0+31, all 256 cols)
// thread: rt = t>>5 (row group, 4 rows), ct = t&31 (cols ct*8..ct*8+7)
__global__ __launch_bounds__(256) void attn_adjs_v2(const float* __restrict__ q,
                                                    const float* __restrict__ k,
                                                    const float* __restrict__ srcm,
                                                    float* __restrict__ adj_s) {
  int blk = blockIdx.x;
  int b = blk >> 3;
  int l0 = (blk & 7) << 5;
  int t = threadIdx.x;
  int rt = t >> 5;
  int ct = t & 31;
  __shared__ float kS[64][260];  // kS[d][m], stride 260 (mult of 4, 4 mod 32)
  __shared__ float qS[32][68];   // qS[r][d]
  float acc[4][8];
#pragma unroll
  for (int i = 0; i < 4; ++i)
#pragma unroll
    for (int j = 0; j < 8; ++j) acc[i][j] = 0.f;
  float cmv[8];
#pragma unroll
  for (int j = 0; j < 8; ++j) cmv[j] = srcm[b * L_ + ct * 8 + j];

  for (int h = 0; h < H_; ++h) {
    __syncthreads();  // previous iteration's readers done
    // kS[d][m] = k[b][m][h*64+d]; thread t owns column m=t
    {
      const float* kp = k + ((long)b * L_ + t) * D_ + h * 64;
#pragma unroll
      for (int i = 0; i < 16; ++i) {
        float4 kv = *(const float4*)(kp + i * 4);
        kS[i * 4 + 0][t] = kv.x;
        kS[i * 4 + 1][t] = kv.y;
        kS[i * 4 + 2][t] = kv.z;
        kS[i * 4 + 3][t] = kv.w;
      }
    }
    // qS[r][d] = q[b][l0+r][h*64+d]
    {
      int r = t >> 3, d0 = (t & 7) * 8;
      const float* qp = q + ((long)b * L_ + l0 + r) * D_ + h * 64 + d0;
      *(float4*)&qS[r][d0] = *(const float4*)qp;
      *(float4*)&qS[r][d0 + 4] = *(const float4*)(qp + 4);
    }
    __syncthreads();

    float s[4][8];
#pragma unroll
    for (int i = 0; i < 4; ++i)
#pragma unroll
      for (int j = 0; j < 8; ++j) s[i][j] = 0.f;

#pragma unroll 4
    for (int d4 = 0; d4 < 16; ++d4) {
      float4 qv[4];
#pragma unroll
      for (int i = 0; i < 4; ++i) qv[i] = *(const float4*)&qS[rt * 4 + i][d4 * 4];
#pragma unroll
      for (int dd = 0; dd < 4; ++dd) {
        float4 ka = *(const float4*)&kS[d4 * 4 + dd][ct * 8];
        float4 kb = *(const float4*)&kS[d4 * 4 + dd][ct * 8 + 4];
#pragma unroll
        for (int i = 0; i < 4; ++i) {
          float qd = comp4(qv[i], dd);
          s[i][0] += qd * ka.x;  s[i][1] += qd * ka.y;
          s[i][2] += qd * ka.z;  s[i][3] += qd * ka.w;
          s[i][4] += qd * kb.x;  s[i][5] += qd * kb.y;
          s[i][6] += qd * kb.z;  s[i][7] += qd * kb.w;
        }
      }
    }

    // per-row softmax, fully in-wave (row group = 32 lanes, xor 1..16 stays inside)
#pragma unroll
    for (int i = 0; i < 4; ++i) {
      float mx = -1e30f;
#pragma unroll
      for (int j = 0; j < 8; ++j) {
        float v = s[i][j] * 0.125f;
        v = (cmv[j] == 0.f) ? -1e9f : v;
        s[i][j] = v;
        mx = fmaxf(mx, v);
      }
#pragma unroll
      for (int o = 1; o < 32; o <<= 1) mx = fmaxf(mx, __shfl_xor(mx, o, 64));
      float sum = 0.f;
#pragma unroll
      for (int j = 0; j < 8; ++j) {
        float e = expf(s[i][j] - mx);
        s[i][j] = e;
        sum += e;
      }
#pragma unroll
      for (int o = 1; o < 32; o <<= 1) sum += __shfl_xor(sum, o, 64);
      float inv = 1.f / sum;
#pragma unroll
      for (int j = 0; j < 8; ++j) acc[i][j] += s[i][j] * inv;
    }
  }

  // epilogue: mean over heads, diag=1, row mask
#pragma unroll
  for (int i = 0; i < 4; ++i) {
    int l = l0 + rt * 4 + i;
    float rm = srcm[b * L_ + l];
#pragma unroll
    for (int j = 0; j < 8; ++j) {
      int m = ct * 8 + j;
      float v = acc[i][j] * (1.f / H_);
      if (m == l) v = 1.f;
      v *= rm;
      adj_s[((long)b * L_ + l) * L_ + m] = v;
    }
  }
}

// ---------------- tmpA[b,h] = asp[b] (L x 64) @ Wm[h] (64 x 64) ----------------
__global__ __launch_bounds__(256) void asp_wm(const float* __restrict__ asp,
                                              const float* __restrict__ wm,
                                              float* __restrict__ tmpA) {
  int bh = blockIdx.x;
  int b = bh / H_, h = bh % H_;
  int t = threadIdx.x;
  __shared__ float WmS[64][64];
  __shared__ float aspS[64][64];
#pragma unroll
  for (int i = 0; i < 16; ++i) {
    int idx = t + i * 256;
    WmS[idx >> 6][idx & 63] = wm[h * 4096 + idx];
  }
  int e = t & 63, lr = t >> 6;
  for (int c = 0; c < 4; ++c) {
    __syncthreads();
#pragma unroll
    for (int i = 0; i < 16; ++i) {
      int idx = t + i * 256;
      aspS[idx >> 6][idx & 63] = asp[((long)b * L_ + c * 64 + (idx >> 6)) * 64 + (idx & 63)];
    }
    __syncthreads();
    for (int s = 0; s < 16; ++s) {
      int ll = s * 4 + lr;
      float accv = 0.f;
#pragma unroll
      for (int d = 0; d < 64; ++d) accv += aspS[ll][d] * WmS[d][e];
      tmpA[(((long)b * H_ + h) * L_ + c * 64 + ll) * 64 + e] = accv;
    }
  }
}

// ---------------- asps_mean[b,l,m] = mean_h tanh(tmpA[b,h,l,:] . k_h[b,m,:] + bias) ----------------
__global__ __launch_bounds__(256) void asps_mean_kernel(const float* __restrict__ tmpA,
                                                        const float* __restrict__ k,
                                                        const float* __restrict__ bias_m,
                                                        float* __restrict__ asps_mean) {
  int blk = blockIdx.x;  // b*16 + chunk
  int b = blk >> 4, l0 = (blk & 15) << 4;
  int m = threadIdx.x;
  float bm = bias_m[0];
  __shared__ float tAs[16][64];
  float acc[16];
#pragma unroll
  for (int i = 0; i < 16; ++i) acc[i] = 0.f;
  for (int h = 0; h < H_; ++h) {
    __syncthreads();
#pragma unroll
    for (int i = 0; i < 4; ++i) {
      int idx = m + i * 256;
      tAs[idx >> 6][idx & 63] =
          tmpA[(((long)b * H_ + h) * L_ + l0 + (idx >> 6)) * 64 + (idx & 63)];
    }
    __syncthreads();
    const float4* k4 = (const float4*)(k + ((long)b * L_ + m) * D_ + h * DK_);
    float4 kr[16];
#pragma unroll
    for (int j = 0; j < 16; ++j) kr[j] = k4[j];
#pragma unroll
    for (int l = 0; l < 16; ++l) {
      float s = 0.f;
#pragma unroll
      for (int j = 0; j < 16; ++j) {
        s += tAs[l][4 * j + 0] * kr[j].x + tAs[l][4 * j + 1] * kr[j].y +
             tAs[l][4 * j + 2] * kr[j].z + tAs[l][4 * j + 3] * kr[j].w;
      }
      acc[l] += tanhf(s + bm);
    }
  }
#pragma unroll
  for (int l = 0; l < 16; ++l)
    asps_mean[((long)b * L_ + l0 + l) * L_ + m] = acc[l] * (1.f / H_);
}

// ---------------- avgH[b,m] = mean_l asps_mean[b,l,m] ----------------
__global__ __launch_bounds__(256) void avgh_kernel(const float* __restrict__ asps_mean,
                                                   float* __restrict__ avgH) {
  int b = blockIdx.x, m = threadIdx.x;
  float s = 0.f;
  for (int l = 0; l < L_; ++l) s += asps_mean[((long)b * L_ + l) * L_ + m];
  avgH[b * L_ + m] = s * (1.f / L_);
}

// ---------------- adj_ag ----------------
__global__ __launch_bounds__(256) void adjag_kernel(const float* __restrict__ asps_mean,
                                                    const float* __restrict__ avgH,
                                                    const float* __restrict__ amask,
                                                    const float* __restrict__ adjr,
                                                    float* __restrict__ adj_ag) {
  long idx = (long)blockIdx.x * 256 + threadIdx.x;
  int m = idx & 255;
  long bl = idx >> 8;
  int l = (int)(bl & 255);
  int b = (int)(bl >> 8);
  bool rowa = amask[b * L_ + l] > 0.f;
  bool cola = amask[b * L_ + m] > 0.f;
  float asa;
  if (rowa && cola) asa = (l >= m) ? avgH[b * L_ + m] : avgH[b * L_ + l];
  else if (rowa)    asa = avgH[b * L_ + m];
  else if (cola)    asa = avgH[b * L_ + l];
  else              asa = asps_mean[idx];
  float r = (asa > 0.25f) ? 1.f : expf(adjr[idx]);  // ALPHA = 1.0
  adj_ag[idx] = r * asa;
}

// ---------------- KL partials + row denominators ----------------
__global__ __launch_bounds__(256) void kl_denom(const float* __restrict__ adj_s,
                                                const float* __restrict__ adj_ag,
                                                float* __restrict__ klpart,
                                                float* __restrict__ den_s,
                                                float* __restrict__ den_ag) {
  long row = blockIdx.x;
  int m = threadIdx.x;
  __shared__ float red[4];
  float s = adj_s[row * L_ + m];
  float a = adj_ag[row * L_ + m];
  float sum_s = blkRedSum(s, red);
  float sum_a = blkRedSum(a, red);
  float mx_s = blkRedMax(s, red);
  float mx_a = blkRedMax(a, red);
  float es = expf(s - mx_s), ea = expf(a - mx_a);
  float ses = blkRedSum(es, red);
  float sea = blkRedSum(ea, red);
  float logq = (s - mx_s) - logf(ses);
  float logp = (a - mx_a) - logf(sea);
  float term = (es / ses) * (logq - logp);
  float kp = blkRedSum(term, red);
  if (m == 0) {
    klpart[row] = kp;
    den_s[row] = sum_s + 1.f;
    den_ag[row] = sum_a + 1.f;
  }
}

__global__ __launch_bounds__(256) void kl_final(const float* __restrict__ klpart,
                                                float* __restrict__ dout) {
  __shared__ float red[4];
  float s = 0.f;
  for (int i = threadIdx.x; i < B_ * L_; i += 256) s += klpart[i];
  s = blkRedSum(s, red);
  if (threadIdx.x == 0) dout[96] = expf(-s * 0.1f);  // GAMA = 0.1
}

// ---------------- in-place row softmax over last dim (256) ----------------
__global__ __launch_bounds__(256) void softmax_rows(float* __restrict__ S) {
  long row = blockIdx.x;
  int m = threadIdx.x;
  __shared__ float red[4];
  float v = S[row * L_ + m];
  float mx = blkRedMax(v, red);
  float e = expf(v - mx);
  float s = blkRedSum(e, red);
  S[row * L_ + m] = e / s;
}

// ---------------- classifier head ----------------
__global__ __launch_bounds__(256) void final_kernel(const float* __restrict__ o_ag,
                                                    const float* __restrict__ o_s,
                                                    const float* __restrict__ pooled,
                                                    const float* __restrict__ amask,
                                                    const float* __restrict__ wc,
                                                    const float* __restrict__ bc,
                                                    float* __restrict__ dout) {
  int b = blockIdx.x, t = threadIdx.x;
  __shared__ float cS[1536];
  __shared__ float maskS[256];
  __shared__ float red[4];
  maskS[t] = amask[b * L_ + t];
  float wn = blkRedSum(maskS[t], red);
  for (int e = t; e < MEM_; e += 256) {
    float s1 = 0.f, s2 = 0.f;
    for (int l = 0; l < L_; ++l) {
      float mk = maskS[l];
      if (mk != 0.f) {
        s1 += mk * o_ag[((long)b * L_ + l) * MEM_ + e];
        s2 += mk * o_s[((long)b * L_ + l) * MEM_ + e];
      }
    }
    cS[e] = s1 / wn;
    cS[MEM_ + e] = s2 / wn;
  }
  for (int j = t; j < D_; j += 256) cS[2 * MEM_ + j] = pooled[b * D_ + j];
  __syncthreads();
  float p0 = 0.f, p1 = 0.f, p2 = 0.f;
  for (int j = t; j < 1536; j += 256) {
    float v = cS[j];
    p0 += v * wc[j * 3 + 0];
    p1 += v * wc[j * 3 + 1];
    p2 += v * wc[j * 3 + 2];
  }
  p0 = blkRedSum(p0, red);
  p1 = blkRedSum(p1, red);
  p2 = blkRedSum(p2, red);
  if (t == 0) {
    dout[b * 3 + 0] = p0 + bc[0];
    dout[b * 3 + 1] = p1 + bc[1];
    dout[b * 3 + 2] = p2 + bc[2];
  }
}

extern "C" void kernel_launch(void* const* d_in, const int* in_sizes, int n_in,
                              void* d_out, int out_size, void* d_ws, size_t ws_size,
                              hipStream_t stream) {
  const float* seq    = (const float*)d_in[0];
  const float* pooled = (const float*)d_in[1];
  const float* adjr   = (const float*)d_in[2];
  const float* srcm   = (const float*)d_in[3];
  const float* amask  = (const float*)d_in[4];
  const float* ln_g   = (const float*)d_in[5];
  const float* ln_b   = (const float*)d_in[6];
  const float* wq     = (const float*)d_in[7];
  const float* bq     = (const float*)d_in[8];
  const float* wk     = (const float*)d_in[9];
  const float* bk     = (const float*)d_in[10];
  const float* wd     = (const float*)d_in[11];
  const float* bd     = (const float*)d_in[12];
  const float* wm     = (const float*)d_in[13];
  const float* bm     = (const float*)d_in[14];
  const float* wa0    = (const float*)d_in[15];
  const float* ba0    = (const float*)d_in[16];
  const float* wa1    = (const float*)d_in[17];
  const float* ba1    = (const float*)d_in[18];
  const float* ws0    = (const float*)d_in[19];
  const float* bs0    = (const float*)d_in[20];
  const float* ws1    = (const float*)d_in[21];
  const float* bs1    = (const float*)d_in[22];
  const float* aff1   = (const float*)d_in[23];
  const float* aff2   = (const float*)d_in[24];
  const float* wc     = (const float*)d_in[25];
  const float* bc     = (const float*)d_in[26];

  float* ws = (float*)d_ws;
  const long SZ_BLD = (long)B_ * L_ * D_;
  const long SZ_BLM = (long)B_ * L_ * MEM_;
  const long SZ_BLL = (long)B_ * L_ * L_;
  float* x      = ws;
  float* qbuf   = ws + SZ_BLD;
  float* kbuf   = ws + 2 * SZ_BLD;
  float* asp    = ws + 3 * SZ_BLD;
  float* asps   = ws + 3 * SZ_BLD + (long)B_ * L_ * DK_;
  float* adj_s  = asps + SZ_BLL;
  float* adj_ag = adj_s + SZ_BLL;
  float* avgH   = adj_ag + SZ_BLL;
  float* den_s  = avgH + B_ * L_;
  float* den_ag = den_s + B_ * L_;
  float* klp    = den_ag + B_ * L_;
  float* tmpA = qbuf;
  float* g_s  = qbuf;            float* u    = qbuf + SZ_BLM;
  float* t    = kbuf;            float* g_ag = kbuf + SZ_BLM;
  float* S    = asps;
  float* o_ag = x;               float* o_s  = x + SZ_BLM;
  float* dout = (float*)d_out;

  const long sAdj = (long)L_ * L_;
  const long sMem = (long)L_ * MEM_;

  ln_kernel<<<B_ * L_, 256, 0, stream>>>(seq, ln_g, ln_b, x);
  gemm64<<<dim3(12, 128, 1), 256, 0, stream>>>(x, wq, qbuf, 8192, 768, 768, 0, 0, 0,
                                               nullptr, bq, nullptr, 0, 0);
  gemm64<<<dim3(12, 128, 1), 256, 0, stream>>>(x, wk, kbuf, 8192, 768, 768, 0, 0, 0,
                                               nullptr, bk, nullptr, 0, 0);
  attn_adjs_v2<<<B_ * 8, 256, 0, stream>>>(qbuf, kbuf, srcm, adj_s);
  gemm64<<<dim3(1, 128, 1), 256, 0, stream>>>(x, wd, asp, 8192, 64, 768, 0, 0, 0,
                                              amask, bd, nullptr, 0, 0);
  asp_wm<<<B_ * H_, 256, 0, stream>>>(asp, wm, tmpA);
  asps_mean_kernel<<<B_ * 16, 256, 0, stream>>>(tmpA, kbuf, bm, asps);
  avgh_kernel<<<B_, 256, 0, stream>>>(asps, avgH);
  adjag_kernel<<<B_ * L_ * L_ / 256, 256, 0, stream>>>(asps, avgH, amask, adjr, adj_ag);
  kl_denom<<<B_ * L_, 256, 0, stream>>>(adj_s, adj_ag, klp, den_s, den_ag);
  kl_final<<<1, 256, 0, stream>>>(klp, dout);

  for (int li = 0; li < 2; ++li) {
    int Kd = li ? MEM_ : D_;
    const float* inag = li ? o_ag : x;
    const float* ins  = li ? o_s : x;
    const float* wA = li ? wa1 : wa0;
    const float* bA = li ? ba1 : ba0;
    const float* wS = li ? ws1 : ws0;
    const float* bS = li ? bs1 : bs0;
    gemm64<<<dim3(6, 128, 1), 256, 0, stream>>>(inag, wA, t, 8192, MEM_, Kd, 0, 0, 0,
                                                nullptr, nullptr, nullptr, 0, 0);
    gemm64<<<dim3(6, 4, 32), 256, 0, stream>>>(adj_ag, t, g_ag, L_, MEM_, L_, sAdj, sMem,
                                               sMem, nullptr, bA, den_ag, 1, 0);
    gemm64<<<dim3(6, 128, 1), 256, 0, stream>>>(ins, wS, t, 8192, MEM_, Kd, 0, 0, 0,
                                                nullptr, nullptr, nullptr, 0, 0);
    gemm64<<<dim3(6, 4, 32), 256, 0, stream>>>(adj_s, t, g_s, L_, MEM_, L_, sAdj, sMem,
                                               sMem, nullptr, bS, den_s, 1, 0);
    gemm64<<<dim3(6, 128, 1), 256, 0, stream>>>(g_ag, aff1, u, 8192, MEM_, MEM_, 0, 0, 0,
                                                nullptr, nullptr, nullptr, 0, 0);
    gemm64<<<dim3(4, 4, 32), 256, 0, stream>>>(u, g_s, S, L_, L_, MEM_, sMem, sMem, sAdj,
                                               nullptr, nullptr, nullptr, 0, 1);
    softmax_rows<<<B_ * L_, 256, 0, stream>>>(S);
    gemm64<<<dim3(6, 4, 32), 256, 0, stream>>>(S, g_s, o_ag, L_, MEM_, L_, sAdj, sMem,
                                               sMem, nullptr, nullptr, nullptr, 0, 0);
    gemm64<<<dim3(6, 128, 1), 256, 0, stream>>>(g_s, aff2, u, 8192, MEM_, MEM_, 0, 0, 0,
                                                nullptr, nullptr, nullptr, 0, 0);
    gemm64<<<dim3(4, 4, 32), 256, 0, stream>>>(u, g_ag, S, L_, L_, MEM_, sMem, sMem, sAdj,
                                               nullptr, nullptr, nullptr, 0, 1);
    softmax_rows<<<B_ * L_, 256, 0, stream>>>(S);
    gemm64<<<dim3(6, 4, 32), 256, 0, stream>>>(S, g_ag, o_s, L_, MEM_, L_, sAdj, sMem,
                                               sMem, nullptr, nullptr, nullptr, 0, 0);
  }

  final_kernel<<<B_, 256, 0, stream>>>(o_ag, o_s, pooled, amask, wc, bc, dout);
}

// Round 3
// 1084.847 us; speedup vs baseline: 2.3370x; 1.7811x over previous
//
#include <hip/hip_runtime.h>

#define B_ 32
#define L_ 256
#define D_ 768
#define H_ 12
#define DK_ 64
#define MEM_ 384

typedef __attribute__((ext_vector_type(8))) short bfrag8;    // 8 bf16 (4 VGPRs)
typedef __attribute__((ext_vector_type(8))) unsigned short us8;
typedef __attribute__((ext_vector_type(4))) float f32x4;

// f32 -> bf16 round-to-nearest-even (finite inputs only)
__device__ inline unsigned short f2bf(float f) {
  unsigned u = __float_as_uint(f);
  return (unsigned short)((u + 0x7fffu + ((u >> 16) & 1u)) >> 16);
}

// ---------------- block reduce helpers (256 threads = 4 waves) ----------------
__device__ inline float waveRedSum(float v) {
#pragma unroll
  for (int o = 32; o; o >>= 1) v += __shfl_xor(v, o, 64);
  return v;
}
__device__ inline float waveRedMax(float v) {
#pragma unroll
  for (int o = 32; o; o >>= 1) v = fmaxf(v, __shfl_xor(v, o, 64));
  return v;
}
__device__ inline float blkRedSum(float v, float* red) {
  v = waveRedSum(v);
  int w = threadIdx.x >> 6;
  __syncthreads();
  if ((threadIdx.x & 63) == 0) red[w] = v;
  __syncthreads();
  return red[0] + red[1] + red[2] + red[3];
}
__device__ inline float blkRedMax(float v, float* red) {
  v = waveRedMax(v);
  int w = threadIdx.x >> 6;
  __syncthreads();
  if ((threadIdx.x & 63) == 0) red[w] = v;
  __syncthreads();
  return fmaxf(fmaxf(red[0], red[1]), fmaxf(red[2], red[3]));
}

__device__ inline float comp4(const float4& v, int i) {
  return i == 0 ? v.x : i == 1 ? v.y : i == 2 ? v.z : v.w;
}

// ---------------- LayerNorm ----------------
__global__ __launch_bounds__(256) void ln_kernel(const float* __restrict__ in,
                                                 const float* __restrict__ g,
                                                 const float* __restrict__ bt,
                                                 float* __restrict__ out) {
  long row = blockIdx.x;
  const float* p = in + row * D_;
  float v[3];
#pragma unroll
  for (int i = 0; i < 3; ++i) v[i] = p[threadIdx.x + i * 256];
  __shared__ float red[4];
  float s = v[0] + v[1] + v[2];
  s = blkRedSum(s, red);
  float mu = s * (1.f / D_);
  float ss = 0.f;
#pragma unroll
  for (int i = 0; i < 3; ++i) { float d = v[i] - mu; ss += d * d; }
  ss = blkRedSum(ss, red);
  float sd = sqrtf(ss * (1.f / (D_ - 1)));
  float inv = 1.f / (sd + 1e-6f);
#pragma unroll
  for (int i = 0; i < 3; ++i) {
    int c = threadIdx.x + i * 256;
    out[row * D_ + c] = g[c] * (v[i] - mu) * inv + bt[c];
  }
}

// ---------------- generic tiled SGEMM (kept for N=64 asp GEMM) ----------------
__global__ __launch_bounds__(256) void gemm64(
    const float* __restrict__ A, const float* __restrict__ B, float* __restrict__ C,
    int M, int N, int K, long sA, long sB, long sC,
    const float* __restrict__ rowScale, const float* __restrict__ bias,
    const float* __restrict__ rowDiv, int relu, int transB) {
  const int tid = threadIdx.x;
  const int bn = blockIdx.x, bm = blockIdx.y, bz = blockIdx.z;
  A += (long)bz * sA; B += (long)bz * sB; C += (long)bz * sC;
  __shared__ float As[16][65];
  __shared__ float Bs[16][65];
  float acc[4][4] = {};
  const int tm = tid & 15, tn = tid >> 4;
  for (int k0 = 0; k0 < K; k0 += 16) {
#pragma unroll
    for (int i = 0; i < 4; ++i) {
      int idx = tid + i * 256;
      int r = idx >> 4, c = idx & 15;
      As[c][r] = A[(long)(bm * 64 + r) * K + k0 + c];
    }
    if (!transB) {
#pragma unroll
      for (int i = 0; i < 4; ++i) {
        int idx = tid + i * 256;
        int r = idx >> 6, c = idx & 63;
        Bs[r][c] = B[(long)(k0 + r) * N + bn * 64 + c];
      }
    } else {
#pragma unroll
      for (int i = 0; i < 4; ++i) {
        int idx = tid + i * 256;
        int r = idx >> 4, c = idx & 15;
        Bs[c][r] = B[(long)(bn * 64 + r) * K + k0 + c];
      }
    }
    __syncthreads();
#pragma unroll
    for (int kk = 0; kk < 16; ++kk) {
      float a[4], bb[4];
#pragma unroll
      for (int i = 0; i < 4; ++i) a[i] = As[kk][tm * 4 + i];
#pragma unroll
      for (int j = 0; j < 4; ++j) bb[j] = Bs[kk][tn * 4 + j];
#pragma unroll
      for (int i = 0; i < 4; ++i)
#pragma unroll
        for (int j = 0; j < 4; ++j) acc[i][j] += a[i] * bb[j];
    }
    __syncthreads();
  }
#pragma unroll
  for (int i = 0; i < 4; ++i) {
    int r = bm * 64 + tm * 4 + i;
    long grow = (long)bz * M + r;
    float rs = rowScale ? rowScale[grow] : 1.f;
    float rd = rowDiv ? 1.f / rowDiv[grow] : 1.f;
#pragma unroll
    for (int j = 0; j < 4; ++j) {
      int cn = bn * 64 + tn * 4 + j;
      float v = acc[i][j] * rs;
      if (bias) v += bias[cn];
      v *= rd;
      if (relu) v = fmaxf(v, 0.f);
      C[(long)r * N + cn] = v;
    }
  }
}

// ---------------- bf16 MFMA GEMM: 128x128 tile, BK=32, 4 waves (2x2), 4x4 frags --------
// f32 global inputs, converted to bf16 (RNE) during LDS staging; f32 accumulate.
// As[r][k] = A[bm*128+r][k0+k]; Bs[n][k] = B-op[k0+k][bn*128+n].
// Requires: M%128==0, N%128==0, K%32==0.
template <int TRANSB>
__global__ __launch_bounds__(256) void gemm_mfma(
    const float* __restrict__ A, const float* __restrict__ B, float* __restrict__ C,
    int M, int N, int K, long sA, long sB, long sC,
    const float* __restrict__ rowScale, const float* __restrict__ bias,
    const float* __restrict__ rowDiv, int relu) {
  const int tid = threadIdx.x;
  const int bn = blockIdx.x, bm = blockIdx.y, bz = blockIdx.z;
  A += (long)bz * sA; B += (long)bz * sB; C += (long)bz * sC;
  __shared__ unsigned short As[128][40];  // pad 32->40 (80B row stride)
  __shared__ unsigned short Bs[128][40];
  f32x4 acc[4][4] = {};

  const int l = tid & 63, w = tid >> 6;
  const int wr = w >> 1, wc = w & 1;
  const int lr = l & 15, kg = (l >> 4) * 8;

  // staging thread coords
  const int ar = tid >> 1, ah = tid & 1;        // A (and trans-B): row, k-half
  const int kp = (tid >> 4) * 2, n8 = (tid & 15) * 8;  // non-trans B: k-pair, n-octet

  for (int k0 = 0; k0 < K; k0 += 32) {
    // ---- stage A tile ----
    {
      const float* src = A + (long)(bm * 128 + ar) * K + k0 + ah * 16;
      float4 f0 = ((const float4*)src)[0];
      float4 f1 = ((const float4*)src)[1];
      float4 f2 = ((const float4*)src)[2];
      float4 f3 = ((const float4*)src)[3];
      us8 v0, v1;
      v0[0] = f2bf(f0.x); v0[1] = f2bf(f0.y); v0[2] = f2bf(f0.z); v0[3] = f2bf(f0.w);
      v0[4] = f2bf(f1.x); v0[5] = f2bf(f1.y); v0[6] = f2bf(f1.z); v0[7] = f2bf(f1.w);
      v1[0] = f2bf(f2.x); v1[1] = f2bf(f2.y); v1[2] = f2bf(f2.z); v1[3] = f2bf(f2.w);
      v1[4] = f2bf(f3.x); v1[5] = f2bf(f3.y); v1[6] = f2bf(f3.z); v1[7] = f2bf(f3.w);
      *(us8*)&As[ar][ah * 16] = v0;
      *(us8*)&As[ar][ah * 16 + 8] = v1;
    }
    // ---- stage B tile ----
    if (TRANSB) {
      const float* src = B + (long)(bn * 128 + ar) * K + k0 + ah * 16;
      float4 f0 = ((const float4*)src)[0];
      float4 f1 = ((const float4*)src)[1];
      float4 f2 = ((const float4*)src)[2];
      float4 f3 = ((const float4*)src)[3];
      us8 v0, v1;
      v0[0] = f2bf(f0.x); v0[1] = f2bf(f0.y); v0[2] = f2bf(f0.z); v0[3] = f2bf(f0.w);
      v0[4] = f2bf(f1.x); v0[5] = f2bf(f1.y); v0[6] = f2bf(f1.z); v0[7] = f2bf(f1.w);
      v1[0] = f2bf(f2.x); v1[1] = f2bf(f2.y); v1[2] = f2bf(f2.z); v1[3] = f2bf(f2.w);
      v1[4] = f2bf(f3.x); v1[5] = f2bf(f3.y); v1[6] = f2bf(f3.z); v1[7] = f2bf(f3.w);
      *(us8*)&Bs[ar][ah * 16] = v0;
      *(us8*)&Bs[ar][ah * 16 + 8] = v1;
    } else {
      const float* s0 = B + (long)(k0 + kp) * N + bn * 128 + n8;
      const float* s1 = s0 + N;
      float4 a0 = ((const float4*)s0)[0];
      float4 a1 = ((const float4*)s0)[1];
      float4 b0 = ((const float4*)s1)[0];
      float4 b1 = ((const float4*)s1)[1];
      float r0[8] = {a0.x, a0.y, a0.z, a0.w, a1.x, a1.y, a1.z, a1.w};
      float r1[8] = {b0.x, b0.y, b0.z, b0.w, b1.x, b1.y, b1.z, b1.w};
#pragma unroll
      for (int j = 0; j < 8; ++j) {
        unsigned pk = (unsigned)f2bf(r0[j]) | ((unsigned)f2bf(r1[j]) << 16);
        *(unsigned*)&Bs[n8 + j][kp] = pk;
      }
    }
    __syncthreads();

    bfrag8 af[4], bf[4];
#pragma unroll
    for (int m = 0; m < 4; ++m) af[m] = *(const bfrag8*)&As[wr * 64 + m * 16 + lr][kg];
#pragma unroll
    for (int n = 0; n < 4; ++n) bf[n] = *(const bfrag8*)&Bs[wc * 64 + n * 16 + lr][kg];
#pragma unroll
    for (int m = 0; m < 4; ++m)
#pragma unroll
      for (int n = 0; n < 4; ++n)
        acc[m][n] = __builtin_amdgcn_mfma_f32_16x16x32_bf16(af[m], bf[n], acc[m][n], 0, 0, 0);
    __syncthreads();
  }

  // ---- epilogue ----
#pragma unroll
  for (int m = 0; m < 4; ++m) {
#pragma unroll
    for (int r = 0; r < 4; ++r) {
      int row = bm * 128 + wr * 64 + m * 16 + (l >> 4) * 4 + r;
      long grow = (long)bz * M + row;
      float rs = rowScale ? rowScale[grow] : 1.f;
      float rd = rowDiv ? 1.f / rowDiv[grow] : 1.f;
#pragma unroll
      for (int n = 0; n < 4; ++n) {
        int col = bn * 128 + wc * 64 + n * 16 + (l & 15);
        float v = acc[m][n][r] * rs;
        if (bias) v += bias[col];
        v *= rd;
        if (relu) v = fmaxf(v, 0.f);
        C[(long)row * N + col] = v;
      }
    }
  }
}

// ---------------- fused attention: tiled scores + in-wave softmax ----------------
__global__ __launch_bounds__(256) void attn_adjs_v2(const float* __restrict__ q,
                                                    const float* __restrict__ k,
                                                    const float* __restrict__ srcm,
                                                    float* __restrict__ adj_s) {
  int blk = blockIdx.x;
  int b = blk >> 3;
  int l0 = (blk & 7) << 5;
  int t = threadIdx.x;
  int rt = t >> 5;
  int ct = t & 31;
  __shared__ float kS[64][260];
  __shared__ float qS[32][68];
  float acc[4][8];
#pragma unroll
  for (int i = 0; i < 4; ++i)
#pragma unroll
    for (int j = 0; j < 8; ++j) acc[i][j] = 0.f;
  float cmv[8];
#pragma unroll
  for (int j = 0; j < 8; ++j) cmv[j] = srcm[b * L_ + ct * 8 + j];

  for (int h = 0; h < H_; ++h) {
    __syncthreads();
    {
      const float* kp = k + ((long)b * L_ + t) * D_ + h * 64;
#pragma unroll
      for (int i = 0; i < 16; ++i) {
        float4 kv = *(const float4*)(kp + i * 4);
        kS[i * 4 + 0][t] = kv.x;
        kS[i * 4 + 1][t] = kv.y;
        kS[i * 4 + 2][t] = kv.z;
        kS[i * 4 + 3][t] = kv.w;
      }
    }
    {
      int r = t >> 3, d0 = (t & 7) * 8;
      const float* qp = q + ((long)b * L_ + l0 + r) * D_ + h * 64 + d0;
      *(float4*)&qS[r][d0] = *(const float4*)qp;
      *(float4*)&qS[r][d0 + 4] = *(const float4*)(qp + 4);
    }
    __syncthreads();

    float s[4][8];
#pragma unroll
    for (int i = 0; i < 4; ++i)
#pragma unroll
      for (int j = 0; j < 8; ++j) s[i][j] = 0.f;

#pragma unroll 4
    for (int d4 = 0; d4 < 16; ++d4) {
      float4 qv[4];
#pragma unroll
      for (int i = 0; i < 4; ++i) qv[i] = *(const float4*)&qS[rt * 4 + i][d4 * 4];
#pragma unroll
      for (int dd = 0; dd < 4; ++dd) {
        float4 ka = *(const float4*)&kS[d4 * 4 + dd][ct * 8];
        float4 kb = *(const float4*)&kS[d4 * 4 + dd][ct * 8 + 4];
#pragma unroll
        for (int i = 0; i < 4; ++i) {
          float qd = comp4(qv[i], dd);
          s[i][0] += qd * ka.x;  s[i][1] += qd * ka.y;
          s[i][2] += qd * ka.z;  s[i][3] += qd * ka.w;
          s[i][4] += qd * kb.x;  s[i][5] += qd * kb.y;
          s[i][6] += qd * kb.z;  s[i][7] += qd * kb.w;
        }
      }
    }

#pragma unroll
    for (int i = 0; i < 4; ++i) {
      float mx = -1e30f;
#pragma unroll
      for (int j = 0; j < 8; ++j) {
        float v = s[i][j] * 0.125f;
        v = (cmv[j] == 0.f) ? -1e9f : v;
        s[i][j] = v;
        mx = fmaxf(mx, v);
      }
#pragma unroll
      for (int o = 1; o < 32; o <<= 1) mx = fmaxf(mx, __shfl_xor(mx, o, 64));
      float sum = 0.f;
#pragma unroll
      for (int j = 0; j < 8; ++j) {
        float e = expf(s[i][j] - mx);
        s[i][j] = e;
        sum += e;
      }
#pragma unroll
      for (int o = 1; o < 32; o <<= 1) sum += __shfl_xor(sum, o, 64);
      float inv = 1.f / sum;
#pragma unroll
      for (int j = 0; j < 8; ++j) acc[i][j] += s[i][j] * inv;
    }
  }

#pragma unroll
  for (int i = 0; i < 4; ++i) {
    int l = l0 + rt * 4 + i;
    float rm = srcm[b * L_ + l];
#pragma unroll
    for (int j = 0; j < 8; ++j) {
      int m = ct * 8 + j;
      float v = acc[i][j] * (1.f / H_);
      if (m == l) v = 1.f;
      v *= rm;
      adj_s[((long)b * L_ + l) * L_ + m] = v;
    }
  }
}

// ---------------- tmpA[b,h] = asp[b] (L x 64) @ Wm[h] (64 x 64) ----------------
__global__ __launch_bounds__(256) void asp_wm(const float* __restrict__ asp,
                                              const float* __restrict__ wm,
                                              float* __restrict__ tmpA) {
  int bh = blockIdx.x;
  int b = bh / H_, h = bh % H_;
  int t = threadIdx.x;
  __shared__ float WmS[64][64];
  __shared__ float aspS[64][64];
#pragma unroll
  for (int i = 0; i < 16; ++i) {
    int idx = t + i * 256;
    WmS[idx >> 6][idx & 63] = wm[h * 4096 + idx];
  }
  int e = t & 63, lr = t >> 6;
  for (int c = 0; c < 4; ++c) {
    __syncthreads();
#pragma unroll
    for (int i = 0; i < 16; ++i) {
      int idx = t + i * 256;
      aspS[idx >> 6][idx & 63] = asp[((long)b * L_ + c * 64 + (idx >> 6)) * 64 + (idx & 63)];
    }
    __syncthreads();
    for (int s = 0; s < 16; ++s) {
      int ll = s * 4 + lr;
      float accv = 0.f;
#pragma unroll
      for (int d = 0; d < 64; ++d) accv += aspS[ll][d] * WmS[d][e];
      tmpA[(((long)b * H_ + h) * L_ + c * 64 + ll) * 64 + e] = accv;
    }
  }
}

// ---------------- asps_mean ----------------
__global__ __launch_bounds__(256) void asps_mean_kernel(const float* __restrict__ tmpA,
                                                        const float* __restrict__ k,
                                                        const float* __restrict__ bias_m,
                                                        float* __restrict__ asps_mean) {
  int blk = blockIdx.x;
  int b = blk >> 4, l0 = (blk & 15) << 4;
  int m = threadIdx.x;
  float bm = bias_m[0];
  __shared__ float tAs[16][64];
  float acc[16];
#pragma unroll
  for (int i = 0; i < 16; ++i) acc[i] = 0.f;
  for (int h = 0; h < H_; ++h) {
    __syncthreads();
#pragma unroll
    for (int i = 0; i < 4; ++i) {
      int idx = m + i * 256;
      tAs[idx >> 6][idx & 63] =
          tmpA[(((long)b * H_ + h) * L_ + l0 + (idx >> 6)) * 64 + (idx & 63)];
    }
    __syncthreads();
    const float4* k4 = (const float4*)(k + ((long)b * L_ + m) * D_ + h * DK_);
    float4 kr[16];
#pragma unroll
    for (int j = 0; j < 16; ++j) kr[j] = k4[j];
#pragma unroll
    for (int l = 0; l < 16; ++l) {
      float s = 0.f;
#pragma unroll
      for (int j = 0; j < 16; ++j) {
        s += tAs[l][4 * j + 0] * kr[j].x + tAs[l][4 * j + 1] * kr[j].y +
             tAs[l][4 * j + 2] * kr[j].z + tAs[l][4 * j + 3] * kr[j].w;
      }
      acc[l] += tanhf(s + bm);
    }
  }
#pragma unroll
  for (int l = 0; l < 16; ++l)
    asps_mean[((long)b * L_ + l0 + l) * L_ + m] = acc[l] * (1.f / H_);
}

// ---------------- avgH ----------------
__global__ __launch_bounds__(256) void avgh_kernel(const float* __restrict__ asps_mean,
                                                   float* __restrict__ avgH) {
  int b = blockIdx.x, m = threadIdx.x;
  float s = 0.f;
  for (int l = 0; l < L_; ++l) s += asps_mean[((long)b * L_ + l) * L_ + m];
  avgH[b * L_ + m] = s * (1.f / L_);
}

// ---------------- adj_ag ----------------
__global__ __launch_bounds__(256) void adjag_kernel(const float* __restrict__ asps_mean,
                                                    const float* __restrict__ avgH,
                                                    const float* __restrict__ amask,
                                                    const float* __restrict__ adjr,
                                                    float* __restrict__ adj_ag) {
  long idx = (long)blockIdx.x * 256 + threadIdx.x;
  int m = idx & 255;
  long bl = idx >> 8;
  int l = (int)(bl & 255);
  int b = (int)(bl >> 8);
  bool rowa = amask[b * L_ + l] > 0.f;
  bool cola = amask[b * L_ + m] > 0.f;
  float asa;
  if (rowa && cola) asa = (l >= m) ? avgH[b * L_ + m] : avgH[b * L_ + l];
  else if (rowa)    asa = avgH[b * L_ + m];
  else if (cola)    asa = avgH[b * L_ + l];
  else              asa = asps_mean[idx];
  float r = (asa > 0.25f) ? 1.f : expf(adjr[idx]);
  adj_ag[idx] = r * asa;
}

// ---------------- KL partials + row denominators ----------------
__global__ __launch_bounds__(256) void kl_denom(const float* __restrict__ adj_s,
                                                const float* __restrict__ adj_ag,
                                                float* __restrict__ klpart,
                                                float* __restrict__ den_s,
                                                float* __restrict__ den_ag) {
  long row = blockIdx.x;
  int m = threadIdx.x;
  __shared__ float red[4];
  float s = adj_s[row * L_ + m];
  float a = adj_ag[row * L_ + m];
  float sum_s = blkRedSum(s, red);
  float sum_a = blkRedSum(a, red);
  float mx_s = blkRedMax(s, red);
  float mx_a = blkRedMax(a, red);
  float es = expf(s - mx_s), ea = expf(a - mx_a);
  float ses = blkRedSum(es, red);
  float sea = blkRedSum(ea, red);
  float logq = (s - mx_s) - logf(ses);
  float logp = (a - mx_a) - logf(sea);
  float term = (es / ses) * (logq - logp);
  float kp = blkRedSum(term, red);
  if (m == 0) {
    klpart[row] = kp;
    den_s[row] = sum_s + 1.f;
    den_ag[row] = sum_a + 1.f;
  }
}

__global__ __launch_bounds__(256) void kl_final(const float* __restrict__ klpart,
                                                float* __restrict__ dout) {
  __shared__ float red[4];
  float s = 0.f;
  for (int i = threadIdx.x; i < B_ * L_; i += 256) s += klpart[i];
  s = blkRedSum(s, red);
  if (threadIdx.x == 0) dout[96] = expf(-s * 0.1f);
}

// ---------------- in-place row softmax ----------------
__global__ __launch_bounds__(256) void softmax_rows(float* __restrict__ S) {
  long row = blockIdx.x;
  int m = threadIdx.x;
  __shared__ float red[4];
  float v = S[row * L_ + m];
  float mx = blkRedMax(v, red);
  float e = expf(v - mx);
  float s = blkRedSum(e, red);
  S[row * L_ + m] = e / s;
}

// ---------------- classifier head ----------------
__global__ __launch_bounds__(256) void final_kernel(const float* __restrict__ o_ag,
                                                    const float* __restrict__ o_s,
                                                    const float* __restrict__ pooled,
                                                    const float* __restrict__ amask,
                                                    const float* __restrict__ wc,
                                                    const float* __restrict__ bc,
                                                    float* __restrict__ dout) {
  int b = blockIdx.x, t = threadIdx.x;
  __shared__ float cS[1536];
  __shared__ float maskS[256];
  __shared__ float red[4];
  maskS[t] = amask[b * L_ + t];
  float wn = blkRedSum(maskS[t], red);
  for (int e = t; e < MEM_; e += 256) {
    float s1 = 0.f, s2 = 0.f;
    for (int l = 0; l < L_; ++l) {
      float mk = maskS[l];
      if (mk != 0.f) {
        s1 += mk * o_ag[((long)b * L_ + l) * MEM_ + e];
        s2 += mk * o_s[((long)b * L_ + l) * MEM_ + e];
      }
    }
    cS[e] = s1 / wn;
    cS[MEM_ + e] = s2 / wn;
  }
  for (int j = t; j < D_; j += 256) cS[2 * MEM_ + j] = pooled[b * D_ + j];
  __syncthreads();
  float p0 = 0.f, p1 = 0.f, p2 = 0.f;
  for (int j = t; j < 1536; j += 256) {
    float v = cS[j];
    p0 += v * wc[j * 3 + 0];
    p1 += v * wc[j * 3 + 1];
    p2 += v * wc[j * 3 + 2];
  }
  p0 = blkRedSum(p0, red);
  p1 = blkRedSum(p1, red);
  p2 = blkRedSum(p2, red);
  if (t == 0) {
    dout[b * 3 + 0] = p0 + bc[0];
    dout[b * 3 + 1] = p1 + bc[1];
    dout[b * 3 + 2] = p2 + bc[2];
  }
}

extern "C" void kernel_launch(void* const* d_in, const int* in_sizes, int n_in,
                              void* d_out, int out_size, void* d_ws, size_t ws_size,
                              hipStream_t stream) {
  const float* seq    = (const float*)d_in[0];
  const float* pooled = (const float*)d_in[1];
  const float* adjr   = (const float*)d_in[2];
  const float* srcm   = (const float*)d_in[3];
  const float* amask  = (const float*)d_in[4];
  const float* ln_g   = (const float*)d_in[5];
  const float* ln_b   = (const float*)d_in[6];
  const float* wq     = (const float*)d_in[7];
  const float* bq     = (const float*)d_in[8];
  const float* wk     = (const float*)d_in[9];
  const float* bk     = (const float*)d_in[10];
  const float* wd     = (const float*)d_in[11];
  const float* bd     = (const float*)d_in[12];
  const float* wm     = (const float*)d_in[13];
  const float* bm     = (const float*)d_in[14];
  const float* wa0    = (const float*)d_in[15];
  const float* ba0    = (const float*)d_in[16];
  const float* wa1    = (const float*)d_in[17];
  const float* ba1    = (const float*)d_in[18];
  const float* ws0    = (const float*)d_in[19];
  const float* bs0    = (const float*)d_in[20];
  const float* ws1    = (const float*)d_in[21];
  const float* bs1    = (const float*)d_in[22];
  const float* aff1   = (const float*)d_in[23];
  const float* aff2   = (const float*)d_in[24];
  const float* wc     = (const float*)d_in[25];
  const float* bc     = (const float*)d_in[26];

  float* ws = (float*)d_ws;
  const long SZ_BLD = (long)B_ * L_ * D_;
  const long SZ_BLM = (long)B_ * L_ * MEM_;
  const long SZ_BLL = (long)B_ * L_ * L_;
  float* x      = ws;
  float* qbuf   = ws + SZ_BLD;
  float* kbuf   = ws + 2 * SZ_BLD;
  float* asp    = ws + 3 * SZ_BLD;
  float* asps   = ws + 3 * SZ_BLD + (long)B_ * L_ * DK_;
  float* adj_s  = asps + SZ_BLL;
  float* adj_ag = adj_s + SZ_BLL;
  float* avgH   = adj_ag + SZ_BLL;
  float* den_s  = avgH + B_ * L_;
  float* den_ag = den_s + B_ * L_;
  float* klp    = den_ag + B_ * L_;
  float* tmpA = qbuf;
  float* g_s  = qbuf;            float* u    = qbuf + SZ_BLM;
  float* t    = kbuf;            float* g_ag = kbuf + SZ_BLM;
  float* S    = asps;
  float* o_ag = x;               float* o_s  = x + SZ_BLM;
  float* dout = (float*)d_out;

  const long sAdj = (long)L_ * L_;
  const long sMem = (long)L_ * MEM_;

  ln_kernel<<<B_ * L_, 256, 0, stream>>>(seq, ln_g, ln_b, x);
  gemm_mfma<0><<<dim3(6, 64, 1), 256, 0, stream>>>(x, wq, qbuf, 8192, 768, 768, 0, 0, 0,
                                                   nullptr, bq, nullptr, 0);
  gemm_mfma<0><<<dim3(6, 64, 1), 256, 0, stream>>>(x, wk, kbuf, 8192, 768, 768, 0, 0, 0,
                                                   nullptr, bk, nullptr, 0);
  attn_adjs_v2<<<B_ * 8, 256, 0, stream>>>(qbuf, kbuf, srcm, adj_s);
  gemm64<<<dim3(1, 128, 1), 256, 0, stream>>>(x, wd, asp, 8192, 64, 768, 0, 0, 0,
                                              amask, bd, nullptr, 0, 0);
  asp_wm<<<B_ * H_, 256, 0, stream>>>(asp, wm, tmpA);
  asps_mean_kernel<<<B_ * 16, 256, 0, stream>>>(tmpA, kbuf, bm, asps);
  avgh_kernel<<<B_, 256, 0, stream>>>(asps, avgH);
  adjag_kernel<<<B_ * L_ * L_ / 256, 256, 0, stream>>>(asps, avgH, amask, adjr, adj_ag);
  kl_denom<<<B_ * L_, 256, 0, stream>>>(adj_s, adj_ag, klp, den_s, den_ag);
  kl_final<<<1, 256, 0, stream>>>(klp, dout);

  for (int li = 0; li < 2; ++li) {
    int Kd = li ? MEM_ : D_;
    const float* inag = li ? o_ag : x;
    const float* ins  = li ? o_s : x;
    const float* wA = li ? wa1 : wa0;
    const float* bA = li ? ba1 : ba0;
    const float* wS = li ? ws1 : ws0;
    const float* bS = li ? bs1 : bs0;
    gemm_mfma<0><<<dim3(3, 64, 1), 256, 0, stream>>>(inag, wA, t, 8192, MEM_, Kd, 0, 0, 0,
                                                     nullptr, nullptr, nullptr, 0);
    gemm_mfma<0><<<dim3(3, 2, 32), 256, 0, stream>>>(adj_ag, t, g_ag, L_, MEM_, L_, sAdj,
                                                     sMem, sMem, nullptr, bA, den_ag, 1);
    gemm_mfma<0><<<dim3(3, 64, 1), 256, 0, stream>>>(ins, wS, t, 8192, MEM_, Kd, 0, 0, 0,
                                                     nullptr, nullptr, nullptr, 0);
    gemm_mfma<0><<<dim3(3, 2, 32), 256, 0, stream>>>(adj_s, t, g_s, L_, MEM_, L_, sAdj,
                                                     sMem, sMem, nullptr, bS, den_s, 1);
    gemm_mfma<0><<<dim3(3, 64, 1), 256, 0, stream>>>(g_ag, aff1, u, 8192, MEM_, MEM_, 0, 0,
                                                     0, nullptr, nullptr, nullptr, 0);
    gemm_mfma<1><<<dim3(2, 2, 32), 256, 0, stream>>>(u, g_s, S, L_, L_, MEM_, sMem, sMem,
                                                     sAdj, nullptr, nullptr, nullptr, 0);
    softmax_rows<<<B_ * L_, 256, 0, stream>>>(S);
    gemm_mfma<0><<<dim3(3, 2, 32), 256, 0, stream>>>(S, g_s, o_ag, L_, MEM_, L_, sAdj,
                                                     sMem, sMem, nullptr, nullptr, nullptr, 0);
    gemm_mfma<0><<<dim3(3, 64, 1), 256, 0, stream>>>(g_s, aff2, u, 8192, MEM_, MEM_, 0, 0,
                                                     0, nullptr, nullptr, nullptr, 0);
    gemm_mfma<1><<<dim3(2, 2, 32), 256, 0, stream>>>(u, g_ag, S, L_, L_, MEM_, sMem, sMem,
                                                     sAdj, nullptr, nullptr, nullptr, 0);
    softmax_rows<<<B_ * L_, 256, 0, stream>>>(S);
    gemm_mfma<0><<<dim3(3, 2, 32), 256, 0, stream>>>(S, g_ag, o_s, L_, MEM_, L_, sAdj,
                                                     sMem, sMem, nullptr, nullptr, nullptr, 0);
  }

  final_kernel<<<B_, 256, 0, stream>>>(o_ag, o_s, pooled, amask, wc, bc, dout);
}

// Round 4
// 851.719 us; speedup vs baseline: 2.9767x; 1.2737x over previous
//
#include <hip/hip_runtime.h>

#define B_ 32
#define L_ 256
#define D_ 768
#define H_ 12
#define DK_ 64
#define MEM_ 384

typedef __attribute__((ext_vector_type(8))) short bfrag8;    // 8 bf16 (4 VGPRs)
typedef __attribute__((ext_vector_type(8))) unsigned short us8;
typedef __attribute__((ext_vector_type(4))) float f32x4;

// f32 -> bf16 round-to-nearest-even (finite inputs only)
__device__ inline unsigned short f2bf(float f) {
  unsigned u = __float_as_uint(f);
  return (unsigned short)((u + 0x7fffu + ((u >> 16) & 1u)) >> 16);
}
__device__ inline float bf2f(unsigned short u) {
  return __uint_as_float(((unsigned)u) << 16);
}
__device__ inline float tanh_fast(float x) {
  x = fminf(fmaxf(x, -30.f), 30.f);
  float e = __expf(2.f * x);
  return (e - 1.f) * __builtin_amdgcn_rcpf(e + 1.f);
}

// ---------------- block reduce helpers (256 threads = 4 waves) ----------------
__device__ inline float waveRedSum(float v) {
#pragma unroll
  for (int o = 32; o; o >>= 1) v += __shfl_xor(v, o, 64);
  return v;
}
__device__ inline float waveRedMax(float v) {
#pragma unroll
  for (int o = 32; o; o >>= 1) v = fmaxf(v, __shfl_xor(v, o, 64));
  return v;
}
__device__ inline float blkRedSum(float v, float* red) {
  v = waveRedSum(v);
  int w = threadIdx.x >> 6;
  __syncthreads();
  if ((threadIdx.x & 63) == 0) red[w] = v;
  __syncthreads();
  return red[0] + red[1] + red[2] + red[3];
}
__device__ inline float blkRedMax(float v, float* red) {
  v = waveRedMax(v);
  int w = threadIdx.x >> 6;
  __syncthreads();
  if ((threadIdx.x & 63) == 0) red[w] = v;
  __syncthreads();
  return fmaxf(fmaxf(red[0], red[1]), fmaxf(red[2], red[3]));
}

__device__ inline float comp4(const float4& v, int i) {
  return i == 0 ? v.x : i == 1 ? v.y : i == 2 ? v.z : v.w;
}

// ---------------- LayerNorm ----------------
__global__ __launch_bounds__(256) void ln_kernel(const float* __restrict__ in,
                                                 const float* __restrict__ g,
                                                 const float* __restrict__ bt,
                                                 float* __restrict__ out) {
  long row = blockIdx.x;
  const float* p = in + row * D_;
  float v[3];
#pragma unroll
  for (int i = 0; i < 3; ++i) v[i] = p[threadIdx.x + i * 256];
  __shared__ float red[4];
  float s = v[0] + v[1] + v[2];
  s = blkRedSum(s, red);
  float mu = s * (1.f / D_);
  float ss = 0.f;
#pragma unroll
  for (int i = 0; i < 3; ++i) { float d = v[i] - mu; ss += d * d; }
  ss = blkRedSum(ss, red);
  float sd = sqrtf(ss * (1.f / (D_ - 1)));
  float inv = 1.f / (sd + 1e-6f);
#pragma unroll
  for (int i = 0; i < 3; ++i) {
    int c = threadIdx.x + i * 256;
    out[row * D_ + c] = g[c] * (v[i] - mu) * inv + bt[c];
  }
}

// ---------------- generic tiled SGEMM (kept for N=64 asp GEMM) ----------------
__global__ __launch_bounds__(256) void gemm64(
    const float* __restrict__ A, const float* __restrict__ B, float* __restrict__ C,
    int M, int N, int K, long sA, long sB, long sC,
    const float* __restrict__ rowScale, const float* __restrict__ bias,
    const float* __restrict__ rowDiv, int relu, int transB) {
  const int tid = threadIdx.x;
  const int bn = blockIdx.x, bm = blockIdx.y, bz = blockIdx.z;
  A += (long)bz * sA; B += (long)bz * sB; C += (long)bz * sC;
  __shared__ float As[16][65];
  __shared__ float Bs[16][65];
  float acc[4][4] = {};
  const int tm = tid & 15, tn = tid >> 4;
  for (int k0 = 0; k0 < K; k0 += 16) {
#pragma unroll
    for (int i = 0; i < 4; ++i) {
      int idx = tid + i * 256;
      int r = idx >> 4, c = idx & 15;
      As[c][r] = A[(long)(bm * 64 + r) * K + k0 + c];
    }
    if (!transB) {
#pragma unroll
      for (int i = 0; i < 4; ++i) {
        int idx = tid + i * 256;
        int r = idx >> 6, c = idx & 63;
        Bs[r][c] = B[(long)(k0 + r) * N + bn * 64 + c];
      }
    } else {
#pragma unroll
      for (int i = 0; i < 4; ++i) {
        int idx = tid + i * 256;
        int r = idx >> 4, c = idx & 15;
        Bs[c][r] = B[(long)(bn * 64 + r) * K + k0 + c];
      }
    }
    __syncthreads();
#pragma unroll
    for (int kk = 0; kk < 16; ++kk) {
      float a[4], bb[4];
#pragma unroll
      for (int i = 0; i < 4; ++i) a[i] = As[kk][tm * 4 + i];
#pragma unroll
      for (int j = 0; j < 4; ++j) bb[j] = Bs[kk][tn * 4 + j];
#pragma unroll
      for (int i = 0; i < 4; ++i)
#pragma unroll
        for (int j = 0; j < 4; ++j) acc[i][j] += a[i] * bb[j];
    }
    __syncthreads();
  }
#pragma unroll
  for (int i = 0; i < 4; ++i) {
    int r = bm * 64 + tm * 4 + i;
    long grow = (long)bz * M + r;
    float rs = rowScale ? rowScale[grow] : 1.f;
    float rd = rowDiv ? 1.f / rowDiv[grow] : 1.f;
#pragma unroll
    for (int j = 0; j < 4; ++j) {
      int cn = bn * 64 + tn * 4 + j;
      float v = acc[i][j] * rs;
      if (bias) v += bias[cn];
      v *= rd;
      if (relu) v = fmaxf(v, 0.f);
      C[(long)r * N + cn] = v;
    }
  }
}

// ---------------- bf16 MFMA GEMM: 128x128 tile, BK=32, 4 waves (2x2), 4x4 frags --------
// Optional bf16 output (Cbf); optional second operand set (z >= zsplit) for
// pairing two independent same-shape GEMMs in one dispatch.
template <int TRANSB>
__global__ __launch_bounds__(256) void gemm_mfma(
    const float* __restrict__ A, const float* __restrict__ B, float* __restrict__ C,
    int M, int N, int K, long sA, long sB, long sC,
    const float* __restrict__ bias, const float* __restrict__ rowDiv, int relu,
    unsigned short* __restrict__ Cbf,
    const float* __restrict__ A2, const float* __restrict__ B2, float* __restrict__ C2,
    const float* __restrict__ bias2, const float* __restrict__ rowDiv2, int zsplit) {
  const int tid = threadIdx.x;
  const int bn = blockIdx.x, bm = blockIdx.y;
  int bz = blockIdx.z;
  const float* Ap = A; const float* Bp = B; float* Cp = C;
  const float* biasp = bias; const float* rowDivp = rowDiv;
  if (zsplit > 0 && bz >= zsplit) {
    bz -= zsplit;
    Ap = A2; Bp = B2; Cp = C2; biasp = bias2; rowDivp = rowDiv2;
  }
  Ap += (long)bz * sA; Bp += (long)bz * sB;
  if (Cp) Cp += (long)bz * sC;
  __shared__ unsigned short As[128][40];  // pad 32->40 (80B row stride)
  __shared__ unsigned short Bs[128][40];
  f32x4 acc[4][4] = {};

  const int l = tid & 63, w = tid >> 6;
  const int wr = w >> 1, wc = w & 1;
  const int lr = l & 15, kg = (l >> 4) * 8;

  const int ar = tid >> 1, ah = tid & 1;
  const int kp = (tid >> 4) * 2, n8 = (tid & 15) * 8;

  for (int k0 = 0; k0 < K; k0 += 32) {
    {
      const float* src = Ap + (long)(bm * 128 + ar) * K + k0 + ah * 16;
      float4 f0 = ((const float4*)src)[0];
      float4 f1 = ((const float4*)src)[1];
      float4 f2 = ((const float4*)src)[2];
      float4 f3 = ((const float4*)src)[3];
      us8 v0, v1;
      v0[0] = f2bf(f0.x); v0[1] = f2bf(f0.y); v0[2] = f2bf(f0.z); v0[3] = f2bf(f0.w);
      v0[4] = f2bf(f1.x); v0[5] = f2bf(f1.y); v0[6] = f2bf(f1.z); v0[7] = f2bf(f1.w);
      v1[0] = f2bf(f2.x); v1[1] = f2bf(f2.y); v1[2] = f2bf(f2.z); v1[3] = f2bf(f2.w);
      v1[4] = f2bf(f3.x); v1[5] = f2bf(f3.y); v1[6] = f2bf(f3.z); v1[7] = f2bf(f3.w);
      *(us8*)&As[ar][ah * 16] = v0;
      *(us8*)&As[ar][ah * 16 + 8] = v1;
    }
    if (TRANSB) {
      const float* src = Bp + (long)(bn * 128 + ar) * K + k0 + ah * 16;
      float4 f0 = ((const float4*)src)[0];
      float4 f1 = ((const float4*)src)[1];
      float4 f2 = ((const float4*)src)[2];
      float4 f3 = ((const float4*)src)[3];
      us8 v0, v1;
      v0[0] = f2bf(f0.x); v0[1] = f2bf(f0.y); v0[2] = f2bf(f0.z); v0[3] = f2bf(f0.w);
      v0[4] = f2bf(f1.x); v0[5] = f2bf(f1.y); v0[6] = f2bf(f1.z); v0[7] = f2bf(f1.w);
      v1[0] = f2bf(f2.x); v1[1] = f2bf(f2.y); v1[2] = f2bf(f2.z); v1[3] = f2bf(f2.w);
      v1[4] = f2bf(f3.x); v1[5] = f2bf(f3.y); v1[6] = f2bf(f3.z); v1[7] = f2bf(f3.w);
      *(us8*)&Bs[ar][ah * 16] = v0;
      *(us8*)&Bs[ar][ah * 16 + 8] = v1;
    } else {
      const float* s0 = Bp + (long)(k0 + kp) * N + bn * 128 + n8;
      const float* s1 = s0 + N;
      float4 a0 = ((const float4*)s0)[0];
      float4 a1 = ((const float4*)s0)[1];
      float4 b0 = ((const float4*)s1)[0];
      float4 b1 = ((const float4*)s1)[1];
      float r0[8] = {a0.x, a0.y, a0.z, a0.w, a1.x, a1.y, a1.z, a1.w};
      float r1[8] = {b0.x, b0.y, b0.z, b0.w, b1.x, b1.y, b1.z, b1.w};
#pragma unroll
      for (int j = 0; j < 8; ++j) {
        unsigned pk = (unsigned)f2bf(r0[j]) | ((unsigned)f2bf(r1[j]) << 16);
        *(unsigned*)&Bs[n8 + j][kp] = pk;
      }
    }
    __syncthreads();

    bfrag8 af[4], bf[4];
#pragma unroll
    for (int m = 0; m < 4; ++m) af[m] = *(const bfrag8*)&As[wr * 64 + m * 16 + lr][kg];
#pragma unroll
    for (int n = 0; n < 4; ++n) bf[n] = *(const bfrag8*)&Bs[wc * 64 + n * 16 + lr][kg];
#pragma unroll
    for (int m = 0; m < 4; ++m)
#pragma unroll
      for (int n = 0; n < 4; ++n)
        acc[m][n] = __builtin_amdgcn_mfma_f32_16x16x32_bf16(af[m], bf[n], acc[m][n], 0, 0, 0);
    __syncthreads();
  }

#pragma unroll
  for (int m = 0; m < 4; ++m) {
#pragma unroll
    for (int r = 0; r < 4; ++r) {
      int row = bm * 128 + wr * 64 + m * 16 + (l >> 4) * 4 + r;
      long grow = (long)bz * M + row;
      float rd = rowDivp ? 1.f / rowDivp[grow] : 1.f;
#pragma unroll
      for (int n = 0; n < 4; ++n) {
        int col = bn * 128 + wc * 64 + n * 16 + (l & 15);
        float v = acc[m][n][r];
        if (biasp) v += biasp[col];
        v *= rd;
        if (relu) v = fmaxf(v, 0.f);
        if (Cp) Cp[(long)row * N + col] = v;
        if (Cbf) Cbf[(long)row * N + col] = f2bf(v);
      }
    }
  }
}

// ---------------- fused attention: tiled scores + in-wave softmax (bf16 k) --------
__global__ __launch_bounds__(256) void attn_adjs_v2(const float* __restrict__ q,
                                                    const unsigned short* __restrict__ kbf,
                                                    const float* __restrict__ srcm,
                                                    float* __restrict__ adj_s) {
  int blk = blockIdx.x;
  int b = blk >> 3;
  int l0 = (blk & 7) << 5;
  int t = threadIdx.x;
  int rt = t >> 5;
  int ct = t & 31;
  __shared__ float kS[64][260];
  __shared__ float qS[32][68];
  float acc[4][8];
#pragma unroll
  for (int i = 0; i < 4; ++i)
#pragma unroll
    for (int j = 0; j < 8; ++j) acc[i][j] = 0.f;
  float cmv[8];
#pragma unroll
  for (int j = 0; j < 8; ++j) cmv[j] = srcm[b * L_ + ct * 8 + j];

  for (int h = 0; h < H_; ++h) {
    __syncthreads();
    {
      const unsigned short* kp = kbf + ((long)b * L_ + t) * D_ + h * 64;
#pragma unroll
      for (int i = 0; i < 8; ++i) {
        us8 kv = *(const us8*)(kp + i * 8);
#pragma unroll
        for (int j = 0; j < 8; ++j) kS[i * 8 + j][t] = bf2f(kv[j]);
      }
    }
    {
      int r = t >> 3, d0 = (t & 7) * 8;
      const float* qp = q + ((long)b * L_ + l0 + r) * D_ + h * 64 + d0;
      *(float4*)&qS[r][d0] = *(const float4*)qp;
      *(float4*)&qS[r][d0 + 4] = *(const float4*)(qp + 4);
    }
    __syncthreads();

    float s[4][8];
#pragma unroll
    for (int i = 0; i < 4; ++i)
#pragma unroll
      for (int j = 0; j < 8; ++j) s[i][j] = 0.f;

#pragma unroll 4
    for (int d4 = 0; d4 < 16; ++d4) {
      float4 qv[4];
#pragma unroll
      for (int i = 0; i < 4; ++i) qv[i] = *(const float4*)&qS[rt * 4 + i][d4 * 4];
#pragma unroll
      for (int dd = 0; dd < 4; ++dd) {
        float4 ka = *(const float4*)&kS[d4 * 4 + dd][ct * 8];
        float4 kb = *(const float4*)&kS[d4 * 4 + dd][ct * 8 + 4];
#pragma unroll
        for (int i = 0; i < 4; ++i) {
          float qd = comp4(qv[i], dd);
          s[i][0] += qd * ka.x;  s[i][1] += qd * ka.y;
          s[i][2] += qd * ka.z;  s[i][3] += qd * ka.w;
          s[i][4] += qd * kb.x;  s[i][5] += qd * kb.y;
          s[i][6] += qd * kb.z;  s[i][7] += qd * kb.w;
        }
      }
    }

#pragma unroll
    for (int i = 0; i < 4; ++i) {
      float mx = -1e30f;
#pragma unroll
      for (int j = 0; j < 8; ++j) {
        float v = s[i][j] * 0.125f;
        v = (cmv[j] == 0.f) ? -1e9f : v;
        s[i][j] = v;
        mx = fmaxf(mx, v);
      }
#pragma unroll
      for (int o = 1; o < 32; o <<= 1) mx = fmaxf(mx, __shfl_xor(mx, o, 64));
      float sum = 0.f;
#pragma unroll
      for (int j = 0; j < 8; ++j) {
        float e = expf(s[i][j] - mx);
        s[i][j] = e;
        sum += e;
      }
#pragma unroll
      for (int o = 1; o < 32; o <<= 1) sum += __shfl_xor(sum, o, 64);
      float inv = 1.f / sum;
#pragma unroll
      for (int j = 0; j < 8; ++j) acc[i][j] += s[i][j] * inv;
    }
  }

#pragma unroll
  for (int i = 0; i < 4; ++i) {
    int l = l0 + rt * 4 + i;
    float rm = srcm[b * L_ + l];
#pragma unroll
    for (int j = 0; j < 8; ++j) {
      int m = ct * 8 + j;
      float v = acc[i][j] * (1.f / H_);
      if (m == l) v = 1.f;
      v *= rm;
      adj_s[((long)b * L_ + l) * L_ + m] = v;
    }
  }
}

// ---------------- tmpA[b,h] = asp[b] (L x 64) @ Wm[h] (64 x 64), bf16 out ----------------
__global__ __launch_bounds__(256) void asp_wm(const float* __restrict__ asp,
                                              const float* __restrict__ wm,
                                              unsigned short* __restrict__ tmpA) {
  int bh = blockIdx.x;
  int b = bh / H_, h = bh % H_;
  int t = threadIdx.x;
  __shared__ float WmS[64][64];
  __shared__ float aspS[64][64];
#pragma unroll
  for (int i = 0; i < 16; ++i) {
    int idx = t + i * 256;
    WmS[idx >> 6][idx & 63] = wm[h * 4096 + idx];
  }
  int e = t & 63, lr = t >> 6;
  for (int c = 0; c < 4; ++c) {
    __syncthreads();
#pragma unroll
    for (int i = 0; i < 16; ++i) {
      int idx = t + i * 256;
      aspS[idx >> 6][idx & 63] = asp[((long)b * L_ + c * 64 + (idx >> 6)) * 64 + (idx & 63)];
    }
    __syncthreads();
    for (int s = 0; s < 16; ++s) {
      int ll = s * 4 + lr;
      float accv = 0.f;
#pragma unroll
      for (int d = 0; d < 64; ++d) accv += aspS[ll][d] * WmS[d][e];
      tmpA[(((long)b * H_ + h) * L_ + c * 64 + ll) * 64 + e] = f2bf(accv);
    }
  }
}

// ---------------- asps_mean via MFMA: one block = (b, 16 rows, all 256 cols) ----------
// asps_mean[b,l,m] = mean_h tanh(tmpA[b,h,l,:] . kbf[b,m,h*64:h*64+64] + bias)
__global__ __launch_bounds__(256) void asps_mean_v2(
    const unsigned short* __restrict__ tmpA,  // bf16 [B,H,L,64]
    const unsigned short* __restrict__ kbf,   // bf16 [B,L,768]
    const float* __restrict__ bias_m,
    float* __restrict__ asps_mean) {
  int blk = blockIdx.x;  // b*16 + rowtile
  int b = blk >> 4, l0 = (blk & 15) << 4;
  int t = threadIdx.x;
  int w = t >> 6, l = t & 63;
  int lr = l & 15, kg = (l >> 4) * 8;
  float bm = bias_m[0];
  float accg[4][4] = {};
  for (int h = 0; h < H_; ++h) {
    const unsigned short* ap = tmpA + (((long)b * H_ + h) * L_ + l0 + lr) * 64 + kg;
    bfrag8 af0 = *(const bfrag8*)ap;
    bfrag8 af1 = *(const bfrag8*)(ap + 32);
#pragma unroll
    for (int ct = 0; ct < 4; ++ct) {
      const unsigned short* bp =
          kbf + ((long)b * L_ + w * 64 + ct * 16 + lr) * D_ + h * 64 + kg;
      bfrag8 bf0 = *(const bfrag8*)bp;
      bfrag8 bf1 = *(const bfrag8*)(bp + 32);
      f32x4 accl = {};
      accl = __builtin_amdgcn_mfma_f32_16x16x32_bf16(af0, bf0, accl, 0, 0, 0);
      accl = __builtin_amdgcn_mfma_f32_16x16x32_bf16(af1, bf1, accl, 0, 0, 0);
#pragma unroll
      for (int r = 0; r < 4; ++r) accg[ct][r] += tanh_fast(accl[r] + bm);
    }
  }
#pragma unroll
  for (int ct = 0; ct < 4; ++ct) {
    int col = w * 64 + ct * 16 + lr;
#pragma unroll
    for (int r = 0; r < 4; ++r) {
      int row = l0 + (l >> 4) * 4 + r;
      asps_mean[((long)b * L_ + row) * L_ + col] = accg[ct][r] * (1.f / H_);
    }
  }
}

// ---------------- avgH ----------------
__global__ __launch_bounds__(256) void avgh_kernel(const float* __restrict__ asps_mean,
                                                   float* __restrict__ avgH) {
  int b = blockIdx.x, m = threadIdx.x;
  float s = 0.f;
  for (int l = 0; l < L_; ++l) s += asps_mean[((long)b * L_ + l) * L_ + m];
  avgH[b * L_ + m] = s * (1.f / L_);
}

// ---------------- adj_ag ----------------
__global__ __launch_bounds__(256) void adjag_kernel(const float* __restrict__ asps_mean,
                                                    const float* __restrict__ avgH,
                                                    const float* __restrict__ amask,
                                                    const float* __restrict__ adjr,
                                                    float* __restrict__ adj_ag) {
  long idx = (long)blockIdx.x * 256 + threadIdx.x;
  int m = idx & 255;
  long bl = idx >> 8;
  int l = (int)(bl & 255);
  int b = (int)(bl >> 8);
  bool rowa = amask[b * L_ + l] > 0.f;
  bool cola = amask[b * L_ + m] > 0.f;
  float asa;
  if (rowa && cola) asa = (l >= m) ? avgH[b * L_ + m] : avgH[b * L_ + l];
  else if (rowa)    asa = avgH[b * L_ + m];
  else if (cola)    asa = avgH[b * L_ + l];
  else              asa = asps_mean[idx];
  float r = (asa > 0.25f) ? 1.f : expf(adjr[idx]);
  adj_ag[idx] = r * asa;
}

// ---------------- KL partials + row denominators ----------------
__global__ __launch_bounds__(256) void kl_denom(const float* __restrict__ adj_s,
                                                const float* __restrict__ adj_ag,
                                                float* __restrict__ klpart,
                                                float* __restrict__ den_s,
                                                float* __restrict__ den_ag) {
  long row = blockIdx.x;
  int m = threadIdx.x;
  __shared__ float red[4];
  float s = adj_s[row * L_ + m];
  float a = adj_ag[row * L_ + m];
  float sum_s = blkRedSum(s, red);
  float sum_a = blkRedSum(a, red);
  float mx_s = blkRedMax(s, red);
  float mx_a = blkRedMax(a, red);
  float es = expf(s - mx_s), ea = expf(a - mx_a);
  float ses = blkRedSum(es, red);
  float sea = blkRedSum(ea, red);
  float logq = (s - mx_s) - logf(ses);
  float logp = (a - mx_a) - logf(sea);
  float term = (es / ses) * (logq - logp);
  float kp = blkRedSum(term, red);
  if (m == 0) {
    klpart[row] = kp;
    den_s[row] = sum_s + 1.f;
    den_ag[row] = sum_a + 1.f;
  }
}

__global__ __launch_bounds__(256) void kl_final(const float* __restrict__ klpart,
                                                float* __restrict__ dout) {
  __shared__ float red[4];
  float s = 0.f;
  for (int i = threadIdx.x; i < B_ * L_; i += 256) s += klpart[i];
  s = blkRedSum(s, red);
  if (threadIdx.x == 0) dout[96] = expf(-s * 0.1f);
}

// ---------------- in-place row softmax ----------------
__global__ __launch_bounds__(256) void softmax_rows(float* __restrict__ S) {
  long row = blockIdx.x;
  int m = threadIdx.x;
  __shared__ float red[4];
  float v = S[row * L_ + m];
  float mx = blkRedMax(v, red);
  float e = expf(v - mx);
  float s = blkRedSum(e, red);
  S[row * L_ + m] = e / s;
}

// ---------------- classifier head ----------------
__global__ __launch_bounds__(256) void final_kernel(const float* __restrict__ o_ag,
                                                    const float* __restrict__ o_s,
                                                    const float* __restrict__ pooled,
                                                    const float* __restrict__ amask,
                                                    const float* __restrict__ wc,
                                                    const float* __restrict__ bc,
                                                    float* __restrict__ dout) {
  int b = blockIdx.x, t = threadIdx.x;
  __shared__ float cS[1536];
  __shared__ float maskS[256];
  __shared__ float red[4];
  maskS[t] = amask[b * L_ + t];
  float wn = blkRedSum(maskS[t], red);
  for (int e = t; e < MEM_; e += 256) {
    float s1 = 0.f, s2 = 0.f;
    for (int l = 0; l < L_; ++l) {
      float mk = maskS[l];
      if (mk != 0.f) {
        s1 += mk * o_ag[((long)b * L_ + l) * MEM_ + e];
        s2 += mk * o_s[((long)b * L_ + l) * MEM_ + e];
      }
    }
    cS[e] = s1 / wn;
    cS[MEM_ + e] = s2 / wn;
  }
  for (int j = t; j < D_; j += 256) cS[2 * MEM_ + j] = pooled[b * D_ + j];
  __syncthreads();
  float p0 = 0.f, p1 = 0.f, p2 = 0.f;
  for (int j = t; j < 1536; j += 256) {
    float v = cS[j];
    p0 += v * wc[j * 3 + 0];
    p1 += v * wc[j * 3 + 1];
    p2 += v * wc[j * 3 + 2];
  }
  p0 = blkRedSum(p0, red);
  p1 = blkRedSum(p1, red);
  p2 = blkRedSum(p2, red);
  if (t == 0) {
    dout[b * 3 + 0] = p0 + bc[0];
    dout[b * 3 + 1] = p1 + bc[1];
    dout[b * 3 + 2] = p2 + bc[2];
  }
}

extern "C" void kernel_launch(void* const* d_in, const int* in_sizes, int n_in,
                              void* d_out, int out_size, void* d_ws, size_t ws_size,
                              hipStream_t stream) {
  const float* seq    = (const float*)d_in[0];
  const float* pooled = (const float*)d_in[1];
  const float* adjr   = (const float*)d_in[2];
  const float* srcm   = (const float*)d_in[3];
  const float* amask  = (const float*)d_in[4];
  const float* ln_g   = (const float*)d_in[5];
  const float* ln_b   = (const float*)d_in[6];
  const float* wq     = (const float*)d_in[7];
  const float* bq     = (const float*)d_in[8];
  const float* wk     = (const float*)d_in[9];
  const float* bk     = (const float*)d_in[10];
  const float* wd     = (const float*)d_in[11];
  const float* bd     = (const float*)d_in[12];
  const float* wm     = (const float*)d_in[13];
  const float* bm     = (const float*)d_in[14];
  const float* wa0    = (const float*)d_in[15];
  const float* ba0    = (const float*)d_in[16];
  const float* wa1    = (const float*)d_in[17];
  const float* ba1    = (const float*)d_in[18];
  const float* ws0    = (const float*)d_in[19];
  const float* bs0    = (const float*)d_in[20];
  const float* ws1    = (const float*)d_in[21];
  const float* bs1    = (const float*)d_in[22];
  const float* aff1   = (const float*)d_in[23];
  const float* aff2   = (const float*)d_in[24];
  const float* wc     = (const float*)d_in[25];
  const float* bc     = (const float*)d_in[26];

  float* ws = (float*)d_ws;
  const long SZ_BLD = (long)B_ * L_ * D_;
  const long SZ_BLM = (long)B_ * L_ * MEM_;
  const long SZ_BLL = (long)B_ * L_ * L_;
  float* x      = ws;                 // x ; later o_ag | o_s
  float* qbuf   = ws + SZ_BLD;        // q f32 ; later tmpA bf16 ; later g_ag | g_s
  float* kbuf   = ws + 2 * SZ_BLD;    // kbf bf16 ; later t_ag|t_s ; then u1|u2
  float* asp    = ws + 3 * SZ_BLD;
  float* asps   = ws + 3 * SZ_BLD + (long)B_ * L_ * DK_;  // asps_mean ; later S
  float* adj_s  = asps + SZ_BLL;
  float* adj_ag = adj_s + SZ_BLL;
  float* avgH   = adj_ag + SZ_BLL;
  float* den_s  = avgH + B_ * L_;
  float* den_ag = den_s + B_ * L_;
  float* klp    = den_ag + B_ * L_;

  unsigned short* kbf  = (unsigned short*)kbuf;   // bf16 [B,L,768]
  unsigned short* tmpA = (unsigned short*)qbuf;   // bf16 [B,H,L,64]
  float* t_ag = kbuf;            float* t_s = kbuf + SZ_BLM;
  float* g_ag = qbuf;            float* g_s = qbuf + SZ_BLM;
  float* u1   = kbuf;            float* u2  = kbuf + SZ_BLM;
  float* S    = asps;
  float* o_ag = x;               float* o_s = x + SZ_BLM;
  float* dout = (float*)d_out;

  const long sAdj = (long)L_ * L_;
  const long sMem = (long)L_ * MEM_;

  ln_kernel<<<B_ * L_, 256, 0, stream>>>(seq, ln_g, ln_b, x);
  // q: f32 out. k: bf16 out only.
  gemm_mfma<0><<<dim3(6, 64, 1), 256, 0, stream>>>(
      x, wq, qbuf, 8192, 768, 768, 0, 0, 0, bq, nullptr, 0, nullptr,
      nullptr, nullptr, nullptr, nullptr, nullptr, 0);
  gemm_mfma<0><<<dim3(6, 64, 1), 256, 0, stream>>>(
      x, wk, nullptr, 8192, 768, 768, 0, 0, 0, bk, nullptr, 0, kbf,
      nullptr, nullptr, nullptr, nullptr, nullptr, 0);
  attn_adjs_v2<<<B_ * 8, 256, 0, stream>>>(qbuf, kbf, srcm, adj_s);
  gemm64<<<dim3(1, 128, 1), 256, 0, stream>>>(x, wd, asp, 8192, 64, 768, 0, 0, 0,
                                              amask, bd, nullptr, 0, 0);
  asp_wm<<<B_ * H_, 256, 0, stream>>>(asp, wm, tmpA);
  asps_mean_v2<<<B_ * 16, 256, 0, stream>>>(tmpA, kbf, bm, asps);
  avgh_kernel<<<B_, 256, 0, stream>>>(asps, avgH);
  adjag_kernel<<<B_ * L_ * L_ / 256, 256, 0, stream>>>(asps, avgH, amask, adjr, adj_ag);
  kl_denom<<<B_ * L_, 256, 0, stream>>>(adj_s, adj_ag, klp, den_s, den_ag);
  kl_final<<<1, 256, 0, stream>>>(klp, dout);

  for (int li = 0; li < 2; ++li) {
    int Kd = li ? MEM_ : D_;
    const float* inag = li ? o_ag : x;
    const float* ins  = li ? o_s : x;
    const float* wA = li ? wa1 : wa0;
    const float* bA = li ? ba1 : ba0;
    const float* wS = li ? ws1 : ws0;
    const float* bS = li ? bs1 : bs0;
    // paired: t_ag = inag@wA ; t_s = ins@wS
    gemm_mfma<0><<<dim3(3, 64, 2), 256, 0, stream>>>(
        inag, wA, t_ag, 8192, MEM_, Kd, 0, 0, 0, nullptr, nullptr, 0, nullptr,
        ins, wS, t_s, nullptr, nullptr, 1);
    // paired: g_ag = relu((adj_ag@t_ag + bA)/den_ag) ; g_s likewise
    gemm_mfma<0><<<dim3(3, 2, 64), 256, 0, stream>>>(
        adj_ag, t_ag, g_ag, L_, MEM_, L_, sAdj, sMem, sMem, bA, den_ag, 1, nullptr,
        adj_s, t_s, g_s, bS, den_s, 32);
    // paired: u1 = g_ag@aff1 ; u2 = g_s@aff2
    gemm_mfma<0><<<dim3(3, 64, 2), 256, 0, stream>>>(
        g_ag, aff1, u1, 8192, MEM_, MEM_, 0, 0, 0, nullptr, nullptr, 0, nullptr,
        g_s, aff2, u2, nullptr, nullptr, 1);
    // S1 = u1 @ g_s^T ; softmax ; o_ag = S1 @ g_s
    gemm_mfma<1><<<dim3(2, 2, 32), 256, 0, stream>>>(
        u1, g_s, S, L_, L_, MEM_, sMem, sMem, sAdj, nullptr, nullptr, 0, nullptr,
        nullptr, nullptr, nullptr, nullptr, nullptr, 0);
    softmax_rows<<<B_ * L_, 256, 0, stream>>>(S);
    gemm_mfma<0><<<dim3(3, 2, 32), 256, 0, stream>>>(
        S, g_s, o_ag, L_, MEM_, L_, sAdj, sMem, sMem, nullptr, nullptr, 0, nullptr,
        nullptr, nullptr, nullptr, nullptr, nullptr, 0);
    // S2 = u2 @ g_ag^T ; softmax ; o_s = S2 @ g_ag
    gemm_mfma<1><<<dim3(2, 2, 32), 256, 0, stream>>>(
        u2, g_ag, S, L_, L_, MEM_, sMem, sMem, sAdj, nullptr, nullptr, 0, nullptr,
        nullptr, nullptr, nullptr, nullptr, nullptr, 0);
    softmax_rows<<<B_ * L_, 256, 0, stream>>>(S);
    gemm_mfma<0><<<dim3(3, 2, 32), 256, 0, stream>>>(
        S, g_ag, o_s, L_, MEM_, L_, sAdj, sMem, sMem, nullptr, nullptr, 0, nullptr,
        nullptr, nullptr, nullptr, nullptr, nullptr, 0);
  }

  final_kernel<<<B_, 256, 0, stream>>>(o_ag, o_s, pooled, amask, wc, bc, dout);
}

// Round 5
// 656.897 us; speedup vs baseline: 3.8595x; 1.2966x over previous
//
#include <hip/hip_runtime.h>

#define B_ 32
#define L_ 256
#define D_ 768
#define H_ 12
#define DK_ 64
#define MEM_ 384

typedef __attribute__((ext_vector_type(8))) short bfrag8;    // 8 bf16 (4 VGPRs)
typedef __attribute__((ext_vector_type(8))) unsigned short us8;
typedef __attribute__((ext_vector_type(4))) float f32x4;

// f32 -> bf16 round-to-nearest-even (finite inputs only)
__device__ inline unsigned short f2bf(float f) {
  unsigned u = __float_as_uint(f);
  return (unsigned short)((u + 0x7fffu + ((u >> 16) & 1u)) >> 16);
}
__device__ inline float bf2f(unsigned short u) {
  return __uint_as_float(((unsigned)u) << 16);
}
__device__ inline float tanh_fast(float x) {
  x = fminf(fmaxf(x, -30.f), 30.f);
  float e = __expf(2.f * x);
  return (e - 1.f) * __builtin_amdgcn_rcpf(e + 1.f);
}

// ---------------- block reduce helpers (256 threads = 4 waves) ----------------
__device__ inline float waveRedSum(float v) {
#pragma unroll
  for (int o = 32; o; o >>= 1) v += __shfl_xor(v, o, 64);
  return v;
}
__device__ inline float waveRedMax(float v) {
#pragma unroll
  for (int o = 32; o; o >>= 1) v = fmaxf(v, __shfl_xor(v, o, 64));
  return v;
}
__device__ inline float blkRedSum(float v, float* red) {
  v = waveRedSum(v);
  int w = threadIdx.x >> 6;
  __syncthreads();
  if ((threadIdx.x & 63) == 0) red[w] = v;
  __syncthreads();
  return red[0] + red[1] + red[2] + red[3];
}
__device__ inline float blkRedMax(float v, float* red) {
  v = waveRedMax(v);
  int w = threadIdx.x >> 6;
  __syncthreads();
  if ((threadIdx.x & 63) == 0) red[w] = v;
  __syncthreads();
  return fmaxf(fmaxf(red[0], red[1]), fmaxf(red[2], red[3]));
}

// ---------------- LayerNorm ----------------
__global__ __launch_bounds__(256) void ln_kernel(const float* __restrict__ in,
                                                 const float* __restrict__ g,
                                                 const float* __restrict__ bt,
                                                 float* __restrict__ out) {
  long row = blockIdx.x;
  const float* p = in + row * D_;
  float v[3];
#pragma unroll
  for (int i = 0; i < 3; ++i) v[i] = p[threadIdx.x + i * 256];
  __shared__ float red[4];
  float s = v[0] + v[1] + v[2];
  s = blkRedSum(s, red);
  float mu = s * (1.f / D_);
  float ss = 0.f;
#pragma unroll
  for (int i = 0; i < 3; ++i) { float d = v[i] - mu; ss += d * d; }
  ss = blkRedSum(ss, red);
  float sd = sqrtf(ss * (1.f / (D_ - 1)));
  float inv = 1.f / (sd + 1e-6f);
#pragma unroll
  for (int i = 0; i < 3; ++i) {
    int c = threadIdx.x + i * 256;
    out[row * D_ + c] = g[c] * (v[i] - mu) * inv + bt[c];
  }
}

// ---------------- generic tiled SGEMM (kept for N=64 asp GEMM) ----------------
__global__ __launch_bounds__(256) void gemm64(
    const float* __restrict__ A, const float* __restrict__ B, float* __restrict__ C,
    int M, int N, int K, long sA, long sB, long sC,
    const float* __restrict__ rowScale, const float* __restrict__ bias,
    const float* __restrict__ rowDiv, int relu, int transB) {
  const int tid = threadIdx.x;
  const int bn = blockIdx.x, bm = blockIdx.y, bz = blockIdx.z;
  A += (long)bz * sA; B += (long)bz * sB; C += (long)bz * sC;
  __shared__ float As[16][65];
  __shared__ float Bs[16][65];
  float acc[4][4] = {};
  const int tm = tid & 15, tn = tid >> 4;
  for (int k0 = 0; k0 < K; k0 += 16) {
#pragma unroll
    for (int i = 0; i < 4; ++i) {
      int idx = tid + i * 256;
      int r = idx >> 4, c = idx & 15;
      As[c][r] = A[(long)(bm * 64 + r) * K + k0 + c];
    }
    if (!transB) {
#pragma unroll
      for (int i = 0; i < 4; ++i) {
        int idx = tid + i * 256;
        int r = idx >> 6, c = idx & 63;
        Bs[r][c] = B[(long)(k0 + r) * N + bn * 64 + c];
      }
    } else {
#pragma unroll
      for (int i = 0; i < 4; ++i) {
        int idx = tid + i * 256;
        int r = idx >> 4, c = idx & 15;
        Bs[c][r] = B[(long)(bn * 64 + r) * K + k0 + c];
      }
    }
    __syncthreads();
#pragma unroll
    for (int kk = 0; kk < 16; ++kk) {
      float a[4], bb[4];
#pragma unroll
      for (int i = 0; i < 4; ++i) a[i] = As[kk][tm * 4 + i];
#pragma unroll
      for (int j = 0; j < 4; ++j) bb[j] = Bs[kk][tn * 4 + j];
#pragma unroll
      for (int i = 0; i < 4; ++i)
#pragma unroll
        for (int j = 0; j < 4; ++j) acc[i][j] += a[i] * bb[j];
    }
    __syncthreads();
  }
#pragma unroll
  for (int i = 0; i < 4; ++i) {
    int r = bm * 64 + tm * 4 + i;
    long grow = (long)bz * M + r;
    float rs = rowScale ? rowScale[grow] : 1.f;
    float rd = rowDiv ? 1.f / rowDiv[grow] : 1.f;
#pragma unroll
    for (int j = 0; j < 4; ++j) {
      int cn = bn * 64 + tn * 4 + j;
      float v = acc[i][j] * rs;
      if (bias) v += bias[cn];
      v *= rd;
      if (relu) v = fmaxf(v, 0.f);
      C[(long)r * N + cn] = v;
    }
  }
}

// ---------------- bf16 MFMA GEMM: 128x128 tile, BK=32, 4 waves (2x2), 4x4 frags --------
// ABF: A operand is bf16 in global (no conversion on stage). Optional f32 and/or
// bf16 outputs. Optional second operand set (z >= zsplit) to pair two GEMMs.
template <int ABF>
__global__ __launch_bounds__(256) void gemm_mfma(
    const void* __restrict__ A, const float* __restrict__ B,
    float* __restrict__ C, unsigned short* __restrict__ Cbf,
    int M, int N, int K, long sA, long sB, long sC,
    const float* __restrict__ bias, const float* __restrict__ rowDiv, int relu,
    const void* __restrict__ A2, const float* __restrict__ B2,
    float* __restrict__ C2, unsigned short* __restrict__ Cbf2,
    const float* __restrict__ bias2, const float* __restrict__ rowDiv2, int zsplit) {
  const int tid = threadIdx.x;
  const int bn = blockIdx.x, bm = blockIdx.y;
  int bz = blockIdx.z;
  const void* Avp = A; const float* Bp = B; float* Cp = C;
  unsigned short* Cbfp = Cbf;
  const float* biasp = bias; const float* rowDivp = rowDiv;
  if (zsplit > 0 && bz >= zsplit) {
    bz -= zsplit;
    Avp = A2; Bp = B2; Cp = C2; Cbfp = Cbf2; biasp = bias2; rowDivp = rowDiv2;
  }
  const float* Af = (const float*)Avp + (ABF ? 0 : (long)bz * sA);
  const unsigned short* Ab = (const unsigned short*)Avp + (ABF ? (long)bz * sA : 0);
  Bp += (long)bz * sB;
  if (Cp) Cp += (long)bz * sC;
  if (Cbfp) Cbfp += (long)bz * sC;
  __shared__ unsigned short As[128][40];  // pad 32->40 (80B row stride)
  __shared__ unsigned short Bs[128][40];
  f32x4 acc[4][4] = {};

  const int l = tid & 63, w = tid >> 6;
  const int wr = w >> 1, wc = w & 1;
  const int lr = l & 15, kg = (l >> 4) * 8;

  const int ar = tid >> 1, ah = tid & 1;
  const int kp = (tid >> 4) * 2, n8 = (tid & 15) * 8;

  for (int k0 = 0; k0 < K; k0 += 32) {
    if (ABF) {
      const unsigned short* src = Ab + (long)(bm * 128 + ar) * K + k0 + ah * 16;
      *(us8*)&As[ar][ah * 16] = ((const us8*)src)[0];
      *(us8*)&As[ar][ah * 16 + 8] = ((const us8*)src)[1];
    } else {
      const float* src = Af + (long)(bm * 128 + ar) * K + k0 + ah * 16;
      float4 f0 = ((const float4*)src)[0];
      float4 f1 = ((const float4*)src)[1];
      float4 f2 = ((const float4*)src)[2];
      float4 f3 = ((const float4*)src)[3];
      us8 v0, v1;
      v0[0] = f2bf(f0.x); v0[1] = f2bf(f0.y); v0[2] = f2bf(f0.z); v0[3] = f2bf(f0.w);
      v0[4] = f2bf(f1.x); v0[5] = f2bf(f1.y); v0[6] = f2bf(f1.z); v0[7] = f2bf(f1.w);
      v1[0] = f2bf(f2.x); v1[1] = f2bf(f2.y); v1[2] = f2bf(f2.z); v1[3] = f2bf(f2.w);
      v1[4] = f2bf(f3.x); v1[5] = f2bf(f3.y); v1[6] = f2bf(f3.z); v1[7] = f2bf(f3.w);
      *(us8*)&As[ar][ah * 16] = v0;
      *(us8*)&As[ar][ah * 16 + 8] = v1;
    }
    {
      const float* s0 = Bp + (long)(k0 + kp) * N + bn * 128 + n8;
      const float* s1 = s0 + N;
      float4 a0 = ((const float4*)s0)[0];
      float4 a1 = ((const float4*)s0)[1];
      float4 b0 = ((const float4*)s1)[0];
      float4 b1 = ((const float4*)s1)[1];
      float r0[8] = {a0.x, a0.y, a0.z, a0.w, a1.x, a1.y, a1.z, a1.w};
      float r1[8] = {b0.x, b0.y, b0.z, b0.w, b1.x, b1.y, b1.z, b1.w};
#pragma unroll
      for (int j = 0; j < 8; ++j) {
        unsigned pk = (unsigned)f2bf(r0[j]) | ((unsigned)f2bf(r1[j]) << 16);
        *(unsigned*)&Bs[n8 + j][kp] = pk;
      }
    }
    __syncthreads();

    bfrag8 af[4], bf[4];
#pragma unroll
    for (int m = 0; m < 4; ++m) af[m] = *(const bfrag8*)&As[wr * 64 + m * 16 + lr][kg];
#pragma unroll
    for (int n = 0; n < 4; ++n) bf[n] = *(const bfrag8*)&Bs[wc * 64 + n * 16 + lr][kg];
#pragma unroll
    for (int m = 0; m < 4; ++m)
#pragma unroll
      for (int n = 0; n < 4; ++n)
        acc[m][n] = __builtin_amdgcn_mfma_f32_16x16x32_bf16(af[m], bf[n], acc[m][n], 0, 0, 0);
    __syncthreads();
  }

#pragma unroll
  for (int m = 0; m < 4; ++m) {
#pragma unroll
    for (int r = 0; r < 4; ++r) {
      int row = bm * 128 + wr * 64 + m * 16 + (l >> 4) * 4 + r;
      long grow = (long)bz * M + row;
      float rd = rowDivp ? 1.f / rowDivp[grow] : 1.f;
#pragma unroll
      for (int n = 0; n < 4; ++n) {
        int col = bn * 128 + wc * 64 + n * 16 + (l & 15);
        float v = acc[m][n][r];
        if (biasp) v += biasp[col];
        v *= rd;
        if (relu) v = fmaxf(v, 0.f);
        if (Cp) Cp[(long)row * N + col] = v;
        if (Cbfp) Cbfp[(long)row * N + col] = f2bf(v);
      }
    }
  }
}

// ---------------- fused MFMA attention: adj_s = rowmask*fixdiag(mean_h softmax(qk^T/8)) ----
// block = (b, 16 rows); 4 waves each own 64 cols; frags straight from global bf16.
__global__ __launch_bounds__(256) void attn_mfma(const unsigned short* __restrict__ qbf,
                                                 const unsigned short* __restrict__ kbf,
                                                 const float* __restrict__ srcm,
                                                 float* __restrict__ adj_s) {
  int blk = blockIdx.x;
  int b = blk >> 4, l0 = (blk & 15) << 4;
  int t = threadIdx.x;
  int w = t >> 6, l = t & 63;
  int lr = l & 15, kg = (l >> 4) * 8;
  int rbase = (l >> 4) * 4;
  __shared__ float redmx[4][16];
  __shared__ float redsm[4][16];
  float acc[4][4] = {};
  float cmv[4];
#pragma unroll
  for (int ct = 0; ct < 4; ++ct) cmv[ct] = srcm[b * L_ + w * 64 + ct * 16 + lr];

  for (int h = 0; h < H_; ++h) {
    const unsigned short* ap = qbf + ((long)b * L_ + l0 + lr) * D_ + h * 64 + kg;
    bfrag8 af0 = *(const bfrag8*)ap;
    bfrag8 af1 = *(const bfrag8*)(ap + 32);
    float sv[4][4];
#pragma unroll
    for (int ct = 0; ct < 4; ++ct) {
      const unsigned short* bp =
          kbf + ((long)b * L_ + w * 64 + ct * 16 + lr) * D_ + h * 64 + kg;
      bfrag8 bf0 = *(const bfrag8*)bp;
      bfrag8 bf1 = *(const bfrag8*)(bp + 32);
      f32x4 c = {};
      c = __builtin_amdgcn_mfma_f32_16x16x32_bf16(af0, bf0, c, 0, 0, 0);
      c = __builtin_amdgcn_mfma_f32_16x16x32_bf16(af1, bf1, c, 0, 0, 0);
#pragma unroll
      for (int r = 0; r < 4; ++r)
        sv[ct][r] = (cmv[ct] == 0.f) ? -1e9f : c[r] * 0.125f;
    }
    // row max: in-reg over ct, shfl over the 16-lane col group, LDS across waves
#pragma unroll
    for (int r = 0; r < 4; ++r) {
      float mx = fmaxf(fmaxf(sv[0][r], sv[1][r]), fmaxf(sv[2][r], sv[3][r]));
#pragma unroll
      for (int o = 1; o < 16; o <<= 1) mx = fmaxf(mx, __shfl_xor(mx, o, 64));
      if (lr == 0) redmx[w][rbase + r] = mx;
    }
    __syncthreads();
#pragma unroll
    for (int r = 0; r < 4; ++r) {
      float mx = fmaxf(fmaxf(redmx[0][rbase + r], redmx[1][rbase + r]),
                       fmaxf(redmx[2][rbase + r], redmx[3][rbase + r]));
      float s = 0.f;
#pragma unroll
      for (int ct = 0; ct < 4; ++ct) {
        float e = __expf(sv[ct][r] - mx);
        sv[ct][r] = e;
        s += e;
      }
#pragma unroll
      for (int o = 1; o < 16; o <<= 1) s += __shfl_xor(s, o, 64);
      if (lr == 0) redsm[w][rbase + r] = s;
    }
    __syncthreads();
#pragma unroll
    for (int r = 0; r < 4; ++r) {
      float tot = redsm[0][rbase + r] + redsm[1][rbase + r] +
                  redsm[2][rbase + r] + redsm[3][rbase + r];
      float inv = 1.f / tot;
#pragma unroll
      for (int ct = 0; ct < 4; ++ct) acc[ct][r] += sv[ct][r] * inv;
    }
  }

#pragma unroll
  for (int r = 0; r < 4; ++r) {
    int row = l0 + rbase + r;
    float rm = srcm[b * L_ + row];
#pragma unroll
    for (int ct = 0; ct < 4; ++ct) {
      int col = w * 64 + ct * 16 + lr;
      float v = acc[ct][r] * (1.f / H_);
      if (col == row) v = 1.f;
      v *= rm;
      adj_s[((long)b * L_ + row) * L_ + col] = v;
    }
  }
}

// ---------------- fused S-GEMM + row softmax: P = softmax(A @ B^T), bf16 out ------------
// A,B f32 [256 x 384] per z; tile 64 rows x all 256 cols; grid (4, 64) with z-pair at 32.
__global__ __launch_bounds__(256) void gemm_sfmx(
    const float* __restrict__ A, const float* __restrict__ Bt,
    unsigned short* __restrict__ P,
    const float* __restrict__ A2, const float* __restrict__ Bt2,
    unsigned short* __restrict__ P2) {
  int bm = blockIdx.x;
  int bz = blockIdx.y;
  const float* Ap; const float* Bp; unsigned short* Pp;
  if (bz < 32) {
    Ap = A + (long)bz * L_ * MEM_; Bp = Bt + (long)bz * L_ * MEM_;
    Pp = P + (long)bz * L_ * L_;
  } else {
    int z = bz - 32;
    Ap = A2 + (long)z * L_ * MEM_; Bp = Bt2 + (long)z * L_ * MEM_;
    Pp = P2 + (long)z * L_ * L_;
  }
  __shared__ unsigned short As[64][40];
  __shared__ unsigned short Bs[256][40];
  __shared__ float redm[2][64];
  __shared__ float reds[2][64];
  const int t = threadIdx.x;
  const int l = t & 63, w = t >> 6;
  const int wr = w >> 1, wc = w & 1;
  const int lr = l & 15, kg = (l >> 4) * 8;
  f32x4 acc[2][8] = {};
  const int arA = t >> 2, akA = (t & 3) * 8;
  const int arB = t >> 1, ahB = t & 1;

  for (int k0 = 0; k0 < MEM_; k0 += 32) {
    {
      const float* src = Ap + (long)(bm * 64 + arA) * MEM_ + k0 + akA;
      float4 f0 = ((const float4*)src)[0];
      float4 f1 = ((const float4*)src)[1];
      us8 v;
      v[0] = f2bf(f0.x); v[1] = f2bf(f0.y); v[2] = f2bf(f0.z); v[3] = f2bf(f0.w);
      v[4] = f2bf(f1.x); v[5] = f2bf(f1.y); v[6] = f2bf(f1.z); v[7] = f2bf(f1.w);
      *(us8*)&As[arA][akA] = v;
    }
#pragma unroll
    for (int it = 0; it < 2; ++it) {
      const float* src = Bp + (long)(it * 128 + arB) * MEM_ + k0 + ahB * 16;
      float4 f0 = ((const float4*)src)[0];
      float4 f1 = ((const float4*)src)[1];
      float4 f2 = ((const float4*)src)[2];
      float4 f3 = ((const float4*)src)[3];
      us8 v0, v1;
      v0[0] = f2bf(f0.x); v0[1] = f2bf(f0.y); v0[2] = f2bf(f0.z); v0[3] = f2bf(f0.w);
      v0[4] = f2bf(f1.x); v0[5] = f2bf(f1.y); v0[6] = f2bf(f1.z); v0[7] = f2bf(f1.w);
      v1[0] = f2bf(f2.x); v1[1] = f2bf(f2.y); v1[2] = f2bf(f2.z); v1[3] = f2bf(f2.w);
      v1[4] = f2bf(f3.x); v1[5] = f2bf(f3.y); v1[6] = f2bf(f3.z); v1[7] = f2bf(f3.w);
      *(us8*)&Bs[it * 128 + arB][ahB * 16] = v0;
      *(us8*)&Bs[it * 128 + arB][ahB * 16 + 8] = v1;
    }
    __syncthreads();
    bfrag8 af[2], bf[8];
#pragma unroll
    for (int m = 0; m < 2; ++m) af[m] = *(const bfrag8*)&As[wr * 32 + m * 16 + lr][kg];
#pragma unroll
    for (int n = 0; n < 8; ++n) bf[n] = *(const bfrag8*)&Bs[wc * 128 + n * 16 + lr][kg];
#pragma unroll
    for (int m = 0; m < 2; ++m)
#pragma unroll
      for (int n = 0; n < 8; ++n)
        acc[m][n] = __builtin_amdgcn_mfma_f32_16x16x32_bf16(af[m], bf[n], acc[m][n], 0, 0, 0);
    __syncthreads();
  }

  // row softmax over the full 256-col row (this block owns it all)
  float mxs[2][4];
#pragma unroll
  for (int m = 0; m < 2; ++m) {
#pragma unroll
    for (int r = 0; r < 4; ++r) {
      int lrow = wr * 32 + m * 16 + (l >> 4) * 4 + r;
      float mx = -1e30f;
#pragma unroll
      for (int n = 0; n < 8; ++n) mx = fmaxf(mx, acc[m][n][r]);
#pragma unroll
      for (int o = 1; o < 16; o <<= 1) mx = fmaxf(mx, __shfl_xor(mx, o, 64));
      if (lr == 0) redm[wc][lrow] = mx;
    }
  }
  __syncthreads();
#pragma unroll
  for (int m = 0; m < 2; ++m) {
#pragma unroll
    for (int r = 0; r < 4; ++r) {
      int lrow = wr * 32 + m * 16 + (l >> 4) * 4 + r;
      float mx = fmaxf(redm[0][lrow], redm[1][lrow]);
      mxs[m][r] = mx;
      float s = 0.f;
#pragma unroll
      for (int n = 0; n < 8; ++n) {
        float e = __expf(acc[m][n][r] - mx);
        acc[m][n][r] = e;
        s += e;
      }
#pragma unroll
      for (int o = 1; o < 16; o <<= 1) s += __shfl_xor(s, o, 64);
      if (lr == 0) reds[wc][lrow] = s;
    }
  }
  __syncthreads();
#pragma unroll
  for (int m = 0; m < 2; ++m) {
#pragma unroll
    for (int r = 0; r < 4; ++r) {
      int lrow = wr * 32 + m * 16 + (l >> 4) * 4 + r;
      float inv = 1.f / (reds[0][lrow] + reds[1][lrow]);
      int row = bm * 64 + lrow;
#pragma unroll
      for (int n = 0; n < 8; ++n) {
        int col = wc * 128 + n * 16 + lr;
        Pp[(long)row * L_ + col] = f2bf(acc[m][n][r] * inv);
      }
    }
  }
}

// ---------------- tmpA[b,h] = asp[b] (L x 64) @ Wm[h] (64 x 64), bf16 out ----------------
__global__ __launch_bounds__(256) void asp_wm(const float* __restrict__ asp,
                                              const float* __restrict__ wm,
                                              unsigned short* __restrict__ tmpA) {
  int bh = blockIdx.x;
  int b = bh / H_, h = bh % H_;
  int t = threadIdx.x;
  __shared__ float WmS[64][64];
  __shared__ float aspS[64][64];
#pragma unroll
  for (int i = 0; i < 16; ++i) {
    int idx = t + i * 256;
    WmS[idx >> 6][idx & 63] = wm[h * 4096 + idx];
  }
  int e = t & 63, lr = t >> 6;
  for (int c = 0; c < 4; ++c) {
    __syncthreads();
#pragma unroll
    for (int i = 0; i < 16; ++i) {
      int idx = t + i * 256;
      aspS[idx >> 6][idx & 63] = asp[((long)b * L_ + c * 64 + (idx >> 6)) * 64 + (idx & 63)];
    }
    __syncthreads();
    for (int s = 0; s < 16; ++s) {
      int ll = s * 4 + lr;
      float accv = 0.f;
#pragma unroll
      for (int d = 0; d < 64; ++d) accv += aspS[ll][d] * WmS[d][e];
      tmpA[(((long)b * H_ + h) * L_ + c * 64 + ll) * 64 + e] = f2bf(accv);
    }
  }
}

// ---------------- asps_mean via MFMA ----------------
__global__ __launch_bounds__(256) void asps_mean_v2(
    const unsigned short* __restrict__ tmpA,  // bf16 [B,H,L,64]
    const unsigned short* __restrict__ kbf,   // bf16 [B,L,768]
    const float* __restrict__ bias_m,
    float* __restrict__ asps_mean) {
  int blk = blockIdx.x;
  int b = blk >> 4, l0 = (blk & 15) << 4;
  int t = threadIdx.x;
  int w = t >> 6, l = t & 63;
  int lr = l & 15, kg = (l >> 4) * 8;
  float bm = bias_m[0];
  float accg[4][4] = {};
  for (int h = 0; h < H_; ++h) {
    const unsigned short* ap = tmpA + (((long)b * H_ + h) * L_ + l0 + lr) * 64 + kg;
    bfrag8 af0 = *(const bfrag8*)ap;
    bfrag8 af1 = *(const bfrag8*)(ap + 32);
#pragma unroll
    for (int ct = 0; ct < 4; ++ct) {
      const unsigned short* bp =
          kbf + ((long)b * L_ + w * 64 + ct * 16 + lr) * D_ + h * 64 + kg;
      bfrag8 bf0 = *(const bfrag8*)bp;
      bfrag8 bf1 = *(const bfrag8*)(bp + 32);
      f32x4 accl = {};
      accl = __builtin_amdgcn_mfma_f32_16x16x32_bf16(af0, bf0, accl, 0, 0, 0);
      accl = __builtin_amdgcn_mfma_f32_16x16x32_bf16(af1, bf1, accl, 0, 0, 0);
#pragma unroll
      for (int r = 0; r < 4; ++r) accg[ct][r] += tanh_fast(accl[r] + bm);
    }
  }
#pragma unroll
  for (int ct = 0; ct < 4; ++ct) {
    int col = w * 64 + ct * 16 + lr;
#pragma unroll
    for (int r = 0; r < 4; ++r) {
      int row = l0 + (l >> 4) * 4 + r;
      asps_mean[((long)b * L_ + row) * L_ + col] = accg[ct][r] * (1.f / H_);
    }
  }
}

// ---------------- avgH ----------------
__global__ __launch_bounds__(256) void avgh_kernel(const float* __restrict__ asps_mean,
                                                   float* __restrict__ avgH) {
  int b = blockIdx.x, m = threadIdx.x;
  float s = 0.f;
  for (int l = 0; l < L_; ++l) s += asps_mean[((long)b * L_ + l) * L_ + m];
  avgH[b * L_ + m] = s * (1.f / L_);
}

// ---------------- adj_ag ----------------
__global__ __launch_bounds__(256) void adjag_kernel(const float* __restrict__ asps_mean,
                                                    const float* __restrict__ avgH,
                                                    const float* __restrict__ amask,
                                                    const float* __restrict__ adjr,
                                                    float* __restrict__ adj_ag) {
  long idx = (long)blockIdx.x * 256 + threadIdx.x;
  int m = idx & 255;
  long bl = idx >> 8;
  int l = (int)(bl & 255);
  int b = (int)(bl >> 8);
  bool rowa = amask[b * L_ + l] > 0.f;
  bool cola = amask[b * L_ + m] > 0.f;
  float asa;
  if (rowa && cola) asa = (l >= m) ? avgH[b * L_ + m] : avgH[b * L_ + l];
  else if (rowa)    asa = avgH[b * L_ + m];
  else if (cola)    asa = avgH[b * L_ + l];
  else              asa = asps_mean[idx];
  float r = (asa > 0.25f) ? 1.f : expf(adjr[idx]);
  adj_ag[idx] = r * asa;
}

// ---------------- KL partials + row denominators ----------------
__global__ __launch_bounds__(256) void kl_denom(const float* __restrict__ adj_s,
                                                const float* __restrict__ adj_ag,
                                                float* __restrict__ klpart,
                                                float* __restrict__ den_s,
                                                float* __restrict__ den_ag) {
  long row = blockIdx.x;
  int m = threadIdx.x;
  __shared__ float red[4];
  float s = adj_s[row * L_ + m];
  float a = adj_ag[row * L_ + m];
  float sum_s = blkRedSum(s, red);
  float sum_a = blkRedSum(a, red);
  float mx_s = blkRedMax(s, red);
  float mx_a = blkRedMax(a, red);
  float es = expf(s - mx_s), ea = expf(a - mx_a);
  float ses = blkRedSum(es, red);
  float sea = blkRedSum(ea, red);
  float logq = (s - mx_s) - logf(ses);
  float logp = (a - mx_a) - logf(sea);
  float term = (es / ses) * (logq - logp);
  float kp = blkRedSum(term, red);
  if (m == 0) {
    klpart[row] = kp;
    den_s[row] = sum_s + 1.f;
    den_ag[row] = sum_a + 1.f;
  }
}

__global__ __launch_bounds__(256) void kl_final(const float* __restrict__ klpart,
                                                float* __restrict__ dout) {
  __shared__ float red[4];
  float s = 0.f;
  for (int i = threadIdx.x; i < B_ * L_; i += 256) s += klpart[i];
  s = blkRedSum(s, red);
  if (threadIdx.x == 0) dout[96] = expf(-s * 0.1f);
}

// ---------------- classifier head ----------------
__global__ __launch_bounds__(256) void final_kernel(const float* __restrict__ o_ag,
                                                    const float* __restrict__ o_s,
                                                    const float* __restrict__ pooled,
                                                    const float* __restrict__ amask,
                                                    const float* __restrict__ wc,
                                                    const float* __restrict__ bc,
                                                    float* __restrict__ dout) {
  int b = blockIdx.x, t = threadIdx.x;
  __shared__ float cS[1536];
  __shared__ float maskS[256];
  __shared__ float red[4];
  maskS[t] = amask[b * L_ + t];
  float wn = blkRedSum(maskS[t], red);
  for (int e = t; e < MEM_; e += 256) {
    float s1 = 0.f, s2 = 0.f;
    for (int l = 0; l < L_; ++l) {
      float mk = maskS[l];
      if (mk != 0.f) {
        s1 += mk * o_ag[((long)b * L_ + l) * MEM_ + e];
        s2 += mk * o_s[((long)b * L_ + l) * MEM_ + e];
      }
    }
    cS[e] = s1 / wn;
    cS[MEM_ + e] = s2 / wn;
  }
  for (int j = t; j < D_; j += 256) cS[2 * MEM_ + j] = pooled[b * D_ + j];
  __syncthreads();
  float p0 = 0.f, p1 = 0.f, p2 = 0.f;
  for (int j = t; j < 1536; j += 256) {
    float v = cS[j];
    p0 += v * wc[j * 3 + 0];
    p1 += v * wc[j * 3 + 1];
    p2 += v * wc[j * 3 + 2];
  }
  p0 = blkRedSum(p0, red);
  p1 = blkRedSum(p1, red);
  p2 = blkRedSum(p2, red);
  if (t == 0) {
    dout[b * 3 + 0] = p0 + bc[0];
    dout[b * 3 + 1] = p1 + bc[1];
    dout[b * 3 + 2] = p2 + bc[2];
  }
}

extern "C" void kernel_launch(void* const* d_in, const int* in_sizes, int n_in,
                              void* d_out, int out_size, void* d_ws, size_t ws_size,
                              hipStream_t stream) {
  const float* seq    = (const float*)d_in[0];
  const float* pooled = (const float*)d_in[1];
  const float* adjr   = (const float*)d_in[2];
  const float* srcm   = (const float*)d_in[3];
  const float* amask  = (const float*)d_in[4];
  const float* ln_g   = (const float*)d_in[5];
  const float* ln_b   = (const float*)d_in[6];
  const float* wq     = (const float*)d_in[7];
  const float* bq     = (const float*)d_in[8];
  const float* wk     = (const float*)d_in[9];
  const float* bk     = (const float*)d_in[10];
  const float* wd     = (const float*)d_in[11];
  const float* bd     = (const float*)d_in[12];
  const float* wm     = (const float*)d_in[13];
  const float* bm     = (const float*)d_in[14];
  const float* wa0    = (const float*)d_in[15];
  const float* ba0    = (const float*)d_in[16];
  const float* wa1    = (const float*)d_in[17];
  const float* ba1    = (const float*)d_in[18];
  const float* ws0    = (const float*)d_in[19];
  const float* bs0    = (const float*)d_in[20];
  const float* ws1    = (const float*)d_in[21];
  const float* bs1    = (const float*)d_in[22];
  const float* aff1   = (const float*)d_in[23];
  const float* aff2   = (const float*)d_in[24];
  const float* wc     = (const float*)d_in[25];
  const float* bc     = (const float*)d_in[26];

  float* ws = (float*)d_ws;
  const long SZ_BLD = (long)B_ * L_ * D_;
  const long SZ_BLM = (long)B_ * L_ * MEM_;
  const long SZ_BLL = (long)B_ * L_ * L_;
  float* x      = ws;                 // x ; later o_ag | o_s
  float* qbuf   = ws + SZ_BLD;        // qbf bf16 ; later tmpA bf16 ; later g_ag | g_s
  float* kbuf   = ws + 2 * SZ_BLD;    // kbf bf16 ; later t_ag|t_s ; then u1|u2
  float* asp    = ws + 3 * SZ_BLD;
  float* asps   = ws + 3 * SZ_BLD + (long)B_ * L_ * DK_;  // asps_mean ; later S1bf|S2bf
  float* adj_s  = asps + SZ_BLL;
  float* adj_ag = adj_s + SZ_BLL;
  float* avgH   = adj_ag + SZ_BLL;
  float* den_s  = avgH + B_ * L_;
  float* den_ag = den_s + B_ * L_;
  float* klp    = den_ag + B_ * L_;

  unsigned short* qbf  = (unsigned short*)qbuf;   // bf16 [B,L,768]
  unsigned short* kbf  = (unsigned short*)kbuf;   // bf16 [B,L,768]
  unsigned short* tmpA = (unsigned short*)qbuf;   // bf16 [B,H,L,64] (after attn)
  float* t_ag = kbuf;            float* t_s = kbuf + SZ_BLM;
  float* g_ag = qbuf;            float* g_s = qbuf + SZ_BLM;
  float* u1   = kbuf;            float* u2  = kbuf + SZ_BLM;
  unsigned short* S1bf = (unsigned short*)asps;
  unsigned short* S2bf = S1bf + SZ_BLL;
  float* o_ag = x;               float* o_s = x + SZ_BLM;
  float* dout = (float*)d_out;

  const long sAdj = (long)L_ * L_;
  const long sMem = (long)L_ * MEM_;

  ln_kernel<<<B_ * L_, 256, 0, stream>>>(seq, ln_g, ln_b, x);
  // paired q/k projections, bf16 outputs only
  gemm_mfma<0><<<dim3(6, 64, 2), 256, 0, stream>>>(
      x, wq, nullptr, qbf, 8192, 768, 768, 0, 0, 0, bq, nullptr, 0,
      x, wk, nullptr, kbf, bk, nullptr, 1);
  attn_mfma<<<B_ * 16, 256, 0, stream>>>(qbf, kbf, srcm, adj_s);
  gemm64<<<dim3(1, 128, 1), 256, 0, stream>>>(x, wd, asp, 8192, 64, 768, 0, 0, 0,
                                              amask, bd, nullptr, 0, 0);
  asp_wm<<<B_ * H_, 256, 0, stream>>>(asp, wm, tmpA);
  asps_mean_v2<<<B_ * 16, 256, 0, stream>>>(tmpA, kbf, bm, asps);
  avgh_kernel<<<B_, 256, 0, stream>>>(asps, avgH);
  adjag_kernel<<<B_ * L_ * L_ / 256, 256, 0, stream>>>(asps, avgH, amask, adjr, adj_ag);
  kl_denom<<<B_ * L_, 256, 0, stream>>>(adj_s, adj_ag, klp, den_s, den_ag);
  kl_final<<<1, 256, 0, stream>>>(klp, dout);

  for (int li = 0; li < 2; ++li) {
    int Kd = li ? MEM_ : D_;
    const float* inag = li ? o_ag : x;
    const float* ins  = li ? o_s : x;
    const float* wA = li ? wa1 : wa0;
    const float* bA = li ? ba1 : ba0;
    const float* wS = li ? ws1 : ws0;
    const float* bS = li ? bs1 : bs0;
    // paired: t_ag = inag@wA ; t_s = ins@wS
    gemm_mfma<0><<<dim3(3, 64, 2), 256, 0, stream>>>(
        inag, wA, t_ag, nullptr, 8192, MEM_, Kd, 0, 0, 0, nullptr, nullptr, 0,
        ins, wS, t_s, nullptr, nullptr, nullptr, 1);
    // paired: g_ag = relu((adj_ag@t_ag + bA)/den_ag) ; g_s likewise
    gemm_mfma<0><<<dim3(3, 2, 64), 256, 0, stream>>>(
        adj_ag, t_ag, g_ag, nullptr, L_, MEM_, L_, sAdj, sMem, sMem, bA, den_ag, 1,
        adj_s, t_s, g_s, nullptr, bS, den_s, 32);
    // paired: u1 = g_ag@aff1 ; u2 = g_s@aff2
    gemm_mfma<0><<<dim3(3, 64, 2), 256, 0, stream>>>(
        g_ag, aff1, u1, nullptr, 8192, MEM_, MEM_, 0, 0, 0, nullptr, nullptr, 0,
        g_s, aff2, u2, nullptr, nullptr, nullptr, 1);
    // paired fused: S1 = softmax(u1@g_s^T) ; S2 = softmax(u2@g_ag^T), bf16
    gemm_sfmx<<<dim3(4, 64), 256, 0, stream>>>(u1, g_s, S1bf, u2, g_ag, S2bf);
    // paired PV (bf16 A): o_ag = S1@g_s ; o_s = S2@g_ag
    gemm_mfma<1><<<dim3(3, 2, 64), 256, 0, stream>>>(
        S1bf, g_s, o_ag, nullptr, L_, MEM_, L_, sAdj, sMem, sMem, nullptr, nullptr, 0,
        S2bf, g_ag, o_s, nullptr, nullptr, nullptr, 32);
  }

  final_kernel<<<B_, 256, 0, stream>>>(o_ag, o_s, pooled, amask, wc, bc, dout);
}

// Round 6
// 584.199 us; speedup vs baseline: 4.3398x; 1.1244x over previous
//
#include <hip/hip_runtime.h>

#define B_ 32
#define L_ 256
#define D_ 768
#define H_ 12
#define DK_ 64
#define MEM_ 384

typedef __attribute__((ext_vector_type(8))) short bfrag8;    // 8 bf16 (4 VGPRs)
typedef __attribute__((ext_vector_type(8))) unsigned short us8;
typedef __attribute__((ext_vector_type(4))) float f32x4;

// f32 -> bf16 round-to-nearest-even (finite inputs only)
__device__ inline unsigned short f2bf(float f) {
  unsigned u = __float_as_uint(f);
  return (unsigned short)((u + 0x7fffu + ((u >> 16) & 1u)) >> 16);
}
__device__ inline float bf2f(unsigned short u) {
  return __uint_as_float(((unsigned)u) << 16);
}
__device__ inline float tanh_fast(float x) {
  x = fminf(fmaxf(x, -30.f), 30.f);
  float e = __expf(2.f * x);
  return (e - 1.f) * __builtin_amdgcn_rcpf(e + 1.f);
}

// ---------------- block reduce helpers (256 threads = 4 waves) ----------------
__device__ inline float waveRedSum(float v) {
#pragma unroll
  for (int o = 32; o; o >>= 1) v += __shfl_xor(v, o, 64);
  return v;
}
__device__ inline float waveRedMax(float v) {
#pragma unroll
  for (int o = 32; o; o >>= 1) v = fmaxf(v, __shfl_xor(v, o, 64));
  return v;
}
__device__ inline float blkRedSum(float v, float* red) {
  v = waveRedSum(v);
  int w = threadIdx.x >> 6;
  __syncthreads();
  if ((threadIdx.x & 63) == 0) red[w] = v;
  __syncthreads();
  return red[0] + red[1] + red[2] + red[3];
}
__device__ inline float blkRedMax(float v, float* red) {
  v = waveRedMax(v);
  int w = threadIdx.x >> 6;
  __syncthreads();
  if ((threadIdx.x & 63) == 0) red[w] = v;
  __syncthreads();
  return fmaxf(fmaxf(red[0], red[1]), fmaxf(red[2], red[3]));
}

// ---------------- LayerNorm (dual f32 + bf16 output) ----------------
__global__ __launch_bounds__(256) void ln_kernel(const float* __restrict__ in,
                                                 const float* __restrict__ g,
                                                 const float* __restrict__ bt,
                                                 float* __restrict__ out,
                                                 unsigned short* __restrict__ outbf) {
  long row = blockIdx.x;
  const float* p = in + row * D_;
  float v[3];
#pragma unroll
  for (int i = 0; i < 3; ++i) v[i] = p[threadIdx.x + i * 256];
  __shared__ float red[4];
  float s = v[0] + v[1] + v[2];
  s = blkRedSum(s, red);
  float mu = s * (1.f / D_);
  float ss = 0.f;
#pragma unroll
  for (int i = 0; i < 3; ++i) { float d = v[i] - mu; ss += d * d; }
  ss = blkRedSum(ss, red);
  float sd = sqrtf(ss * (1.f / (D_ - 1)));
  float inv = 1.f / (sd + 1e-6f);
#pragma unroll
  for (int i = 0; i < 3; ++i) {
    int c = threadIdx.x + i * 256;
    float o = g[c] * (v[i] - mu) * inv + bt[c];
    out[row * D_ + c] = o;
    outbf[row * D_ + c] = f2bf(o);
  }
}

// ---------------- transpose + convert: dst[C][R] bf16 = src[R][C] f32 ----------------
__global__ __launch_bounds__(256) void tc_pair(const float* __restrict__ s1,
                                               unsigned short* __restrict__ d1,
                                               const float* __restrict__ s2,
                                               unsigned short* __restrict__ d2,
                                               int R, int C) {
  const float* src = blockIdx.z ? s2 : s1;
  unsigned short* dst = blockIdx.z ? d2 : d1;
  __shared__ float tile[64][65];
  int c0 = blockIdx.x * 64, r0 = blockIdx.y * 64;
  int tx = threadIdx.x & 63, ty = threadIdx.x >> 6;
#pragma unroll
  for (int i = 0; i < 16; ++i)
    tile[ty + i * 4][tx] = src[(long)(r0 + ty + i * 4) * C + c0 + tx];
  __syncthreads();
#pragma unroll
  for (int i = 0; i < 16; ++i)
    dst[(long)(c0 + ty + i * 4) * R + r0 + tx] = f2bf(tile[tx][ty + i * 4]);
}

// ---------------- generic tiled SGEMM (kept for N=64 asp GEMM) ----------------
__global__ __launch_bounds__(256) void gemm64(
    const float* __restrict__ A, const float* __restrict__ B, float* __restrict__ C,
    int M, int N, int K, long sA, long sB, long sC,
    const float* __restrict__ rowScale, const float* __restrict__ bias,
    const float* __restrict__ rowDiv, int relu, int transB) {
  const int tid = threadIdx.x;
  const int bn = blockIdx.x, bm = blockIdx.y, bz = blockIdx.z;
  A += (long)bz * sA; B += (long)bz * sB; C += (long)bz * sC;
  __shared__ float As[16][65];
  __shared__ float Bs[16][65];
  float acc[4][4] = {};
  const int tm = tid & 15, tn = tid >> 4;
  for (int k0 = 0; k0 < K; k0 += 16) {
#pragma unroll
    for (int i = 0; i < 4; ++i) {
      int idx = tid + i * 256;
      int r = idx >> 4, c = idx & 15;
      As[c][r] = A[(long)(bm * 64 + r) * K + k0 + c];
    }
    if (!transB) {
#pragma unroll
      for (int i = 0; i < 4; ++i) {
        int idx = tid + i * 256;
        int r = idx >> 6, c = idx & 63;
        Bs[r][c] = B[(long)(k0 + r) * N + bn * 64 + c];
      }
    } else {
#pragma unroll
      for (int i = 0; i < 4; ++i) {
        int idx = tid + i * 256;
        int r = idx >> 4, c = idx & 15;
        Bs[c][r] = B[(long)(bn * 64 + r) * K + k0 + c];
      }
    }
    __syncthreads();
#pragma unroll
    for (int kk = 0; kk < 16; ++kk) {
      float a[4], bb[4];
#pragma unroll
      for (int i = 0; i < 4; ++i) a[i] = As[kk][tm * 4 + i];
#pragma unroll
      for (int j = 0; j < 4; ++j) bb[j] = Bs[kk][tn * 4 + j];
#pragma unroll
      for (int i = 0; i < 4; ++i)
#pragma unroll
        for (int j = 0; j < 4; ++j) acc[i][j] += a[i] * bb[j];
    }
    __syncthreads();
  }
#pragma unroll
  for (int i = 0; i < 4; ++i) {
    int r = bm * 64 + tm * 4 + i;
    long grow = (long)bz * M + r;
    float rs = rowScale ? rowScale[grow] : 1.f;
    float rd = rowDiv ? 1.f / rowDiv[grow] : 1.f;
#pragma unroll
    for (int j = 0; j < 4; ++j) {
      int cn = bn * 64 + tn * 4 + j;
      float v = acc[i][j] * rs;
      if (bias) v += bias[cn];
      v *= rd;
      if (relu) v = fmaxf(v, 0.f);
      C[(long)r * N + cn] = v;
    }
  }
}

// ---------------- all-bf16 MFMA GEMM: 128x128 tile, BK=32, 4 waves (2x2) -------------
// A bf16 [m][k]; Bt bf16 [n][k] (both k-contiguous). Outputs: C f32, Cbf row-major
// bf16, CT bf16 transposed-per-256-row-group: CT[(row>>8)*sCT + col*256 + (row&255)].
// Second operand set (z >= zsplit) pairs two independent same-shape GEMMs.
__global__ __launch_bounds__(256) void gemm_bb(
    const unsigned short* __restrict__ A, const unsigned short* __restrict__ Bt,
    float* __restrict__ C, unsigned short* __restrict__ Cbf,
    unsigned short* __restrict__ CT,
    int M, int N, int K, long sA, long sB, long sC, long sCT,
    const float* __restrict__ bias, const float* __restrict__ rowDiv, int relu,
    const unsigned short* __restrict__ A2, const unsigned short* __restrict__ Bt2,
    float* __restrict__ C2, unsigned short* __restrict__ Cbf2,
    unsigned short* __restrict__ CT2,
    const float* __restrict__ bias2, const float* __restrict__ rowDiv2, int zsplit) {
  __shared__ unsigned short smem[2 * 128 * 40];
  auto As = (unsigned short(*)[40])smem;
  auto Bs = (unsigned short(*)[40])(smem + 128 * 40);
  const int tid = threadIdx.x;
  const int bn = blockIdx.x, bm = blockIdx.y;
  int bz = blockIdx.z;
  const unsigned short* Ap = A; const unsigned short* Btp = Bt;
  float* Cp = C; unsigned short* Cbp = Cbf; unsigned short* CTp = CT;
  const float* biasp = bias; const float* rowDivp = rowDiv;
  if (zsplit > 0 && bz >= zsplit) {
    bz -= zsplit;
    Ap = A2; Btp = Bt2; Cp = C2; Cbp = Cbf2; CTp = CT2; biasp = bias2; rowDivp = rowDiv2;
  }
  Ap += (long)bz * sA; Btp += (long)bz * sB;
  if (Cp) Cp += (long)bz * sC;
  if (Cbp) Cbp += (long)bz * sC;
  if (CTp) CTp += (long)bz * sCT;

  f32x4 acc[4][4] = {};
  const int l = tid & 63, w = tid >> 6;
  const int wr = w >> 1, wc = w & 1;
  const int lr = l & 15, kg = (l >> 4) * 8;
  const int ar = tid >> 1, ah = tid & 1;

  for (int k0 = 0; k0 < K; k0 += 32) {
    {
      const unsigned short* sa = Ap + (long)(bm * 128 + ar) * K + k0 + ah * 16;
      *(us8*)&As[ar][ah * 16] = ((const us8*)sa)[0];
      *(us8*)&As[ar][ah * 16 + 8] = ((const us8*)sa)[1];
      const unsigned short* sb = Btp + (long)(bn * 128 + ar) * K + k0 + ah * 16;
      *(us8*)&Bs[ar][ah * 16] = ((const us8*)sb)[0];
      *(us8*)&Bs[ar][ah * 16 + 8] = ((const us8*)sb)[1];
    }
    __syncthreads();
    bfrag8 af[4], bf[4];
#pragma unroll
    for (int m = 0; m < 4; ++m) af[m] = *(const bfrag8*)&As[wr * 64 + m * 16 + lr][kg];
#pragma unroll
    for (int n = 0; n < 4; ++n) bf[n] = *(const bfrag8*)&Bs[wc * 64 + n * 16 + lr][kg];
#pragma unroll
    for (int m = 0; m < 4; ++m)
#pragma unroll
      for (int n = 0; n < 4; ++n)
        acc[m][n] = __builtin_amdgcn_mfma_f32_16x16x32_bf16(af[m], bf[n], acc[m][n], 0, 0, 0);
    __syncthreads();
  }

  // ---- row/col epilogue (f32 / bf16 row-major) ----
  if (Cp || Cbp) {
#pragma unroll
    for (int m = 0; m < 4; ++m) {
#pragma unroll
      for (int r = 0; r < 4; ++r) {
        int row = bm * 128 + wr * 64 + m * 16 + (l >> 4) * 4 + r;
        float rd = rowDivp ? 1.f / rowDivp[(long)bz * M + row] : 1.f;
#pragma unroll
        for (int n = 0; n < 4; ++n) {
          int col = bn * 128 + wc * 64 + n * 16 + lr;
          float v = acc[m][n][r];
          if (biasp) v += biasp[col];
          v *= rd;
          if (relu) v = fmaxf(v, 0.f);
          if (Cp) Cp[(long)row * N + col] = v;
          if (Cbp) Cbp[(long)row * N + col] = f2bf(v);
        }
      }
    }
  }
  // ---- transposed bf16 epilogue via LDS (two 64-col chunks) ----
  if (CT) {
    auto Ts = (unsigned short(*)[136])smem;  // 64 x 136 shorts = 17.4 KB
#pragma unroll
    for (int ch = 0; ch < 2; ++ch) {
      __syncthreads();
      if (wc == ch) {
#pragma unroll
        for (int m = 0; m < 4; ++m) {
#pragma unroll
          for (int r = 0; r < 4; ++r) {
            int rowl = wr * 64 + m * 16 + (l >> 4) * 4 + r;
            float rd = rowDivp ? 1.f / rowDivp[(long)bz * M + bm * 128 + rowl] : 1.f;
#pragma unroll
            for (int n = 0; n < 4; ++n) {
              int col = bn * 128 + wc * 64 + n * 16 + lr;
              float v = acc[m][n][r];
              if (biasp) v += biasp[col];
              v *= rd;
              if (relu) v = fmaxf(v, 0.f);
              Ts[n * 16 + lr][rowl] = f2bf(v);
            }
          }
        }
      }
      __syncthreads();
      int trow = tid >> 2, tc = (tid & 3) * 32;
      int colg = bn * 128 + ch * 64 + trow;
      int rowg = bm * 128 + tc;
      unsigned short* dp = CTp + (long)(rowg >> 8) * sCT + (long)colg * 256 + (rowg & 255);
#pragma unroll
      for (int j = 0; j < 4; ++j)
        *(us8*)(dp + j * 8) = *(const us8*)&Ts[trow][tc + j * 8];
    }
  }
}

// ---------------- fused MFMA attention (dual f32 + bf16 adj_s) ----------------
__global__ __launch_bounds__(256) void attn_mfma(const unsigned short* __restrict__ qbf,
                                                 const unsigned short* __restrict__ kbf,
                                                 const float* __restrict__ srcm,
                                                 float* __restrict__ adj_s,
                                                 unsigned short* __restrict__ adjsbf) {
  int blk = blockIdx.x;
  int b = blk >> 4, l0 = (blk & 15) << 4;
  int t = threadIdx.x;
  int w = t >> 6, l = t & 63;
  int lr = l & 15, kg = (l >> 4) * 8;
  int rbase = (l >> 4) * 4;
  __shared__ float redmx[4][16];
  __shared__ float redsm[4][16];
  float acc[4][4] = {};
  float cmv[4];
#pragma unroll
  for (int ct = 0; ct < 4; ++ct) cmv[ct] = srcm[b * L_ + w * 64 + ct * 16 + lr];

  for (int h = 0; h < H_; ++h) {
    const unsigned short* ap = qbf + ((long)b * L_ + l0 + lr) * D_ + h * 64 + kg;
    bfrag8 af0 = *(const bfrag8*)ap;
    bfrag8 af1 = *(const bfrag8*)(ap + 32);
    float sv[4][4];
#pragma unroll
    for (int ct = 0; ct < 4; ++ct) {
      const unsigned short* bp =
          kbf + ((long)b * L_ + w * 64 + ct * 16 + lr) * D_ + h * 64 + kg;
      bfrag8 bf0 = *(const bfrag8*)bp;
      bfrag8 bf1 = *(const bfrag8*)(bp + 32);
      f32x4 c = {};
      c = __builtin_amdgcn_mfma_f32_16x16x32_bf16(af0, bf0, c, 0, 0, 0);
      c = __builtin_amdgcn_mfma_f32_16x16x32_bf16(af1, bf1, c, 0, 0, 0);
#pragma unroll
      for (int r = 0; r < 4; ++r)
        sv[ct][r] = (cmv[ct] == 0.f) ? -1e9f : c[r] * 0.125f;
    }
#pragma unroll
    for (int r = 0; r < 4; ++r) {
      float mx = fmaxf(fmaxf(sv[0][r], sv[1][r]), fmaxf(sv[2][r], sv[3][r]));
#pragma unroll
      for (int o = 1; o < 16; o <<= 1) mx = fmaxf(mx, __shfl_xor(mx, o, 64));
      if (lr == 0) redmx[w][rbase + r] = mx;
    }
    __syncthreads();
#pragma unroll
    for (int r = 0; r < 4; ++r) {
      float mx = fmaxf(fmaxf(redmx[0][rbase + r], redmx[1][rbase + r]),
                       fmaxf(redmx[2][rbase + r], redmx[3][rbase + r]));
      float s = 0.f;
#pragma unroll
      for (int ct = 0; ct < 4; ++ct) {
        float e = __expf(sv[ct][r] - mx);
        sv[ct][r] = e;
        s += e;
      }
#pragma unroll
      for (int o = 1; o < 16; o <<= 1) s += __shfl_xor(s, o, 64);
      if (lr == 0) redsm[w][rbase + r] = s;
    }
    __syncthreads();
#pragma unroll
    for (int r = 0; r < 4; ++r) {
      float tot = redsm[0][rbase + r] + redsm[1][rbase + r] +
                  redsm[2][rbase + r] + redsm[3][rbase + r];
      float inv = 1.f / tot;
#pragma unroll
      for (int ct = 0; ct < 4; ++ct) acc[ct][r] += sv[ct][r] * inv;
    }
  }

#pragma unroll
  for (int r = 0; r < 4; ++r) {
    int row = l0 + rbase + r;
    float rm = srcm[b * L_ + row];
#pragma unroll
    for (int ct = 0; ct < 4; ++ct) {
      int col = w * 64 + ct * 16 + lr;
      float v = acc[ct][r] * (1.f / H_);
      if (col == row) v = 1.f;
      v *= rm;
      long idx = ((long)b * L_ + row) * L_ + col;
      adj_s[idx] = v;
      adjsbf[idx] = f2bf(v);
    }
  }
}

// ---------------- fused S-GEMM + row softmax (all-bf16 in): P = softmax(u @ g^T) -------
__global__ __launch_bounds__(256) void gemm_sfmx(
    const unsigned short* __restrict__ u1, const unsigned short* __restrict__ g1,
    unsigned short* __restrict__ P1,
    const unsigned short* __restrict__ u2, const unsigned short* __restrict__ g2,
    unsigned short* __restrict__ P2) {
  int bm = blockIdx.x;
  int bz = blockIdx.y;
  const unsigned short* Ap; const unsigned short* Bp; unsigned short* Pp;
  if (bz < 32) {
    Ap = u1 + (long)bz * L_ * MEM_; Bp = g1 + (long)bz * L_ * MEM_;
    Pp = P1 + (long)bz * L_ * L_;
  } else {
    int z = bz - 32;
    Ap = u2 + (long)z * L_ * MEM_; Bp = g2 + (long)z * L_ * MEM_;
    Pp = P2 + (long)z * L_ * L_;
  }
  __shared__ unsigned short As[64][40];
  __shared__ unsigned short Bs[256][40];
  __shared__ float redm[2][64];
  __shared__ float reds[2][64];
  const int t = threadIdx.x;
  const int l = t & 63, w = t >> 6;
  const int wr = w >> 1, wc = w & 1;
  const int lr = l & 15, kg = (l >> 4) * 8;
  f32x4 acc[2][8] = {};
  const int arA = t >> 2, akA = (t & 3) * 8;

  for (int k0 = 0; k0 < MEM_; k0 += 32) {
    *(us8*)&As[arA][akA] = *(const us8*)(Ap + (long)(bm * 64 + arA) * MEM_ + k0 + akA);
#pragma unroll
    for (int j = 0; j < 4; ++j)
      *(us8*)&Bs[t][j * 8] = *(const us8*)(Bp + (long)t * MEM_ + k0 + j * 8);
    __syncthreads();
    bfrag8 af[2], bf[8];
#pragma unroll
    for (int m = 0; m < 2; ++m) af[m] = *(const bfrag8*)&As[wr * 32 + m * 16 + lr][kg];
#pragma unroll
    for (int n = 0; n < 8; ++n) bf[n] = *(const bfrag8*)&Bs[wc * 128 + n * 16 + lr][kg];
#pragma unroll
    for (int m = 0; m < 2; ++m)
#pragma unroll
      for (int n = 0; n < 8; ++n)
        acc[m][n] = __builtin_amdgcn_mfma_f32_16x16x32_bf16(af[m], bf[n], acc[m][n], 0, 0, 0);
    __syncthreads();
  }

#pragma unroll
  for (int m = 0; m < 2; ++m) {
#pragma unroll
    for (int r = 0; r < 4; ++r) {
      int lrow = wr * 32 + m * 16 + (l >> 4) * 4 + r;
      float mx = -1e30f;
#pragma unroll
      for (int n = 0; n < 8; ++n) mx = fmaxf(mx, acc[m][n][r]);
#pragma unroll
      for (int o = 1; o < 16; o <<= 1) mx = fmaxf(mx, __shfl_xor(mx, o, 64));
      if (lr == 0) redm[wc][lrow] = mx;
    }
  }
  __syncthreads();
#pragma unroll
  for (int m = 0; m < 2; ++m) {
#pragma unroll
    for (int r = 0; r < 4; ++r) {
      int lrow = wr * 32 + m * 16 + (l >> 4) * 4 + r;
      float mx = fmaxf(redm[0][lrow], redm[1][lrow]);
      float s = 0.f;
#pragma unroll
      for (int n = 0; n < 8; ++n) {
        float e = __expf(acc[m][n][r] - mx);
        acc[m][n][r] = e;
        s += e;
      }
#pragma unroll
      for (int o = 1; o < 16; o <<= 1) s += __shfl_xor(s, o, 64);
      if (lr == 0) reds[wc][lrow] = s;
    }
  }
  __syncthreads();
#pragma unroll
  for (int m = 0; m < 2; ++m) {
#pragma unroll
    for (int r = 0; r < 4; ++r) {
      int lrow = wr * 32 + m * 16 + (l >> 4) * 4 + r;
      float inv = 1.f / (reds[0][lrow] + reds[1][lrow]);
      int row = bm * 64 + lrow;
#pragma unroll
      for (int n = 0; n < 8; ++n) {
        int col = wc * 128 + n * 16 + lr;
        Pp[(long)row * L_ + col] = f2bf(acc[m][n][r] * inv);
      }
    }
  }
}

// ---------------- tmpA[b,h] = asp[b] (L x 64) @ Wm[h] (64 x 64), bf16 out ----------------
__global__ __launch_bounds__(256) void asp_wm(const float* __restrict__ asp,
                                              const float* __restrict__ wm,
                                              unsigned short* __restrict__ tmpA) {
  int bh = blockIdx.x;
  int b = bh / H_, h = bh % H_;
  int t = threadIdx.x;
  __shared__ float WmS[64][64];
  __shared__ float aspS[64][64];
#pragma unroll
  for (int i = 0; i < 16; ++i) {
    int idx = t + i * 256;
    WmS[idx >> 6][idx & 63] = wm[h * 4096 + idx];
  }
  int e = t & 63, lr = t >> 6;
  for (int c = 0; c < 4; ++c) {
    __syncthreads();
#pragma unroll
    for (int i = 0; i < 16; ++i) {
      int idx = t + i * 256;
      aspS[idx >> 6][idx & 63] = asp[((long)b * L_ + c * 64 + (idx >> 6)) * 64 + (idx & 63)];
    }
    __syncthreads();
    for (int s = 0; s < 16; ++s) {
      int ll = s * 4 + lr;
      float accv = 0.f;
#pragma unroll
      for (int d = 0; d < 64; ++d) accv += aspS[ll][d] * WmS[d][e];
      tmpA[(((long)b * H_ + h) * L_ + c * 64 + ll) * 64 + e] = f2bf(accv);
    }
  }
}

// ---------------- asps_mean via MFMA ----------------
__global__ __launch_bounds__(256) void asps_mean_v2(
    const unsigned short* __restrict__ tmpA,
    const unsigned short* __restrict__ kbf,
    const float* __restrict__ bias_m,
    float* __restrict__ asps_mean) {
  int blk = blockIdx.x;
  int b = blk >> 4, l0 = (blk & 15) << 4;
  int t = threadIdx.x;
  int w = t >> 6, l = t & 63;
  int lr = l & 15, kg = (l >> 4) * 8;
  float bm = bias_m[0];
  float accg[4][4] = {};
  for (int h = 0; h < H_; ++h) {
    const unsigned short* ap = tmpA + (((long)b * H_ + h) * L_ + l0 + lr) * 64 + kg;
    bfrag8 af0 = *(const bfrag8*)ap;
    bfrag8 af1 = *(const bfrag8*)(ap + 32);
#pragma unroll
    for (int ct = 0; ct < 4; ++ct) {
      const unsigned short* bp =
          kbf + ((long)b * L_ + w * 64 + ct * 16 + lr) * D_ + h * 64 + kg;
      bfrag8 bf0 = *(const bfrag8*)bp;
      bfrag8 bf1 = *(const bfrag8*)(bp + 32);
      f32x4 accl = {};
      accl = __builtin_amdgcn_mfma_f32_16x16x32_bf16(af0, bf0, accl, 0, 0, 0);
      accl = __builtin_amdgcn_mfma_f32_16x16x32_bf16(af1, bf1, accl, 0, 0, 0);
#pragma unroll
      for (int r = 0; r < 4; ++r) accg[ct][r] += tanh_fast(accl[r] + bm);
    }
  }
#pragma unroll
  for (int ct = 0; ct < 4; ++ct) {
    int col = w * 64 + ct * 16 + lr;
#pragma unroll
    for (int r = 0; r < 4; ++r) {
      int row = l0 + (l >> 4) * 4 + r;
      asps_mean[((long)b * L_ + row) * L_ + col] = accg[ct][r] * (1.f / H_);
    }
  }
}

// ---------------- avgH ----------------
__global__ __launch_bounds__(256) void avgh_kernel(const float* __restrict__ asps_mean,
                                                   float* __restrict__ avgH) {
  int b = blockIdx.x, m = threadIdx.x;
  float s = 0.f;
  for (int l = 0; l < L_; ++l) s += asps_mean[((long)b * L_ + l) * L_ + m];
  avgH[b * L_ + m] = s * (1.f / L_);
}

// ---------------- adj_ag (dual f32 + bf16) ----------------
__global__ __launch_bounds__(256) void adjag_kernel(const float* __restrict__ asps_mean,
                                                    const float* __restrict__ avgH,
                                                    const float* __restrict__ amask,
                                                    const float* __restrict__ adjr,
                                                    float* __restrict__ adj_ag,
                                                    unsigned short* __restrict__ adjagbf) {
  long idx = (long)blockIdx.x * 256 + threadIdx.x;
  int m = idx & 255;
  long bl = idx >> 8;
  int l = (int)(bl & 255);
  int b = (int)(bl >> 8);
  bool rowa = amask[b * L_ + l] > 0.f;
  bool cola = amask[b * L_ + m] > 0.f;
  float asa;
  if (rowa && cola) asa = (l >= m) ? avgH[b * L_ + m] : avgH[b * L_ + l];
  else if (rowa)    asa = avgH[b * L_ + m];
  else if (cola)    asa = avgH[b * L_ + l];
  else              asa = asps_mean[idx];
  float r = (asa > 0.25f) ? 1.f : expf(adjr[idx]);
  float v = r * asa;
  adj_ag[idx] = v;
  adjagbf[idx] = f2bf(v);
}

// ---------------- KL partials + row denominators ----------------
__global__ __launch_bounds__(256) void kl_denom(const float* __restrict__ adj_s,
                                                const float* __restrict__ adj_ag,
                                                float* __restrict__ klpart,
                                                float* __restrict__ den_s,
                                                float* __restrict__ den_ag) {
  long row = blockIdx.x;
  int m = threadIdx.x;
  __shared__ float red[4];
  float s = adj_s[row * L_ + m];
  float a = adj_ag[row * L_ + m];
  float sum_s = blkRedSum(s, red);
  float sum_a = blkRedSum(a, red);
  float mx_s = blkRedMax(s, red);
  float mx_a = blkRedMax(a, red);
  float es = expf(s - mx_s), ea = expf(a - mx_a);
  float ses = blkRedSum(es, red);
  float sea = blkRedSum(ea, red);
  float logq = (s - mx_s) - logf(ses);
  float logp = (a - mx_a) - logf(sea);
  float term = (es / ses) * (logq - logp);
  float kp = blkRedSum(term, red);
  if (m == 0) {
    klpart[row] = kp;
    den_s[row] = sum_s + 1.f;
    den_ag[row] = sum_a + 1.f;
  }
}

__global__ __launch_bounds__(256) void kl_final(const float* __restrict__ klpart,
                                                float* __restrict__ dout) {
  __shared__ float red[4];
  float s = 0.f;
  for (int i = threadIdx.x; i < B_ * L_; i += 256) s += klpart[i];
  s = blkRedSum(s, red);
  if (threadIdx.x == 0) dout[96] = expf(-s * 0.1f);
}

// ---------------- classifier head (bf16 o inputs) ----------------
__global__ __launch_bounds__(256) void final_kernel(const unsigned short* __restrict__ o_ag,
                                                    const unsigned short* __restrict__ o_s,
                                                    const float* __restrict__ pooled,
                                                    const float* __restrict__ amask,
                                                    const float* __restrict__ wc,
                                                    const float* __restrict__ bc,
                                                    float* __restrict__ dout) {
  int b = blockIdx.x, t = threadIdx.x;
  __shared__ float cS[1536];
  __shared__ float maskS[256];
  __shared__ float red[4];
  maskS[t] = amask[b * L_ + t];
  float wn = blkRedSum(maskS[t], red);
  for (int e = t; e < MEM_; e += 256) {
    float s1 = 0.f, s2 = 0.f;
    for (int l = 0; l < L_; ++l) {
      float mk = maskS[l];
      if (mk != 0.f) {
        s1 += mk * bf2f(o_ag[((long)b * L_ + l) * MEM_ + e]);
        s2 += mk * bf2f(o_s[((long)b * L_ + l) * MEM_ + e]);
      }
    }
    cS[e] = s1 / wn;
    cS[MEM_ + e] = s2 / wn;
  }
  for (int j = t; j < D_; j += 256) cS[2 * MEM_ + j] = pooled[b * D_ + j];
  __syncthreads();
  float p0 = 0.f, p1 = 0.f, p2 = 0.f;
  for (int j = t; j < 1536; j += 256) {
    float v = cS[j];
    p0 += v * wc[j * 3 + 0];
    p1 += v * wc[j * 3 + 1];
    p2 += v * wc[j * 3 + 2];
  }
  p0 = blkRedSum(p0, red);
  p1 = blkRedSum(p1, red);
  p2 = blkRedSum(p2, red);
  if (t == 0) {
    dout[b * 3 + 0] = p0 + bc[0];
    dout[b * 3 + 1] = p1 + bc[1];
    dout[b * 3 + 2] = p2 + bc[2];
  }
}

extern "C" void kernel_launch(void* const* d_in, const int* in_sizes, int n_in,
                              void* d_out, int out_size, void* d_ws, size_t ws_size,
                              hipStream_t stream) {
  const float* seq    = (const float*)d_in[0];
  const float* pooled = (const float*)d_in[1];
  const float* adjr   = (const float*)d_in[2];
  const float* srcm   = (const float*)d_in[3];
  const float* amask  = (const float*)d_in[4];
  const float* ln_g   = (const float*)d_in[5];
  const float* ln_b   = (const float*)d_in[6];
  const float* wq     = (const float*)d_in[7];
  const float* bq     = (const float*)d_in[8];
  const float* wk     = (const float*)d_in[9];
  const float* bk     = (const float*)d_in[10];
  const float* wd     = (const float*)d_in[11];
  const float* bd     = (const float*)d_in[12];
  const float* wm     = (const float*)d_in[13];
  const float* bm     = (const float*)d_in[14];
  const float* wa0    = (const float*)d_in[15];
  const float* ba0    = (const float*)d_in[16];
  const float* wa1    = (const float*)d_in[17];
  const float* ba1    = (const float*)d_in[18];
  const float* ws0    = (const float*)d_in[19];
  const float* bs0    = (const float*)d_in[20];
  const float* ws1    = (const float*)d_in[21];
  const float* bs1    = (const float*)d_in[22];
  const float* aff1   = (const float*)d_in[23];
  const float* aff2   = (const float*)d_in[24];
  const float* wc     = (const float*)d_in[25];
  const float* bc     = (const float*)d_in[26];

  float* ws = (float*)d_ws;
  // ---- workspace layout (float units) ----
  float* S0 = ws;                        // 6291456: x f32 -> {o_agbf|o_sbf|gTag|gTs}
  float* S1 = S0 + 6291456;              // 3145728: xbf
  float* S2 = S1 + 3145728;              // 3145728: qbf -> tmpA -> {g_agbf|g_sbf}
  float* S3 = S2 + 3145728;              // 3145728: kbf -> {tTag|tTs} -> {u1bf|u2bf}
  float* S4 = S3 + 3145728;              // 524288 : asp f32
  float* S5 = S4 + 524288;               // 2097152: asps f32 -> {P1bf|P2bf}
  float* adj_s  = S5 + 2097152;          // 2097152
  float* adj_ag = adj_s + 2097152;       // 2097152
  unsigned short* adjsbf  = (unsigned short*)(adj_ag + 2097152);  // 2097152 sh
  unsigned short* adjagbf = adjsbf + 2097152;                     // 2097152 sh
  unsigned short* wT      = adjagbf + 2097152;                    // 2359296 sh
  unsigned short* wqT   = wT;
  unsigned short* wkT   = wT + 589824;
  unsigned short* wa0T  = wT + 1179648;
  unsigned short* ws0T  = wT + 1474560;
  unsigned short* wa1T  = wT + 1769472;
  unsigned short* ws1T  = wT + 1916928;
  unsigned short* aff1T = wT + 2064384;
  unsigned short* aff2T = wT + 2211840;
  float* tail   = (float*)(wT + 2359296);
  float* avgH   = tail;
  float* den_s  = avgH + 8192;
  float* den_ag = den_s + 8192;
  float* klp    = den_ag + 8192;

  float* x = S0;
  unsigned short* o_agbf = (unsigned short*)S0;
  unsigned short* o_sbf  = o_agbf + 3145728;
  unsigned short* gTag   = o_agbf + 6291456;
  unsigned short* gTs    = o_agbf + 9437184;
  unsigned short* xbf    = (unsigned short*)S1;
  unsigned short* qbf    = (unsigned short*)S2;
  unsigned short* tmpA   = (unsigned short*)S2;
  unsigned short* g_agbf = (unsigned short*)S2;
  unsigned short* g_sbf  = g_agbf + 3145728;
  unsigned short* kbf    = (unsigned short*)S3;
  unsigned short* tTag   = (unsigned short*)S3;
  unsigned short* tTs    = tTag + 3145728;
  unsigned short* u1bf   = (unsigned short*)S3;
  unsigned short* u2bf   = u1bf + 3145728;
  float* asp  = S4;
  float* asps = S5;
  unsigned short* P1bf = (unsigned short*)S5;
  unsigned short* P2bf = P1bf + 2097152;
  float* dout = (float*)d_out;

  const long sAdjSh = (long)L_ * L_;     // 65536 shorts per z
  const long sMemSh = (long)L_ * MEM_;   // 98304 shorts per z

  // ---- weight transpose/convert (once per call) ----
  tc_pair<<<dim3(12, 12, 2), 256, 0, stream>>>(wq, wqT, wk, wkT, 768, 768);
  tc_pair<<<dim3(6, 12, 2), 256, 0, stream>>>(wa0, wa0T, ws0, ws0T, 768, 384);
  tc_pair<<<dim3(6, 6, 2), 256, 0, stream>>>(wa1, wa1T, ws1, ws1T, 384, 384);
  tc_pair<<<dim3(6, 6, 2), 256, 0, stream>>>(aff1, aff1T, aff2, aff2T, 384, 384);

  ln_kernel<<<B_ * L_, 256, 0, stream>>>(seq, ln_g, ln_b, x, xbf);
  // paired q/k projections (bf16 in/out)
  gemm_bb<<<dim3(6, 64, 2), 256, 0, stream>>>(
      xbf, wqT, nullptr, qbf, nullptr, 8192, 768, 768, 0, 0, 0, 0, bq, nullptr, 0,
      xbf, wkT, nullptr, kbf, nullptr, bk, nullptr, 1);
  attn_mfma<<<B_ * 16, 256, 0, stream>>>(qbf, kbf, srcm, adj_s, adjsbf);
  gemm64<<<dim3(1, 128, 1), 256, 0, stream>>>(x, wd, asp, 8192, 64, 768, 0, 0, 0,
                                              amask, bd, nullptr, 0, 0);
  asp_wm<<<B_ * H_, 256, 0, stream>>>(asp, wm, tmpA);
  asps_mean_v2<<<B_ * 16, 256, 0, stream>>>(tmpA, kbf, bm, asps);
  avgh_kernel<<<B_, 256, 0, stream>>>(asps, avgH);
  adjag_kernel<<<B_ * L_ * L_ / 256, 256, 0, stream>>>(asps, avgH, amask, adjr,
                                                       adj_ag, adjagbf);
  kl_denom<<<B_ * L_, 256, 0, stream>>>(adj_s, adj_ag, klp, den_s, den_ag);
  kl_final<<<1, 256, 0, stream>>>(klp, dout);

  for (int li = 0; li < 2; ++li) {
    int Kd = li ? MEM_ : D_;
    const unsigned short* inag = li ? o_agbf : xbf;
    const unsigned short* ins  = li ? o_sbf : xbf;
    const unsigned short* wAT = li ? wa1T : wa0T;
    const float* bA = li ? ba1 : ba0;
    const unsigned short* wST = li ? ws1T : ws0T;
    const float* bS = li ? bs1 : bs0;
    // paired t-GEMMs -> transposed bf16 tT
    gemm_bb<<<dim3(3, 64, 2), 256, 0, stream>>>(
        inag, wAT, nullptr, nullptr, tTag, 8192, MEM_, Kd, 0, 0, 0, sMemSh,
        nullptr, nullptr, 0,
        ins, wST, nullptr, nullptr, tTs, nullptr, nullptr, 1);
    // paired g-GEMMs: g = relu((adj@t + b)/den), outputs g bf16 + gT bf16
    gemm_bb<<<dim3(3, 2, 64), 256, 0, stream>>>(
        adjagbf, tTag, nullptr, g_agbf, gTag, L_, MEM_, L_, sAdjSh, sMemSh, sMemSh,
        sMemSh, bA, den_ag, 1,
        adjsbf, tTs, nullptr, g_sbf, gTs, bS, den_s, 32);
    // paired u-GEMMs
    gemm_bb<<<dim3(3, 64, 2), 256, 0, stream>>>(
        g_agbf, aff1T, nullptr, u1bf, nullptr, 8192, MEM_, MEM_, 0, 0, 0, 0,
        nullptr, nullptr, 0,
        g_sbf, aff2T, nullptr, u2bf, nullptr, nullptr, nullptr, 1);
    // paired fused S+softmax
    gemm_sfmx<<<dim3(4, 64), 256, 0, stream>>>(u1bf, g_sbf, P1bf, u2bf, g_agbf, P2bf);
    // paired PV: o_ag = P1@g_s (B = gTs), o_s = P2@g_ag (B = gTag)
    gemm_bb<<<dim3(3, 2, 64), 256, 0, stream>>>(
        P1bf, gTs, nullptr, o_agbf, nullptr, L_, MEM_, L_, sAdjSh, sMemSh, sMemSh, 0,
        nullptr, nullptr, 0,
        P2bf, gTag, nullptr, o_sbf, nullptr, nullptr, nullptr, 32);
  }

  final_kernel<<<B_, 256, 0, stream>>>(o_agbf, o_sbf, pooled, amask, wc, bc, dout);
}

// Round 7
// 504.492 us; speedup vs baseline: 5.0255x; 1.1580x over previous
//
#include <hip/hip_runtime.h>

#define B_ 32
#define L_ 256
#define D_ 768
#define H_ 12
#define DK_ 64
#define MEM_ 384

typedef __attribute__((ext_vector_type(8))) short bfrag8;    // 8 bf16 (4 VGPRs)
typedef __attribute__((ext_vector_type(8))) unsigned short us8;
typedef __attribute__((ext_vector_type(4))) float f32x4;

// f32 -> bf16 round-to-nearest-even (finite inputs only)
__device__ inline unsigned short f2bf(float f) {
  unsigned u = __float_as_uint(f);
  return (unsigned short)((u + 0x7fffu + ((u >> 16) & 1u)) >> 16);
}
__device__ inline float bf2f(unsigned short u) {
  return __uint_as_float(((unsigned)u) << 16);
}
__device__ inline float tanh_fast(float x) {
  x = fminf(fmaxf(x, -30.f), 30.f);
  float e = __expf(2.f * x);
  return (e - 1.f) * __builtin_amdgcn_rcpf(e + 1.f);
}

// ---------------- block reduce helpers (256 threads = 4 waves) ----------------
__device__ inline float waveRedSum(float v) {
#pragma unroll
  for (int o = 32; o; o >>= 1) v += __shfl_xor(v, o, 64);
  return v;
}
__device__ inline float waveRedMax(float v) {
#pragma unroll
  for (int o = 32; o; o >>= 1) v = fmaxf(v, __shfl_xor(v, o, 64));
  return v;
}
__device__ inline float blkRedSum(float v, float* red) {
  v = waveRedSum(v);
  int w = threadIdx.x >> 6;
  __syncthreads();
  if ((threadIdx.x & 63) == 0) red[w] = v;
  __syncthreads();
  return red[0] + red[1] + red[2] + red[3];
}
__device__ inline float blkRedMax(float v, float* red) {
  v = waveRedMax(v);
  int w = threadIdx.x >> 6;
  __syncthreads();
  if ((threadIdx.x & 63) == 0) red[w] = v;
  __syncthreads();
  return fmaxf(fmaxf(red[0], red[1]), fmaxf(red[2], red[3]));
}

// ---------------- LayerNorm (dual f32 + bf16 output) ----------------
__global__ __launch_bounds__(256) void ln_kernel(const float* __restrict__ in,
                                                 const float* __restrict__ g,
                                                 const float* __restrict__ bt,
                                                 float* __restrict__ out,
                                                 unsigned short* __restrict__ outbf) {
  long row = blockIdx.x;
  const float* p = in + row * D_;
  float v[3];
#pragma unroll
  for (int i = 0; i < 3; ++i) v[i] = p[threadIdx.x + i * 256];
  __shared__ float red[4];
  float s = v[0] + v[1] + v[2];
  s = blkRedSum(s, red);
  float mu = s * (1.f / D_);
  float ss = 0.f;
#pragma unroll
  for (int i = 0; i < 3; ++i) { float d = v[i] - mu; ss += d * d; }
  ss = blkRedSum(ss, red);
  float sd = sqrtf(ss * (1.f / (D_ - 1)));
  float inv = 1.f / (sd + 1e-6f);
#pragma unroll
  for (int i = 0; i < 3; ++i) {
    int c = threadIdx.x + i * 256;
    float o = g[c] * (v[i] - mu) * inv + bt[c];
    out[row * D_ + c] = o;
    outbf[row * D_ + c] = f2bf(o);
  }
}

// ---------------- transpose + convert: dst[C][R] bf16 = src[R][C] f32 ----------------
__global__ __launch_bounds__(256) void tc_pair(const float* __restrict__ s1,
                                               unsigned short* __restrict__ d1,
                                               const float* __restrict__ s2,
                                               unsigned short* __restrict__ d2,
                                               int R, int C) {
  const float* src = blockIdx.z ? s2 : s1;
  unsigned short* dst = blockIdx.z ? d2 : d1;
  __shared__ float tile[64][65];
  int c0 = blockIdx.x * 64, r0 = blockIdx.y * 64;
  int tx = threadIdx.x & 63, ty = threadIdx.x >> 6;
#pragma unroll
  for (int i = 0; i < 16; ++i)
    tile[ty + i * 4][tx] = src[(long)(r0 + ty + i * 4) * C + c0 + tx];
  __syncthreads();
#pragma unroll
  for (int i = 0; i < 16; ++i)
    dst[(long)(c0 + ty + i * 4) * R + r0 + tx] = f2bf(tile[tx][ty + i * 4]);
}

// ---------------- per-head transpose: wmT[h][e][d] = wm[h][d][e], bf16 ----------------
__global__ __launch_bounds__(256) void tc_wm(const float* __restrict__ wm,
                                             unsigned short* __restrict__ wmT) {
  int h = blockIdx.x;
  __shared__ float tile[64][65];
  int tx = threadIdx.x & 63, ty = threadIdx.x >> 6;
#pragma unroll
  for (int i = 0; i < 16; ++i)
    tile[ty + i * 4][tx] = wm[h * 4096 + (ty + i * 4) * 64 + tx];
  __syncthreads();
#pragma unroll
  for (int i = 0; i < 16; ++i)
    wmT[h * 4096 + (ty + i * 4) * 64 + tx] = f2bf(tile[tx][ty + i * 4]);
}

// ---------------- asp = bf16(mask_row * (x @ wd) + bd), MFMA, no LDS ----------------
// grid 512: block = 16 rows; 4 waves x 16 cols.
__global__ __launch_bounds__(256) void asp_mfma(const unsigned short* __restrict__ xbf,
                                                const unsigned short* __restrict__ wdT,
                                                const float* __restrict__ amask,
                                                const float* __restrict__ bd,
                                                unsigned short* __restrict__ aspbf) {
  int l0 = blockIdx.x << 4;
  int t = threadIdx.x;
  int w = t >> 6, l = t & 63;
  int lr = l & 15, kg = (l >> 4) * 8;
  const unsigned short* ap = xbf + (long)(l0 + lr) * D_ + kg;
  const unsigned short* bp = wdT + (long)(w * 16 + lr) * D_ + kg;
  f32x4 acc = {};
#pragma unroll
  for (int k0 = 0; k0 < D_; k0 += 32) {
    bfrag8 af = *(const bfrag8*)(ap + k0);
    bfrag8 bf = *(const bfrag8*)(bp + k0);
    acc = __builtin_amdgcn_mfma_f32_16x16x32_bf16(af, bf, acc, 0, 0, 0);
  }
  int col = w * 16 + lr;
#pragma unroll
  for (int r = 0; r < 4; ++r) {
    int row = l0 + (l >> 4) * 4 + r;
    float v = acc[r] * amask[row] + bd[col];
    aspbf[(long)row * DK_ + col] = f2bf(v);
  }
}

// ---------------- tmpA[b,h] = aspbf[b] @ Wm[h], MFMA, no LDS ----------------
// grid B*H: 4 waves, wave w = rows w*64..w*64+63, all 64 cols.
__global__ __launch_bounds__(256) void asp_wm_v2(const unsigned short* __restrict__ aspbf,
                                                 const unsigned short* __restrict__ wmT,
                                                 unsigned short* __restrict__ tmpA) {
  int bh = blockIdx.x;
  int b = bh / H_, h = bh % H_;
  int t = threadIdx.x;
  int w = t >> 6, l = t & 63;
  int lr = l & 15, kg = (l >> 4) * 8;
  const unsigned short* wp = wmT + h * 4096;
  f32x4 acc[4][4] = {};
#pragma unroll
  for (int ks = 0; ks < 2; ++ks) {
    int k0 = ks * 32;
    bfrag8 af[4], bf[4];
#pragma unroll
    for (int m = 0; m < 4; ++m)
      af[m] = *(const bfrag8*)(aspbf + (long)(b * L_ + w * 64 + m * 16 + lr) * DK_ + k0 + kg);
#pragma unroll
    for (int n = 0; n < 4; ++n)
      bf[n] = *(const bfrag8*)(wp + (n * 16 + lr) * 64 + k0 + kg);
#pragma unroll
    for (int m = 0; m < 4; ++m)
#pragma unroll
      for (int n = 0; n < 4; ++n)
        acc[m][n] = __builtin_amdgcn_mfma_f32_16x16x32_bf16(af[m], bf[n], acc[m][n], 0, 0, 0);
  }
#pragma unroll
  for (int m = 0; m < 4; ++m)
#pragma unroll
    for (int n = 0; n < 4; ++n)
#pragma unroll
      for (int r = 0; r < 4; ++r) {
        int row = w * 64 + m * 16 + (l >> 4) * 4 + r;
        int col = n * 16 + lr;
        tmpA[(((long)b * H_ + h) * L_ + row) * DK_ + col] = f2bf(acc[m][n][r]);
      }
}

// ---------------- all-bf16 MFMA GEMM: 128x128 tile, BK=32, 4 waves (2x2) -------------
__global__ __launch_bounds__(256) void gemm_bb(
    const unsigned short* __restrict__ A, const unsigned short* __restrict__ Bt,
    float* __restrict__ C, unsigned short* __restrict__ Cbf,
    unsigned short* __restrict__ CT,
    int M, int N, int K, long sA, long sB, long sC, long sCT,
    const float* __restrict__ bias, const float* __restrict__ rowDiv, int relu,
    const unsigned short* __restrict__ A2, const unsigned short* __restrict__ Bt2,
    float* __restrict__ C2, unsigned short* __restrict__ Cbf2,
    unsigned short* __restrict__ CT2,
    const float* __restrict__ bias2, const float* __restrict__ rowDiv2, int zsplit) {
  __shared__ unsigned short smem[2 * 128 * 40];
  auto As = (unsigned short(*)[40])smem;
  auto Bs = (unsigned short(*)[40])(smem + 128 * 40);
  const int tid = threadIdx.x;
  const int bn = blockIdx.x, bm = blockIdx.y;
  int bz = blockIdx.z;
  const unsigned short* Ap = A; const unsigned short* Btp = Bt;
  float* Cp = C; unsigned short* Cbp = Cbf; unsigned short* CTp = CT;
  const float* biasp = bias; const float* rowDivp = rowDiv;
  if (zsplit > 0 && bz >= zsplit) {
    bz -= zsplit;
    Ap = A2; Btp = Bt2; Cp = C2; Cbp = Cbf2; CTp = CT2; biasp = bias2; rowDivp = rowDiv2;
  }
  Ap += (long)bz * sA; Btp += (long)bz * sB;
  if (Cp) Cp += (long)bz * sC;
  if (Cbp) Cbp += (long)bz * sC;
  if (CTp) CTp += (long)bz * sCT;

  f32x4 acc[4][4] = {};
  const int l = tid & 63, w = tid >> 6;
  const int wr = w >> 1, wc = w & 1;
  const int lr = l & 15, kg = (l >> 4) * 8;
  const int ar = tid >> 1, ah = tid & 1;

  for (int k0 = 0; k0 < K; k0 += 32) {
    {
      const unsigned short* sa = Ap + (long)(bm * 128 + ar) * K + k0 + ah * 16;
      *(us8*)&As[ar][ah * 16] = ((const us8*)sa)[0];
      *(us8*)&As[ar][ah * 16 + 8] = ((const us8*)sa)[1];
      const unsigned short* sb = Btp + (long)(bn * 128 + ar) * K + k0 + ah * 16;
      *(us8*)&Bs[ar][ah * 16] = ((const us8*)sb)[0];
      *(us8*)&Bs[ar][ah * 16 + 8] = ((const us8*)sb)[1];
    }
    __syncthreads();
    bfrag8 af[4], bf[4];
#pragma unroll
    for (int m = 0; m < 4; ++m) af[m] = *(const bfrag8*)&As[wr * 64 + m * 16 + lr][kg];
#pragma unroll
    for (int n = 0; n < 4; ++n) bf[n] = *(const bfrag8*)&Bs[wc * 64 + n * 16 + lr][kg];
#pragma unroll
    for (int m = 0; m < 4; ++m)
#pragma unroll
      for (int n = 0; n < 4; ++n)
        acc[m][n] = __builtin_amdgcn_mfma_f32_16x16x32_bf16(af[m], bf[n], acc[m][n], 0, 0, 0);
    __syncthreads();
  }

  if (Cp || Cbp) {
#pragma unroll
    for (int m = 0; m < 4; ++m) {
#pragma unroll
      for (int r = 0; r < 4; ++r) {
        int row = bm * 128 + wr * 64 + m * 16 + (l >> 4) * 4 + r;
        float rd = rowDivp ? 1.f / rowDivp[(long)bz * M + row] : 1.f;
#pragma unroll
        for (int n = 0; n < 4; ++n) {
          int col = bn * 128 + wc * 64 + n * 16 + lr;
          float v = acc[m][n][r];
          if (biasp) v += biasp[col];
          v *= rd;
          if (relu) v = fmaxf(v, 0.f);
          if (Cp) Cp[(long)row * N + col] = v;
          if (Cbp) Cbp[(long)row * N + col] = f2bf(v);
        }
      }
    }
  }
  if (CT) {
    auto Ts = (unsigned short(*)[136])smem;
#pragma unroll
    for (int ch = 0; ch < 2; ++ch) {
      __syncthreads();
      if (wc == ch) {
#pragma unroll
        for (int m = 0; m < 4; ++m) {
#pragma unroll
          for (int r = 0; r < 4; ++r) {
            int rowl = wr * 64 + m * 16 + (l >> 4) * 4 + r;
            float rd = rowDivp ? 1.f / rowDivp[(long)bz * M + bm * 128 + rowl] : 1.f;
#pragma unroll
            for (int n = 0; n < 4; ++n) {
              int col = bn * 128 + wc * 64 + n * 16 + lr;
              float v = acc[m][n][r];
              if (biasp) v += biasp[col];
              v *= rd;
              if (relu) v = fmaxf(v, 0.f);
              Ts[n * 16 + lr][rowl] = f2bf(v);
            }
          }
        }
      }
      __syncthreads();
      int trow = tid >> 2, tc = (tid & 3) * 32;
      int colg = bn * 128 + ch * 64 + trow;
      int rowg = bm * 128 + tc;
      unsigned short* dp = CTp + (long)(rowg >> 8) * sCT + (long)colg * 256 + (rowg & 255);
#pragma unroll
      for (int j = 0; j < 4; ++j)
        *(us8*)(dp + j * 8) = *(const us8*)&Ts[trow][tc + j * 8];
    }
  }
}

// ---------------- fused MFMA attention (dual f32 + bf16 adj_s) ----------------
__global__ __launch_bounds__(256) void attn_mfma(const unsigned short* __restrict__ qbf,
                                                 const unsigned short* __restrict__ kbf,
                                                 const float* __restrict__ srcm,
                                                 float* __restrict__ adj_s,
                                                 unsigned short* __restrict__ adjsbf) {
  int blk = blockIdx.x;
  int b = blk >> 4, l0 = (blk & 15) << 4;
  int t = threadIdx.x;
  int w = t >> 6, l = t & 63;
  int lr = l & 15, kg = (l >> 4) * 8;
  int rbase = (l >> 4) * 4;
  __shared__ float redmx[4][16];
  __shared__ float redsm[4][16];
  float acc[4][4] = {};
  float cmv[4];
#pragma unroll
  for (int ct = 0; ct < 4; ++ct) cmv[ct] = srcm[b * L_ + w * 64 + ct * 16 + lr];

  for (int h = 0; h < H_; ++h) {
    const unsigned short* ap = qbf + ((long)b * L_ + l0 + lr) * D_ + h * 64 + kg;
    bfrag8 af0 = *(const bfrag8*)ap;
    bfrag8 af1 = *(const bfrag8*)(ap + 32);
    float sv[4][4];
#pragma unroll
    for (int ct = 0; ct < 4; ++ct) {
      const unsigned short* bp =
          kbf + ((long)b * L_ + w * 64 + ct * 16 + lr) * D_ + h * 64 + kg;
      bfrag8 bf0 = *(const bfrag8*)bp;
      bfrag8 bf1 = *(const bfrag8*)(bp + 32);
      f32x4 c = {};
      c = __builtin_amdgcn_mfma_f32_16x16x32_bf16(af0, bf0, c, 0, 0, 0);
      c = __builtin_amdgcn_mfma_f32_16x16x32_bf16(af1, bf1, c, 0, 0, 0);
#pragma unroll
      for (int r = 0; r < 4; ++r)
        sv[ct][r] = (cmv[ct] == 0.f) ? -1e9f : c[r] * 0.125f;
    }
#pragma unroll
    for (int r = 0; r < 4; ++r) {
      float mx = fmaxf(fmaxf(sv[0][r], sv[1][r]), fmaxf(sv[2][r], sv[3][r]));
#pragma unroll
      for (int o = 1; o < 16; o <<= 1) mx = fmaxf(mx, __shfl_xor(mx, o, 64));
      if (lr == 0) redmx[w][rbase + r] = mx;
    }
    __syncthreads();
#pragma unroll
    for (int r = 0; r < 4; ++r) {
      float mx = fmaxf(fmaxf(redmx[0][rbase + r], redmx[1][rbase + r]),
                       fmaxf(redmx[2][rbase + r], redmx[3][rbase + r]));
      float s = 0.f;
#pragma unroll
      for (int ct = 0; ct < 4; ++ct) {
        float e = __expf(sv[ct][r] - mx);
        sv[ct][r] = e;
        s += e;
      }
#pragma unroll
      for (int o = 1; o < 16; o <<= 1) s += __shfl_xor(s, o, 64);
      if (lr == 0) redsm[w][rbase + r] = s;
    }
    __syncthreads();
#pragma unroll
    for (int r = 0; r < 4; ++r) {
      float tot = redsm[0][rbase + r] + redsm[1][rbase + r] +
                  redsm[2][rbase + r] + redsm[3][rbase + r];
      float inv = 1.f / tot;
#pragma unroll
      for (int ct = 0; ct < 4; ++ct) acc[ct][r] += sv[ct][r] * inv;
    }
  }

#pragma unroll
  for (int r = 0; r < 4; ++r) {
    int row = l0 + rbase + r;
    float rm = srcm[b * L_ + row];
#pragma unroll
    for (int ct = 0; ct < 4; ++ct) {
      int col = w * 64 + ct * 16 + lr;
      float v = acc[ct][r] * (1.f / H_);
      if (col == row) v = 1.f;
      v *= rm;
      long idx = ((long)b * L_ + row) * L_ + col;
      adj_s[idx] = v;
      adjsbf[idx] = f2bf(v);
    }
  }
}

// ---------------- fused S-GEMM + row softmax (all-bf16 in): P = softmax(u @ g^T) -------
__global__ __launch_bounds__(256) void gemm_sfmx(
    const unsigned short* __restrict__ u1, const unsigned short* __restrict__ g1,
    unsigned short* __restrict__ P1,
    const unsigned short* __restrict__ u2, const unsigned short* __restrict__ g2,
    unsigned short* __restrict__ P2) {
  int bm = blockIdx.x;
  int bz = blockIdx.y;
  const unsigned short* Ap; const unsigned short* Bp; unsigned short* Pp;
  if (bz < 32) {
    Ap = u1 + (long)bz * L_ * MEM_; Bp = g1 + (long)bz * L_ * MEM_;
    Pp = P1 + (long)bz * L_ * L_;
  } else {
    int z = bz - 32;
    Ap = u2 + (long)z * L_ * MEM_; Bp = g2 + (long)z * L_ * MEM_;
    Pp = P2 + (long)z * L_ * L_;
  }
  __shared__ unsigned short As[64][40];
  __shared__ unsigned short Bs[256][40];
  __shared__ float redm[2][64];
  __shared__ float reds[2][64];
  const int t = threadIdx.x;
  const int l = t & 63, w = t >> 6;
  const int wr = w >> 1, wc = w & 1;
  const int lr = l & 15, kg = (l >> 4) * 8;
  f32x4 acc[2][8] = {};
  const int arA = t >> 2, akA = (t & 3) * 8;

  for (int k0 = 0; k0 < MEM_; k0 += 32) {
    *(us8*)&As[arA][akA] = *(const us8*)(Ap + (long)(bm * 64 + arA) * MEM_ + k0 + akA);
#pragma unroll
    for (int j = 0; j < 4; ++j)
      *(us8*)&Bs[t][j * 8] = *(const us8*)(Bp + (long)t * MEM_ + k0 + j * 8);
    __syncthreads();
    bfrag8 af[2], bf[8];
#pragma unroll
    for (int m = 0; m < 2; ++m) af[m] = *(const bfrag8*)&As[wr * 32 + m * 16 + lr][kg];
#pragma unroll
    for (int n = 0; n < 8; ++n) bf[n] = *(const bfrag8*)&Bs[wc * 128 + n * 16 + lr][kg];
#pragma unroll
    for (int m = 0; m < 2; ++m)
#pragma unroll
      for (int n = 0; n < 8; ++n)
        acc[m][n] = __builtin_amdgcn_mfma_f32_16x16x32_bf16(af[m], bf[n], acc[m][n], 0, 0, 0);
    __syncthreads();
  }

#pragma unroll
  for (int m = 0; m < 2; ++m) {
#pragma unroll
    for (int r = 0; r < 4; ++r) {
      int lrow = wr * 32 + m * 16 + (l >> 4) * 4 + r;
      float mx = -1e30f;
#pragma unroll
      for (int n = 0; n < 8; ++n) mx = fmaxf(mx, acc[m][n][r]);
#pragma unroll
      for (int o = 1; o < 16; o <<= 1) mx = fmaxf(mx, __shfl_xor(mx, o, 64));
      if (lr == 0) redm[wc][lrow] = mx;
    }
  }
  __syncthreads();
#pragma unroll
  for (int m = 0; m < 2; ++m) {
#pragma unroll
    for (int r = 0; r < 4; ++r) {
      int lrow = wr * 32 + m * 16 + (l >> 4) * 4 + r;
      float mx = fmaxf(redm[0][lrow], redm[1][lrow]);
      float s = 0.f;
#pragma unroll
      for (int n = 0; n < 8; ++n) {
        float e = __expf(acc[m][n][r] - mx);
        acc[m][n][r] = e;
        s += e;
      }
#pragma unroll
      for (int o = 1; o < 16; o <<= 1) s += __shfl_xor(s, o, 64);
      if (lr == 0) reds[wc][lrow] = s;
    }
  }
  __syncthreads();
#pragma unroll
  for (int m = 0; m < 2; ++m) {
#pragma unroll
    for (int r = 0; r < 4; ++r) {
      int lrow = wr * 32 + m * 16 + (l >> 4) * 4 + r;
      float inv = 1.f / (reds[0][lrow] + reds[1][lrow]);
      int row = bm * 64 + lrow;
#pragma unroll
      for (int n = 0; n < 8; ++n) {
        int col = wc * 128 + n * 16 + lr;
        Pp[(long)row * L_ + col] = f2bf(acc[m][n][r] * inv);
      }
    }
  }
}

// ---------------- asps_mean via MFMA ----------------
__global__ __launch_bounds__(256) void asps_mean_v2(
    const unsigned short* __restrict__ tmpA,
    const unsigned short* __restrict__ kbf,
    const float* __restrict__ bias_m,
    float* __restrict__ asps_mean) {
  int blk = blockIdx.x;
  int b = blk >> 4, l0 = (blk & 15) << 4;
  int t = threadIdx.x;
  int w = t >> 6, l = t & 63;
  int lr = l & 15, kg = (l >> 4) * 8;
  float bm = bias_m[0];
  float accg[4][4] = {};
  for (int h = 0; h < H_; ++h) {
    const unsigned short* ap = tmpA + (((long)b * H_ + h) * L_ + l0 + lr) * 64 + kg;
    bfrag8 af0 = *(const bfrag8*)ap;
    bfrag8 af1 = *(const bfrag8*)(ap + 32);
#pragma unroll
    for (int ct = 0; ct < 4; ++ct) {
      const unsigned short* bp =
          kbf + ((long)b * L_ + w * 64 + ct * 16 + lr) * D_ + h * 64 + kg;
      bfrag8 bf0 = *(const bfrag8*)bp;
      bfrag8 bf1 = *(const bfrag8*)(bp + 32);
      f32x4 accl = {};
      accl = __builtin_amdgcn_mfma_f32_16x16x32_bf16(af0, bf0, accl, 0, 0, 0);
      accl = __builtin_amdgcn_mfma_f32_16x16x32_bf16(af1, bf1, accl, 0, 0, 0);
#pragma unroll
      for (int r = 0; r < 4; ++r) accg[ct][r] += tanh_fast(accl[r] + bm);
    }
  }
#pragma unroll
  for (int ct = 0; ct < 4; ++ct) {
    int col = w * 64 + ct * 16 + lr;
#pragma unroll
    for (int r = 0; r < 4; ++r) {
      int row = l0 + (l >> 4) * 4 + r;
      asps_mean[((long)b * L_ + row) * L_ + col] = accg[ct][r] * (1.f / H_);
    }
  }
}

// ---------------- avgH (1024 threads: 4-way l-split) ----------------
__global__ __launch_bounds__(1024) void avgh_kernel(const float* __restrict__ asps_mean,
                                                    float* __restrict__ avgH) {
  int b = blockIdx.x;
  int m = threadIdx.x & 255, q = threadIdx.x >> 8;
  __shared__ float part[4][256];
  float s = 0.f;
  for (int l = q * 64; l < q * 64 + 64; ++l)
    s += asps_mean[((long)b * L_ + l) * L_ + m];
  part[q][m] = s;
  __syncthreads();
  if (q == 0)
    avgH[b * L_ + m] = (part[0][m] + part[1][m] + part[2][m] + part[3][m]) * (1.f / L_);
}

// ---------------- adj_ag (dual f32 + bf16) ----------------
__global__ __launch_bounds__(256) void adjag_kernel(const float* __restrict__ asps_mean,
                                                    const float* __restrict__ avgH,
                                                    const float* __restrict__ amask,
                                                    const float* __restrict__ adjr,
                                                    float* __restrict__ adj_ag,
                                                    unsigned short* __restrict__ adjagbf) {
  long idx = (long)blockIdx.x * 256 + threadIdx.x;
  int m = idx & 255;
  long bl = idx >> 8;
  int l = (int)(bl & 255);
  int b = (int)(bl >> 8);
  bool rowa = amask[b * L_ + l] > 0.f;
  bool cola = amask[b * L_ + m] > 0.f;
  float asa;
  if (rowa && cola) asa = (l >= m) ? avgH[b * L_ + m] : avgH[b * L_ + l];
  else if (rowa)    asa = avgH[b * L_ + m];
  else if (cola)    asa = avgH[b * L_ + l];
  else              asa = asps_mean[idx];
  float r = (asa > 0.25f) ? 1.f : expf(adjr[idx]);
  float v = r * asa;
  adj_ag[idx] = v;
  adjagbf[idx] = f2bf(v);
}

// ---------------- KL partials + row denominators ----------------
__global__ __launch_bounds__(256) void kl_denom(const float* __restrict__ adj_s,
                                                const float* __restrict__ adj_ag,
                                                float* __restrict__ klpart,
                                                float* __restrict__ den_s,
                                                float* __restrict__ den_ag) {
  long row = blockIdx.x;
  int m = threadIdx.x;
  __shared__ float red[4];
  float s = adj_s[row * L_ + m];
  float a = adj_ag[row * L_ + m];
  float sum_s = blkRedSum(s, red);
  float sum_a = blkRedSum(a, red);
  float mx_s = blkRedMax(s, red);
  float mx_a = blkRedMax(a, red);
  float es = expf(s - mx_s), ea = expf(a - mx_a);
  float ses = blkRedSum(es, red);
  float sea = blkRedSum(ea, red);
  float logq = (s - mx_s) - logf(ses);
  float logp = (a - mx_a) - logf(sea);
  float term = (es / ses) * (logq - logp);
  float kp = blkRedSum(term, red);
  if (m == 0) {
    klpart[row] = kp;
    den_s[row] = sum_s + 1.f;
    den_ag[row] = sum_a + 1.f;
  }
}

__global__ __launch_bounds__(256) void kl_final(const float* __restrict__ klpart,
                                                float* __restrict__ dout) {
  __shared__ float red[4];
  float s = 0.f;
  for (int i = threadIdx.x; i < B_ * L_; i += 256) s += klpart[i];
  s = blkRedSum(s, red);
  if (threadIdx.x == 0) dout[96] = expf(-s * 0.1f);
}

// ---------------- classifier head (bf16 o inputs) ----------------
__global__ __launch_bounds__(256) void final_kernel(const unsigned short* __restrict__ o_ag,
                                                    const unsigned short* __restrict__ o_s,
                                                    const float* __restrict__ pooled,
                                                    const float* __restrict__ amask,
                                                    const float* __restrict__ wc,
                                                    const float* __restrict__ bc,
                                                    float* __restrict__ dout) {
  int b = blockIdx.x, t = threadIdx.x;
  __shared__ float cS[1536];
  __shared__ float maskS[256];
  __shared__ float red[4];
  maskS[t] = amask[b * L_ + t];
  float wn = blkRedSum(maskS[t], red);
  for (int e = t; e < MEM_; e += 256) {
    float s1 = 0.f, s2 = 0.f;
    for (int l = 0; l < L_; ++l) {
      float mk = maskS[l];
      if (mk != 0.f) {
        s1 += mk * bf2f(o_ag[((long)b * L_ + l) * MEM_ + e]);
        s2 += mk * bf2f(o_s[((long)b * L_ + l) * MEM_ + e]);
      }
    }
    cS[e] = s1 / wn;
    cS[MEM_ + e] = s2 / wn;
  }
  for (int j = t; j < D_; j += 256) cS[2 * MEM_ + j] = pooled[b * D_ + j];
  __syncthreads();
  float p0 = 0.f, p1 = 0.f, p2 = 0.f;
  for (int j = t; j < 1536; j += 256) {
    float v = cS[j];
    p0 += v * wc[j * 3 + 0];
    p1 += v * wc[j * 3 + 1];
    p2 += v * wc[j * 3 + 2];
  }
  p0 = blkRedSum(p0, red);
  p1 = blkRedSum(p1, red);
  p2 = blkRedSum(p2, red);
  if (t == 0) {
    dout[b * 3 + 0] = p0 + bc[0];
    dout[b * 3 + 1] = p1 + bc[1];
    dout[b * 3 + 2] = p2 + bc[2];
  }
}

extern "C" void kernel_launch(void* const* d_in, const int* in_sizes, int n_in,
                              void* d_out, int out_size, void* d_ws, size_t ws_size,
                              hipStream_t stream) {
  const float* seq    = (const float*)d_in[0];
  const float* pooled = (const float*)d_in[1];
  const float* adjr   = (const float*)d_in[2];
  const float* srcm   = (const float*)d_in[3];
  const float* amask  = (const float*)d_in[4];
  const float* ln_g   = (const float*)d_in[5];
  const float* ln_b   = (const float*)d_in[6];
  const float* wq     = (const float*)d_in[7];
  const float* bq     = (const float*)d_in[8];
  const float* wk     = (const float*)d_in[9];
  const float* bk     = (const float*)d_in[10];
  const float* wd     = (const float*)d_in[11];
  const float* bd     = (const float*)d_in[12];
  const float* wm     = (const float*)d_in[13];
  const float* bm     = (const float*)d_in[14];
  const float* wa0    = (const float*)d_in[15];
  const float* ba0    = (const float*)d_in[16];
  const float* wa1    = (const float*)d_in[17];
  const float* ba1    = (const float*)d_in[18];
  const float* ws0    = (const float*)d_in[19];
  const float* bs0    = (const float*)d_in[20];
  const float* ws1    = (const float*)d_in[21];
  const float* bs1    = (const float*)d_in[22];
  const float* aff1   = (const float*)d_in[23];
  const float* aff2   = (const float*)d_in[24];
  const float* wc     = (const float*)d_in[25];
  const float* bc     = (const float*)d_in[26];

  float* ws = (float*)d_ws;
  // ---- workspace layout (float units) ----
  float* S0 = ws;                        // 6291456: x f32 -> {o_agbf|o_sbf|gTag|gTs}
  float* S1 = S0 + 6291456;              // 3145728: xbf
  float* S2 = S1 + 3145728;              // 3145728: qbf -> tmpA -> {g_agbf|g_sbf}
  float* S3 = S2 + 3145728;              // 3145728: kbf -> {tTag|tTs} -> {u1bf|u2bf}
  float* S4 = S3 + 3145728;              // 524288 : aspbf + wdT + wmT (shorts)
  float* S5 = S4 + 524288;               // 2097152: asps f32 -> {P1bf|P2bf}
  float* adj_s  = S5 + 2097152;          // 2097152
  float* adj_ag = adj_s + 2097152;       // 2097152
  unsigned short* adjsbf  = (unsigned short*)(adj_ag + 2097152);  // 2097152 sh
  unsigned short* adjagbf = adjsbf + 2097152;                     // 2097152 sh
  unsigned short* wT      = adjagbf + 2097152;                    // 2359296 sh
  unsigned short* wqT   = wT;
  unsigned short* wkT   = wT + 589824;
  unsigned short* wa0T  = wT + 1179648;
  unsigned short* ws0T  = wT + 1474560;
  unsigned short* wa1T  = wT + 1769472;
  unsigned short* ws1T  = wT + 1916928;
  unsigned short* aff1T = wT + 2064384;
  unsigned short* aff2T = wT + 2211840;
  float* tail   = (float*)(wT + 2359296);
  float* avgH   = tail;
  float* den_s  = avgH + 8192;
  float* den_ag = den_s + 8192;
  float* klp    = den_ag + 8192;

  float* x = S0;
  unsigned short* o_agbf = (unsigned short*)S0;
  unsigned short* o_sbf  = o_agbf + 3145728;
  unsigned short* gTag   = o_agbf + 6291456;
  unsigned short* gTs    = o_agbf + 9437184;
  unsigned short* xbf    = (unsigned short*)S1;
  unsigned short* qbf    = (unsigned short*)S2;
  unsigned short* tmpA   = (unsigned short*)S2;
  unsigned short* g_agbf = (unsigned short*)S2;
  unsigned short* g_sbf  = g_agbf + 3145728;
  unsigned short* kbf    = (unsigned short*)S3;
  unsigned short* tTag   = (unsigned short*)S3;
  unsigned short* tTs    = tTag + 3145728;
  unsigned short* u1bf   = (unsigned short*)S3;
  unsigned short* u2bf   = u1bf + 3145728;
  unsigned short* aspbf  = (unsigned short*)S4;      // 524288 shorts
  unsigned short* wdT    = aspbf + 524288;           // 49152 shorts
  unsigned short* wmT    = wdT + 49152;              // 49152 shorts
  float* asps = S5;
  unsigned short* P1bf = (unsigned short*)S5;
  unsigned short* P2bf = P1bf + 2097152;
  float* dout = (float*)d_out;

  const long sAdjSh = (long)L_ * L_;     // 65536 shorts per z
  const long sMemSh = (long)L_ * MEM_;   // 98304 shorts per z

  // ---- weight transpose/convert (once per call) ----
  tc_pair<<<dim3(12, 12, 2), 256, 0, stream>>>(wq, wqT, wk, wkT, 768, 768);
  tc_pair<<<dim3(6, 12, 2), 256, 0, stream>>>(wa0, wa0T, ws0, ws0T, 768, 384);
  tc_pair<<<dim3(6, 6, 2), 256, 0, stream>>>(wa1, wa1T, ws1, ws1T, 384, 384);
  tc_pair<<<dim3(6, 6, 2), 256, 0, stream>>>(aff1, aff1T, aff2, aff2T, 384, 384);
  tc_pair<<<dim3(1, 12, 1), 256, 0, stream>>>(wd, wdT, nullptr, nullptr, 768, 64);
  tc_wm<<<H_, 256, 0, stream>>>(wm, wmT);

  ln_kernel<<<B_ * L_, 256, 0, stream>>>(seq, ln_g, ln_b, x, xbf);
  // paired q/k projections (bf16 in/out)
  gemm_bb<<<dim3(6, 64, 2), 256, 0, stream>>>(
      xbf, wqT, nullptr, qbf, nullptr, 8192, 768, 768, 0, 0, 0, 0, bq, nullptr, 0,
      xbf, wkT, nullptr, kbf, nullptr, bk, nullptr, 1);
  attn_mfma<<<B_ * 16, 256, 0, stream>>>(qbf, kbf, srcm, adj_s, adjsbf);
  // asp chain (MFMA)
  asp_mfma<<<512, 256, 0, stream>>>(xbf, wdT, amask, bd, aspbf);
  asp_wm_v2<<<B_ * H_, 256, 0, stream>>>(aspbf, wmT, tmpA);  // after attn (tmpA aliases qbf)
  asps_mean_v2<<<B_ * 16, 256, 0, stream>>>(tmpA, kbf, bm, asps);
  avgh_kernel<<<B_, 1024, 0, stream>>>(asps, avgH);
  adjag_kernel<<<B_ * L_ * L_ / 256, 256, 0, stream>>>(asps, avgH, amask, adjr,
                                                       adj_ag, adjagbf);
  kl_denom<<<B_ * L_, 256, 0, stream>>>(adj_s, adj_ag, klp, den_s, den_ag);
  kl_final<<<1, 256, 0, stream>>>(klp, dout);

  for (int li = 0; li < 2; ++li) {
    int Kd = li ? MEM_ : D_;
    const unsigned short* inag = li ? o_agbf : xbf;
    const unsigned short* ins  = li ? o_sbf : xbf;
    const unsigned short* wAT = li ? wa1T : wa0T;
    const float* bA = li ? ba1 : ba0;
    const unsigned short* wST = li ? ws1T : ws0T;
    const float* bS = li ? bs1 : bs0;
    // paired t-GEMMs -> transposed bf16 tT
    gemm_bb<<<dim3(3, 64, 2), 256, 0, stream>>>(
        inag, wAT, nullptr, nullptr, tTag, 8192, MEM_, Kd, 0, 0, 0, sMemSh,
        nullptr, nullptr, 0,
        ins, wST, nullptr, nullptr, tTs, nullptr, nullptr, 1);
    // paired g-GEMMs: g = relu((adj@t + b)/den), outputs g bf16 + gT bf16
    gemm_bb<<<dim3(3, 2, 64), 256, 0, stream>>>(
        adjagbf, tTag, nullptr, g_agbf, gTag, L_, MEM_, L_, sAdjSh, sMemSh, sMemSh,
        sMemSh, bA, den_ag, 1,
        adjsbf, tTs, nullptr, g_sbf, gTs, bS, den_s, 32);
    // paired u-GEMMs
    gemm_bb<<<dim3(3, 64, 2), 256, 0, stream>>>(
        g_agbf, aff1T, nullptr, u1bf, nullptr, 8192, MEM_, MEM_, 0, 0, 0, 0,
        nullptr, nullptr, 0,
        g_sbf, aff2T, nullptr, u2bf, nullptr, nullptr, nullptr, 1);
    // paired fused S+softmax
    gemm_sfmx<<<dim3(4, 64), 256, 0, stream>>>(u1bf, g_sbf, P1bf, u2bf, g_agbf, P2bf);
    // paired PV: o_ag = P1@g_s (B = gTs), o_s = P2@g_ag (B = gTag)
    gemm_bb<<<dim3(3, 2, 64), 256, 0, stream>>>(
        P1bf, gTs, nullptr, o_agbf, nullptr, L_, MEM_, L_, sAdjSh, sMemSh, sMemSh, 0,
        nullptr, nullptr, 0,
        P2bf, gTag, nullptr, o_sbf, nullptr, nullptr, nullptr, 32);
  }

  final_kernel<<<B_, 256, 0, stream>>>(o_agbf, o_sbf, pooled, amask, wc, bc, dout);
}